// Round 2
// baseline (29545.551 us; speedup 1.0000x reference)
//
#include <hip/hip_runtime.h>

#define HW 4096            // 64*64
#define CIN 32

// ---------- per-plane GN stats: write (sc, sh) per (b,c) plane -------------
__global__ __launch_bounds__(256)
void stats_kernel(const float* __restrict__ in, float* __restrict__ st,
                  const float* __restrict__ gamma, const float* __restrict__ beta)
{
    const int p = blockIdx.x;
    const int c = p & 31;
    const int t = threadIdx.x;
    const float4* ip = (const float4*)(in + (size_t)p * HW);
    float s = 0.f, ss = 0.f;
#pragma unroll
    for (int i = 0; i < 4; ++i) {
        float4 q = ip[t + i * 256];
        s += q.x + q.y + q.z + q.w;
        ss += q.x * q.x + q.y * q.y + q.z * q.z + q.w * q.w;
    }
#pragma unroll
    for (int off = 32; off > 0; off >>= 1) {
        s  += __shfl_xor(s, off);
        ss += __shfl_xor(ss, off);
    }
    __shared__ float red[8];
    const int wid = t >> 6;
    if ((t & 63) == 0) { red[wid] = s; red[4 + wid] = ss; }
    __syncthreads();
    if (t == 0) {
        s  = red[0] + red[1] + red[2] + red[3];
        ss = red[4] + red[5] + red[6] + red[7];
        const float mean = s * (1.f / HW);
        const float var  = ss * (1.f / HW) - mean * mean;
        const float rstd = rsqrtf(var + 1e-5f);
        const float sc = gamma[c] * rstd;
        st[p * 2]     = sc;
        st[p * 2 + 1] = beta[c] - mean * sc;
    }
}

// ---------- conv 3x3 with fused input GN+ReLU (via stats) ------------------
// in: raw tensor; st: per-plane (sc, sh). LDS tile = normalized+relu'd input.
// Weights/bias fetched via wave-uniform (readfirstlane) scalar loads.
template<int HAS_TIME>
__global__ __launch_bounds__(256)
void conv3x3_kernel(const float* __restrict__ in, float* __restrict__ out,
                    const float* __restrict__ st,
                    const float* __restrict__ wgt, const float* __restrict__ cb,
                    float tval)
{
    const int WS = HAS_TIME ? 33 : 32;     // weight input-channel stride
    const int blk = blockIdx.x;
    const int b = blk >> 4;
    const int h0 = (blk & 15) * 4;
    const int t = threadIdx.x;
    const int tw = t & 63;
    const int ogu = __builtin_amdgcn_readfirstlane(t >> 6);   // wave-uniform

    __shared__ float smem[6][CIN][64];     // rows h0-1 .. h0+4, normalized

    const float* inb = in + (size_t)b * (CIN * HW);
    const float* stb = st + (size_t)b * (CIN * 2);
    for (int i = t; i < 6 * CIN * 64; i += 256) {
        const int r = i >> 11;
        const int rem = i & 2047;
        const int c = rem >> 6;
        const int wq = rem & 63;
        const int hh = h0 - 1 + r;
        float v = 0.f;
        if (hh >= 0 && hh < 64) {
            const float raw = inb[(size_t)c * HW + hh * 64 + wq];
            v = fmaxf(raw * stb[c * 2] + stb[c * 2 + 1], 0.f);
        }
        smem[r][c][wq] = v;
    }
    __syncthreads();

    float acc[4][8];
#pragma unroll
    for (int r = 0; r < 4; ++r)
#pragma unroll
        for (int o = 0; o < 8; ++o) acc[r][o] = 0.f;

    float iv[6][3];

    for (int c = 0; c < CIN; ++c) {
#pragma unroll
        for (int r = 0; r < 6; ++r) {
            iv[r][1] = smem[r][c][tw];
            iv[r][0] = (tw > 0)  ? smem[r][c][tw - 1] : 0.f;
            iv[r][2] = (tw < 63) ? smem[r][c][tw + 1] : 0.f;
        }
        const int ci = HAS_TIME ? (c + 1) : c;
#pragma unroll
        for (int o8 = 0; o8 < 8; ++o8) {
            const float* wp = wgt + ((size_t)((ogu * 8 + o8) * WS + ci)) * 9;
            float wq[9];
#pragma unroll
            for (int k = 0; k < 9; ++k) wq[k] = wp[k];   // scalar s_load path
#pragma unroll
            for (int dy = 0; dy < 3; ++dy)
#pragma unroll
                for (int dx = 0; dx < 3; ++dx) {
                    const float wv = wq[dy * 3 + dx];
#pragma unroll
                    for (int r = 0; r < 4; ++r)
                        acc[r][o8] += iv[r + dy][dx] * wv;
                }
        }
    }

    if (HAS_TIME) {
        // constant time plane, zero-padded like the image
#pragma unroll
        for (int r = 0; r < 6; ++r) {
            const int hh = h0 - 1 + r;
            const float hv = (hh >= 0 && hh < 64) ? tval : 0.f;
            iv[r][1] = hv;
            iv[r][0] = (tw > 0)  ? hv : 0.f;
            iv[r][2] = (tw < 63) ? hv : 0.f;
        }
#pragma unroll
        for (int o8 = 0; o8 < 8; ++o8) {
            const float* wp = wgt + ((size_t)((ogu * 8 + o8) * WS)) * 9;
            float wq[9];
#pragma unroll
            for (int k = 0; k < 9; ++k) wq[k] = wp[k];
#pragma unroll
            for (int dy = 0; dy < 3; ++dy)
#pragma unroll
                for (int dx = 0; dx < 3; ++dx) {
                    const float wv = wq[dy * 3 + dx];
#pragma unroll
                    for (int r = 0; r < 4; ++r)
                        acc[r][o8] += iv[r + dy][dx] * wv;
                }
        }
    }

    const size_t ob = (size_t)b * (CIN * HW);
#pragma unroll
    for (int o8 = 0; o8 < 8; ++o8) {
        const int o = ogu * 8 + o8;
        const float bias = cb[o];
#pragma unroll
        for (int r = 0; r < 4; ++r)
            out[ob + (size_t)o * HW + (size_t)(h0 + r) * 64 + tw] = acc[r][o8] + bias;
    }
}

// ---------- atten_init tail: gn2+relu then gn3, plane in registers ---------
__global__ __launch_bounds__(256)
void dgn_kernel(const float* __restrict__ in, float* __restrict__ out,
                const float* __restrict__ g2, const float* __restrict__ b2,
                const float* __restrict__ g3, const float* __restrict__ b3)
{
    const int p = blockIdx.x;
    const int c = p & 31;
    const int t = threadIdx.x;
    const float4* ip = (const float4*)(in + (size_t)p * HW);
    float4* op = (float4*)(out + (size_t)p * HW);
    __shared__ float red[8];
    const int wid = t >> 6;

    float4 v[4];
    float s = 0.f, ss = 0.f;
#pragma unroll
    for (int i = 0; i < 4; ++i) {
        float4 q = ip[t + i * 256];
        v[i] = q;
        s += q.x + q.y + q.z + q.w;
        ss += q.x * q.x + q.y * q.y + q.z * q.z + q.w * q.w;
    }
#pragma unroll
    for (int off = 32; off > 0; off >>= 1) {
        s  += __shfl_xor(s, off);
        ss += __shfl_xor(ss, off);
    }
    if ((t & 63) == 0) { red[wid] = s; red[4 + wid] = ss; }
    __syncthreads();
    s  = red[0] + red[1] + red[2] + red[3];
    ss = red[4] + red[5] + red[6] + red[7];
    float mean = s * (1.f / HW);
    float var  = ss * (1.f / HW) - mean * mean;
    float rstd = rsqrtf(var + 1e-5f);
    float sc = g2[c] * rstd;
    float sh = b2[c] - mean * sc;

    s = 0.f; ss = 0.f;
#pragma unroll
    for (int i = 0; i < 4; ++i) {
        float4 q = v[i];
        q.x = fmaxf(q.x * sc + sh, 0.f); q.y = fmaxf(q.y * sc + sh, 0.f);
        q.z = fmaxf(q.z * sc + sh, 0.f); q.w = fmaxf(q.w * sc + sh, 0.f);
        v[i] = q;
        s += q.x + q.y + q.z + q.w;
        ss += q.x * q.x + q.y * q.y + q.z * q.z + q.w * q.w;
    }
#pragma unroll
    for (int off = 32; off > 0; off >>= 1) {
        s  += __shfl_xor(s, off);
        ss += __shfl_xor(ss, off);
    }
    __syncthreads();
    if ((t & 63) == 0) { red[wid] = s; red[4 + wid] = ss; }
    __syncthreads();
    s  = red[0] + red[1] + red[2] + red[3];
    ss = red[4] + red[5] + red[6] + red[7];
    mean = s * (1.f / HW);
    var  = ss * (1.f / HW) - mean * mean;
    rstd = rsqrtf(var + 1e-5f);
    sc = g3[c] * rstd;
    sh = b3[c] - mean * sc;
#pragma unroll
    for (int i = 0; i < 4; ++i) {
        float4 q = v[i];
        q.x = q.x * sc + sh; q.y = q.y * sc + sh;
        q.z = q.z * sc + sh; q.w = q.w * sc + sh;
        op[t + i * 256] = q;
    }
}

// ---------- fused GN3 + RK stage update ------------------------------------
// kin (=YT): conv2 output; k = gn(kin). Overwrites kin with next stage input.
// mode 0: acc = y + ca*k ; yt = y + cy*k
// mode 1: acc += ca*k    ; yt = y + cy*k
// mode 2: y = acc + ca*k   (no yt write)
__global__ __launch_bounds__(256)
void gnrk_kernel(float* __restrict__ kin,
                 const float* __restrict__ g, const float* __restrict__ bt,
                 float* __restrict__ y, float* __restrict__ acc,
                 float ca, float cy, int mode)
{
    const int p = blockIdx.x;
    const int c = p & 31;
    const int t = threadIdx.x;
    float4* kp = (float4*)(kin + (size_t)p * HW);
    float4* yp = (float4*)(y   + (size_t)p * HW);
    float4* ap = (float4*)(acc + (size_t)p * HW);
    __shared__ float red[8];
    const int wid = t >> 6;

    float4 v[4];
    float s = 0.f, ss = 0.f;
#pragma unroll
    for (int i = 0; i < 4; ++i) {
        float4 q = kp[t + i * 256];
        v[i] = q;
        s += q.x + q.y + q.z + q.w;
        ss += q.x * q.x + q.y * q.y + q.z * q.z + q.w * q.w;
    }
#pragma unroll
    for (int off = 32; off > 0; off >>= 1) {
        s  += __shfl_xor(s, off);
        ss += __shfl_xor(ss, off);
    }
    if ((t & 63) == 0) { red[wid] = s; red[4 + wid] = ss; }
    __syncthreads();
    s  = red[0] + red[1] + red[2] + red[3];
    ss = red[4] + red[5] + red[6] + red[7];
    const float mean = s * (1.f / HW);
    const float var  = ss * (1.f / HW) - mean * mean;
    const float rstd = rsqrtf(var + 1e-5f);
    const float sc = g[c] * rstd;
    const float sh = bt[c] - mean * sc;

#pragma unroll
    for (int i = 0; i < 4; ++i) {
        float4 kq = v[i];
        kq.x = kq.x * sc + sh; kq.y = kq.y * sc + sh;
        kq.z = kq.z * sc + sh; kq.w = kq.w * sc + sh;
        const int idx = t + i * 256;
        if (mode == 2) {
            float4 av = ap[idx];
            av.x += ca * kq.x; av.y += ca * kq.y;
            av.z += ca * kq.z; av.w += ca * kq.w;
            yp[idx] = av;
        } else {
            float4 yv = yp[idx];
            float4 av;
            if (mode == 0) {
                av.x = yv.x + ca * kq.x; av.y = yv.y + ca * kq.y;
                av.z = yv.z + ca * kq.z; av.w = yv.w + ca * kq.w;
            } else {
                av = ap[idx];
                av.x += ca * kq.x; av.y += ca * kq.y;
                av.z += ca * kq.z; av.w += ca * kq.w;
            }
            ap[idx] = av;
            float4 tv;
            tv.x = yv.x + cy * kq.x; tv.y = yv.y + cy * kq.y;
            tv.z = yv.z + cy * kq.z; tv.w = yv.w + cy * kq.w;
            kp[idx] = tv;            // becomes next stage input
        }
    }
}

extern "C" void kernel_launch(void* const* d_in, const int* in_sizes, int n_in,
                              void* d_out, int out_size, void* d_ws, size_t ws_size,
                              hipStream_t stream) {
    (void)in_sizes; (void)n_in; (void)out_size; (void)ws_size;
    const float* x      = (const float*)d_in[0];
    const float* ai_g1  = (const float*)d_in[1];
    const float* ai_b1  = (const float*)d_in[2];
    const float* ai_w   = (const float*)d_in[3];
    const float* ai_cb  = (const float*)d_in[4];
    const float* ai_g2  = (const float*)d_in[5];
    const float* ai_b2  = (const float*)d_in[6];
    const float* ai_g3  = (const float*)d_in[7];
    const float* ai_b3  = (const float*)d_in[8];
    const float* of_g1  = (const float*)d_in[9];
    const float* of_b1  = (const float*)d_in[10];
    const float* of_w1  = (const float*)d_in[11];
    const float* of_cb1 = (const float*)d_in[12];
    const float* of_g2  = (const float*)d_in[13];
    const float* of_b2  = (const float*)d_in[14];
    const float* of_w2  = (const float*)d_in[15];
    const float* of_cb2 = (const float*)d_in[16];
    const float* of_g3  = (const float*)d_in[17];
    const float* of_b3  = (const float*)d_in[18];

    float* y = (float*)d_out;                         // state, (256,32,64,64)
    const size_t N  = (size_t)256 * 32 * 64 * 64;
    const size_t NH = N / 2;
    float* ws  = (float*)d_ws;
    float* A   = ws;                                  // conv1 out / conv2 in
    float* YT  = ws + N;                              // stage input / conv2 out
    float* ACC = ws + 2 * N;                          // RK accumulator
    float* ST  = ws + 3 * N;                          // per-plane (sc, sh)

    const float h = 0.125f;

    // ---- atten_init (batch 128) ----
    stats_kernel<<<4096, 256, 0, stream>>>(x, ST, ai_g1, ai_b1);
    conv3x3_kernel<0><<<2048, 256, 0, stream>>>(x, A, ST, ai_w, ai_cb, 0.f);
    dgn_kernel<<<4096, 256, 0, stream>>>(A, y + NH, ai_g2, ai_b2, ai_g3, ai_b3);
    hipMemcpyAsync(y, x, NH * sizeof(float), hipMemcpyDeviceToDevice, stream);

    // ---- odefunc: yin -> gn3 fused into RK update ----
    auto eval = [&](const float* yin, float tv, float ca, float cy, int mode) {
        stats_kernel<<<8192, 256, 0, stream>>>(yin, ST, of_g1, of_b1);
        conv3x3_kernel<1><<<4096, 256, 0, stream>>>(yin, A, ST, of_w1, of_cb1, tv);
        stats_kernel<<<8192, 256, 0, stream>>>(A, ST, of_g2, of_b2);
        conv3x3_kernel<1><<<4096, 256, 0, stream>>>(A, YT, ST, of_w2, of_cb2, tv);
        gnrk_kernel<<<8192, 256, 0, stream>>>(YT, of_g3, of_b3, y, ACC, ca, cy, mode);
    };

    for (int s = 0; s < 8; ++s) {
        const float t0 = h * (float)s;
        eval(y,  t0,            h / 6.f, 0.5f * h, 0);   // k1
        eval(YT, t0 + 0.5f * h, h / 3.f, 0.5f * h, 1);   // k2
        eval(YT, t0 + 0.5f * h, h / 3.f, h,        1);   // k3
        eval(YT, t0 + h,        h / 6.f, 0.f,      2);   // k4
    }
}

// Round 3
// 25534.566 us; speedup vs baseline: 1.1571x; 1.1571x over previous
//
#include <hip/hip_runtime.h>

#define HW 4096            // 64*64
#define CIN 32

// ---------- weight prep: reorder to [ci][og(4)][o8(8)*9] for LDS b128 reads
__global__ __launch_bounds__(256)
void prep_kernel(const float* __restrict__ ai_w,
                 const float* __restrict__ of_w1,
                 const float* __restrict__ of_w2,
                 float* __restrict__ wp_ai,
                 float* __restrict__ wp_of1,
                 float* __restrict__ wp_of2)
{
    const int t = threadIdx.x;
    for (int i = t; i < 32 * 32 * 9; i += 256) {
        const int oc = i / 288, rem = i - oc * 288;
        const int ci = rem / 9, tap = rem - ci * 9;
        wp_ai[(ci * 4 + (oc >> 3)) * 72 + (oc & 7) * 9 + tap] = ai_w[i];
    }
    for (int i = t; i < 32 * 33 * 9; i += 256) {
        const int oc = i / 297, rem = i - oc * 297;
        const int ci = rem / 9, tap = rem - ci * 9;
        const int d = (ci * 4 + (oc >> 3)) * 72 + (oc & 7) * 9 + tap;
        wp_of1[d] = of_w1[i];
        wp_of2[d] = of_w2[i];
    }
}

// ---------- per-plane GN stats: write (sc, sh) per (b,c) plane -------------
__global__ __launch_bounds__(256)
void stats_kernel(const float* __restrict__ in, float* __restrict__ st,
                  const float* __restrict__ gamma, const float* __restrict__ beta)
{
    const int p = blockIdx.x;
    const int c = p & 31;
    const int t = threadIdx.x;
    const float4* ip = (const float4*)(in + (size_t)p * HW);
    float s = 0.f, ss = 0.f;
#pragma unroll
    for (int i = 0; i < 4; ++i) {
        float4 q = ip[t + i * 256];
        s += q.x + q.y + q.z + q.w;
        ss += q.x * q.x + q.y * q.y + q.z * q.z + q.w * q.w;
    }
#pragma unroll
    for (int off = 32; off > 0; off >>= 1) {
        s  += __shfl_xor(s, off);
        ss += __shfl_xor(ss, off);
    }
    __shared__ float red[8];
    const int wid = t >> 6;
    if ((t & 63) == 0) { red[wid] = s; red[4 + wid] = ss; }
    __syncthreads();
    if (t == 0) {
        s  = red[0] + red[1] + red[2] + red[3];
        ss = red[4] + red[5] + red[6] + red[7];
        const float mean = s * (1.f / HW);
        const float var  = ss * (1.f / HW) - mean * mean;
        const float rstd = rsqrtf(var + 1e-5f);
        const float sc = gamma[c] * rstd;
        st[p * 2]     = sc;
        st[p * 2 + 1] = beta[c] - mean * sc;
    }
}

// ---------- conv 3x3 (fused input GN+ReLU), weights in LDS -----------------
// block = 256 threads = 4 waves; wave og owns 8 output channels; thread:
// 4 output rows x 8 oc. Input: direct global loads (center col) + shfl for
// L/R neighbors. Optional stats epilogue -> deterministic per-block partials.
template<int HAS_TIME, int STATS>
__global__ __launch_bounds__(256)
void conv_kernel(const float* __restrict__ in, float* __restrict__ out,
                 const float* __restrict__ st, const float* __restrict__ wp,
                 const float* __restrict__ cb, float tval,
                 float* __restrict__ straw)
{
    const int NCI = HAS_TIME ? 33 : 32;
    const int blk = blockIdx.x;
    const int b = blk >> 4;
    const int hb = blk & 15;
    const int h0 = hb * 4;
    const int t = threadIdx.x;
    const int tw = t & 63;
    const int og = t >> 6;

    __shared__ float wlds[33 * 288];   // 38016 B max
    __shared__ float sst[96];          // [0..63] (sc,sh) per c ; [64..95] bias

    for (int i = t; i < NCI * 288; i += 256) wlds[i] = wp[i];
    if (t < 64) sst[t] = st[b * 64 + t];
    if (t < 32) sst[64 + t] = cb[t];
    __syncthreads();

    float acc[4][8];
#pragma unroll
    for (int r = 0; r < 4; ++r)
#pragma unroll
        for (int o = 0; o < 8; ++o) acc[r][o] = 0.f;

    const float* inb = in + (size_t)b * (CIN * HW);
    int hofs[6];
    bool val[6];
#pragma unroll
    for (int r = 0; r < 6; ++r) {
        const int hh = h0 - 1 + r;
        val[r] = (hh >= 0) && (hh < 64);
        hofs[r] = (val[r] ? hh : 0) * 64 + tw;
    }

    for (int c = 0; c < CIN; ++c) {
        const float scv = sst[2 * c], shv = sst[2 * c + 1];
        const float* inc = inb + (size_t)c * HW;
        float iv[6][3];
#pragma unroll
        for (int r = 0; r < 6; ++r) {
            const float m = val[r] ? fmaxf(inc[hofs[r]] * scv + shv, 0.f) : 0.f;
            const float l  = __shfl_up(m, 1);
            const float rr = __shfl_down(m, 1);
            iv[r][0] = (tw == 0)  ? 0.f : l;
            iv[r][1] = m;
            iv[r][2] = (tw == 63) ? 0.f : rr;
        }
        const int ci = HAS_TIME ? (c + 1) : c;
        const float* wbase = &wlds[(ci * 4 + og) * 72];
#pragma unroll
        for (int half = 0; half < 2; ++half) {
            float wf[36];
            const float4* wg = (const float4*)(wbase + half * 36);
#pragma unroll
            for (int k = 0; k < 9; ++k) {
                const float4 w4 = wg[k];
                wf[k * 4]     = w4.x; wf[k * 4 + 1] = w4.y;
                wf[k * 4 + 2] = w4.z; wf[k * 4 + 3] = w4.w;
            }
#pragma unroll
            for (int o4 = 0; o4 < 4; ++o4) {
                const int o8 = half * 4 + o4;
#pragma unroll
                for (int dy = 0; dy < 3; ++dy)
#pragma unroll
                    for (int dx = 0; dx < 3; ++dx) {
                        const float wv = wf[o4 * 9 + dy * 3 + dx];
#pragma unroll
                        for (int r = 0; r < 4; ++r)
                            acc[r][o8] += iv[r + dy][dx] * wv;
                    }
            }
        }
    }

    if (HAS_TIME) {
        float iv[6][3];
#pragma unroll
        for (int r = 0; r < 6; ++r) {
            const float hv = val[r] ? tval : 0.f;
            iv[r][0] = (tw == 0)  ? 0.f : hv;
            iv[r][1] = hv;
            iv[r][2] = (tw == 63) ? 0.f : hv;
        }
        const float* wbase = &wlds[og * 72];   // ci = 0 (time channel)
#pragma unroll
        for (int half = 0; half < 2; ++half) {
            float wf[36];
            const float4* wg = (const float4*)(wbase + half * 36);
#pragma unroll
            for (int k = 0; k < 9; ++k) {
                const float4 w4 = wg[k];
                wf[k * 4]     = w4.x; wf[k * 4 + 1] = w4.y;
                wf[k * 4 + 2] = w4.z; wf[k * 4 + 3] = w4.w;
            }
#pragma unroll
            for (int o4 = 0; o4 < 4; ++o4) {
                const int o8 = half * 4 + o4;
#pragma unroll
                for (int dy = 0; dy < 3; ++dy)
#pragma unroll
                    for (int dx = 0; dx < 3; ++dx) {
                        const float wv = wf[o4 * 9 + dy * 3 + dx];
#pragma unroll
                        for (int r = 0; r < 4; ++r)
                            acc[r][o8] += iv[r + dy][dx] * wv;
                    }
            }
        }
    }

    const size_t ob = (size_t)b * (CIN * HW);
#pragma unroll
    for (int o8 = 0; o8 < 8; ++o8) {
        const int oc = og * 8 + o8;
        const float bias = sst[64 + oc];
        float s = 0.f, ss = 0.f;
#pragma unroll
        for (int r = 0; r < 4; ++r) {
            const float v = acc[r][o8] + bias;
            out[ob + (size_t)oc * HW + (size_t)(h0 + r) * 64 + tw] = v;
            if (STATS) { s += v; ss += v * v; }
        }
        if (STATS) {
#pragma unroll
            for (int off = 32; off > 0; off >>= 1) {
                s  += __shfl_xor(s, off);
                ss += __shfl_xor(ss, off);
            }
            if (tw == 0) {
                float* dst = straw + ((size_t)(b * 32 + oc) * 16 + hb) * 2;
                dst[0] = s; dst[1] = ss;
            }
        }
    }
}

// ---------- stats finalize: 16 per-block partials -> (sc, sh) --------------
__global__ __launch_bounds__(256)
void finalize_kernel(const float* __restrict__ straw, float* __restrict__ st,
                     const float* __restrict__ g, const float* __restrict__ bt)
{
    const int p = blockIdx.x * 256 + threadIdx.x;   // 8192 planes
    const int c = p & 31;
    const float* sp = straw + (size_t)p * 32;
    float s = 0.f, ss = 0.f;
#pragma unroll
    for (int i = 0; i < 16; ++i) { s += sp[2 * i]; ss += sp[2 * i + 1]; }
    const float mean = s * (1.f / HW);
    const float var  = ss * (1.f / HW) - mean * mean;
    const float rstd = rsqrtf(var + 1e-5f);
    const float sc = g[c] * rstd;
    st[p * 2]     = sc;
    st[p * 2 + 1] = bt[c] - mean * sc;
}

// ---------- atten_init tail: gn2+relu then gn3; emits GN1 stats of output --
__global__ __launch_bounds__(256)
void dgn_kernel(const float* __restrict__ in, float* __restrict__ out,
                const float* __restrict__ g2, const float* __restrict__ b2,
                const float* __restrict__ g3, const float* __restrict__ b3,
                const float* __restrict__ g1n, const float* __restrict__ b1n,
                float* __restrict__ stout)
{
    const int p = blockIdx.x;
    const int c = p & 31;
    const int t = threadIdx.x;
    const float4* ip = (const float4*)(in + (size_t)p * HW);
    float4* op = (float4*)(out + (size_t)p * HW);
    __shared__ float red[8];
    const int wid = t >> 6;

    float4 v[4];
    float s = 0.f, ss = 0.f;
#pragma unroll
    for (int i = 0; i < 4; ++i) {
        float4 q = ip[t + i * 256];
        v[i] = q;
        s += q.x + q.y + q.z + q.w;
        ss += q.x * q.x + q.y * q.y + q.z * q.z + q.w * q.w;
    }
#pragma unroll
    for (int off = 32; off > 0; off >>= 1) {
        s  += __shfl_xor(s, off);
        ss += __shfl_xor(ss, off);
    }
    if ((t & 63) == 0) { red[wid] = s; red[4 + wid] = ss; }
    __syncthreads();
    s  = red[0] + red[1] + red[2] + red[3];
    ss = red[4] + red[5] + red[6] + red[7];
    float mean = s * (1.f / HW);
    float var  = ss * (1.f / HW) - mean * mean;
    float rstd = rsqrtf(var + 1e-5f);
    float sc = g2[c] * rstd;
    float sh = b2[c] - mean * sc;

    s = 0.f; ss = 0.f;
#pragma unroll
    for (int i = 0; i < 4; ++i) {
        float4 q = v[i];
        q.x = fmaxf(q.x * sc + sh, 0.f); q.y = fmaxf(q.y * sc + sh, 0.f);
        q.z = fmaxf(q.z * sc + sh, 0.f); q.w = fmaxf(q.w * sc + sh, 0.f);
        v[i] = q;
        s += q.x + q.y + q.z + q.w;
        ss += q.x * q.x + q.y * q.y + q.z * q.z + q.w * q.w;
    }
#pragma unroll
    for (int off = 32; off > 0; off >>= 1) {
        s  += __shfl_xor(s, off);
        ss += __shfl_xor(ss, off);
    }
    __syncthreads();
    if ((t & 63) == 0) { red[wid] = s; red[4 + wid] = ss; }
    __syncthreads();
    s  = red[0] + red[1] + red[2] + red[3];
    ss = red[4] + red[5] + red[6] + red[7];
    mean = s * (1.f / HW);
    var  = ss * (1.f / HW) - mean * mean;
    rstd = rsqrtf(var + 1e-5f);
    sc = g3[c] * rstd;
    sh = b3[c] - mean * sc;

    float s3 = 0.f, ss3 = 0.f;
#pragma unroll
    for (int i = 0; i < 4; ++i) {
        float4 q = v[i];
        q.x = q.x * sc + sh; q.y = q.y * sc + sh;
        q.z = q.z * sc + sh; q.w = q.w * sc + sh;
        op[t + i * 256] = q;
        s3 += q.x + q.y + q.z + q.w;
        ss3 += q.x * q.x + q.y * q.y + q.z * q.z + q.w * q.w;
    }
#pragma unroll
    for (int off = 32; off > 0; off >>= 1) {
        s3  += __shfl_xor(s3, off);
        ss3 += __shfl_xor(ss3, off);
    }
    __syncthreads();
    if ((t & 63) == 0) { red[wid] = s3; red[4 + wid] = ss3; }
    __syncthreads();
    if (t == 0) {
        s3  = red[0] + red[1] + red[2] + red[3];
        ss3 = red[4] + red[5] + red[6] + red[7];
        const float m3 = s3 * (1.f / HW);
        const float v3 = ss3 * (1.f / HW) - m3 * m3;
        const float r3 = rsqrtf(v3 + 1e-5f);
        const float sc1 = g1n[c] * r3;
        stout[p * 2]     = sc1;
        stout[p * 2 + 1] = b1n[c] - m3 * sc1;
    }
}

// ---------- fused GN3 + RK update; emits GN1 stats of written next-input ---
// mode 0: acc = y + ca*k ; yt = y + cy*k   (yt -> kin buffer)
// mode 1: acc += ca*k    ; yt = y + cy*k
// mode 2: y = acc + ca*k
__global__ __launch_bounds__(256)
void gnrk_kernel(float* __restrict__ kin,
                 const float* __restrict__ g, const float* __restrict__ bt,
                 float* __restrict__ y, float* __restrict__ acc,
                 float ca, float cy, int mode,
                 const float* __restrict__ g1n, const float* __restrict__ b1n,
                 float* __restrict__ stout)
{
    const int p = blockIdx.x;
    const int c = p & 31;
    const int t = threadIdx.x;
    float4* kp = (float4*)(kin + (size_t)p * HW);
    float4* yp = (float4*)(y   + (size_t)p * HW);
    float4* ap = (float4*)(acc + (size_t)p * HW);
    __shared__ float red[8];
    const int wid = t >> 6;

    float4 v[4];
    float s = 0.f, ss = 0.f;
#pragma unroll
    for (int i = 0; i < 4; ++i) {
        float4 q = kp[t + i * 256];
        v[i] = q;
        s += q.x + q.y + q.z + q.w;
        ss += q.x * q.x + q.y * q.y + q.z * q.z + q.w * q.w;
    }
#pragma unroll
    for (int off = 32; off > 0; off >>= 1) {
        s  += __shfl_xor(s, off);
        ss += __shfl_xor(ss, off);
    }
    if ((t & 63) == 0) { red[wid] = s; red[4 + wid] = ss; }
    __syncthreads();
    s  = red[0] + red[1] + red[2] + red[3];
    ss = red[4] + red[5] + red[6] + red[7];
    const float mean = s * (1.f / HW);
    const float var  = ss * (1.f / HW) - mean * mean;
    const float rstd = rsqrtf(var + 1e-5f);
    const float sc = g[c] * rstd;
    const float sh = bt[c] - mean * sc;

    float s2 = 0.f, ss2 = 0.f;
#pragma unroll
    for (int i = 0; i < 4; ++i) {
        float4 kq = v[i];
        kq.x = kq.x * sc + sh; kq.y = kq.y * sc + sh;
        kq.z = kq.z * sc + sh; kq.w = kq.w * sc + sh;
        const int idx = t + i * 256;
        float4 w;
        if (mode == 2) {
            float4 av = ap[idx];
            w.x = av.x + ca * kq.x; w.y = av.y + ca * kq.y;
            w.z = av.z + ca * kq.z; w.w = av.w + ca * kq.w;
            yp[idx] = w;
        } else {
            float4 yv = yp[idx];
            float4 av;
            if (mode == 0) {
                av.x = yv.x + ca * kq.x; av.y = yv.y + ca * kq.y;
                av.z = yv.z + ca * kq.z; av.w = yv.w + ca * kq.w;
            } else {
                av = ap[idx];
                av.x += ca * kq.x; av.y += ca * kq.y;
                av.z += ca * kq.z; av.w += ca * kq.w;
            }
            ap[idx] = av;
            w.x = yv.x + cy * kq.x; w.y = yv.y + cy * kq.y;
            w.z = yv.z + cy * kq.z; w.w = yv.w + cy * kq.w;
            kp[idx] = w;
        }
        s2  += w.x + w.y + w.z + w.w;
        ss2 += w.x * w.x + w.y * w.y + w.z * w.z + w.w * w.w;
    }
#pragma unroll
    for (int off = 32; off > 0; off >>= 1) {
        s2  += __shfl_xor(s2, off);
        ss2 += __shfl_xor(ss2, off);
    }
    __syncthreads();
    if ((t & 63) == 0) { red[wid] = s2; red[4 + wid] = ss2; }
    __syncthreads();
    if (t == 0) {
        s2  = red[0] + red[1] + red[2] + red[3];
        ss2 = red[4] + red[5] + red[6] + red[7];
        const float m2 = s2 * (1.f / HW);
        const float v2 = ss2 * (1.f / HW) - m2 * m2;
        const float r2 = rsqrtf(v2 + 1e-5f);
        const float sc1 = g1n[c] * r2;
        stout[p * 2]     = sc1;
        stout[p * 2 + 1] = b1n[c] - m2 * sc1;
    }
}

extern "C" void kernel_launch(void* const* d_in, const int* in_sizes, int n_in,
                              void* d_out, int out_size, void* d_ws, size_t ws_size,
                              hipStream_t stream) {
    (void)in_sizes; (void)n_in; (void)out_size; (void)ws_size;
    const float* x      = (const float*)d_in[0];
    const float* ai_g1  = (const float*)d_in[1];
    const float* ai_b1  = (const float*)d_in[2];
    const float* ai_w   = (const float*)d_in[3];
    const float* ai_cb  = (const float*)d_in[4];
    const float* ai_g2  = (const float*)d_in[5];
    const float* ai_b2  = (const float*)d_in[6];
    const float* ai_g3  = (const float*)d_in[7];
    const float* ai_b3  = (const float*)d_in[8];
    const float* of_g1  = (const float*)d_in[9];
    const float* of_b1  = (const float*)d_in[10];
    const float* of_w1  = (const float*)d_in[11];
    const float* of_cb1 = (const float*)d_in[12];
    const float* of_g2  = (const float*)d_in[13];
    const float* of_b2  = (const float*)d_in[14];
    const float* of_w2  = (const float*)d_in[15];
    const float* of_cb2 = (const float*)d_in[16];
    const float* of_g3  = (const float*)d_in[17];
    const float* of_b3  = (const float*)d_in[18];

    float* y = (float*)d_out;                         // (256,32,64,64)
    const size_t N  = (size_t)256 * 32 * 64 * 64;
    const size_t NH = N / 2;
    float* ws  = (float*)d_ws;
    float* A     = ws;                 // conv1 out / conv2 in
    float* YT    = ws + N;             // stage input / conv2 out
    float* ACC   = ws + 2 * N;         // RK accumulator
    float* tail  = ws + 3 * N;
    float* ST1   = tail;               tail += 16384;   // GN1 stats (8192 planes)
    float* ST2   = tail;               tail += 16384;   // GN2 stats
    float* ST_AI = tail;               tail += 8192;    // atten GN1 stats (4096)
    float* STRAW = tail;               tail += 262144;  // per-block partials
    float* WPai  = tail;               tail += 9216;
    float* WP1   = tail;               tail += 9504;
    float* WP2   = tail;               tail += 9504;

    const float h = 0.125f;

    prep_kernel<<<1, 256, 0, stream>>>(ai_w, of_w1, of_w2, WPai, WP1, WP2);

    // ---- atten_init (batch 128) ----
    stats_kernel<<<4096, 256, 0, stream>>>(x, ST_AI, ai_g1, ai_b1);
    conv_kernel<0, 0><<<2048, 256, 0, stream>>>(x, A, ST_AI, WPai, ai_cb, 0.f, nullptr);
    dgn_kernel<<<4096, 256, 0, stream>>>(A, y + NH, ai_g2, ai_b2, ai_g3, ai_b3,
                                         of_g1, of_b1, ST1 + 8192);
    stats_kernel<<<4096, 256, 0, stream>>>(x, ST1, of_g1, of_b1);
    hipMemcpyAsync(y, x, NH * sizeof(float), hipMemcpyDeviceToDevice, stream);

    auto eval = [&](const float* yin, float tv, float ca, float cy, int mode) {
        conv_kernel<1, 1><<<4096, 256, 0, stream>>>(yin, A, ST1, WP1, of_cb1, tv, STRAW);
        finalize_kernel<<<32, 256, 0, stream>>>(STRAW, ST2, of_g2, of_b2);
        conv_kernel<1, 0><<<4096, 256, 0, stream>>>(A, YT, ST2, WP2, of_cb2, tv, nullptr);
        gnrk_kernel<<<8192, 256, 0, stream>>>(YT, of_g3, of_b3, y, ACC, ca, cy, mode,
                                              of_g1, of_b1, ST1);
    };

    for (int s = 0; s < 8; ++s) {
        const float t0 = h * (float)s;
        eval(y,  t0,            h / 6.f, 0.5f * h, 0);   // k1
        eval(YT, t0 + 0.5f * h, h / 3.f, 0.5f * h, 1);   // k2
        eval(YT, t0 + 0.5f * h, h / 3.f, h,        1);   // k3
        eval(YT, t0 + h,        h / 6.f, 0.f,      2);   // k4
    }
}

// Round 4
// 9526.147 us; speedup vs baseline: 3.1015x; 2.6805x over previous
//
#include <hip/hip_runtime.h>

#define HW 4096            // 64*64
#define CIN 32

typedef __bf16 bf16x8 __attribute__((ext_vector_type(8)));
typedef float  f32x4  __attribute__((ext_vector_type(4)));
typedef unsigned short ushort8_v __attribute__((ext_vector_type(8)));

__device__ __forceinline__ unsigned short f2b(float f) {
    unsigned int u = __builtin_bit_cast(unsigned int, f);
    unsigned int r = (u + 0x7FFFu + ((u >> 16) & 1u)) >> 16;
    return (unsigned short)r;
}
__device__ __forceinline__ float b2f(unsigned short s) {
    unsigned int u = ((unsigned int)s) << 16;
    return __builtin_bit_cast(float, u);
}
__device__ __forceinline__ bf16x8 ld_frag(const unsigned short* p) {
    ushort8_v u = *(const ushort8_v*)p;
    return __builtin_bit_cast(bf16x8, u);
}

// ---------- weight prep -----------------------------------------------------
// WP layout: [tap s][oc][ci40] bf16 (ci = image channel, pad 40, zeros in pad).
// Tcls[oc][9]: time-channel tap-sums per (row-class, col-class).
__global__ __launch_bounds__(256)
void prep_kernel(const float* __restrict__ ai_w,
                 const float* __restrict__ of_w1,
                 const float* __restrict__ of_w2,
                 unsigned short* __restrict__ wp_ai,
                 unsigned short* __restrict__ wp1,
                 unsigned short* __restrict__ wp2,
                 float* __restrict__ tc1, float* __restrict__ tc2)
{
    const int t = threadIdx.x;
    for (int i = t; i < 9 * 32 * 40; i += 256) {
        const int s = i / 1280;
        const int rem = i - s * 1280;
        const int oc = rem / 40;
        const int ci = rem - oc * 40;
        unsigned short va = 0, v1 = 0, v2 = 0;
        if (ci < 32) {
            va = f2b(ai_w[(oc * 32 + ci) * 9 + s]);
            v1 = f2b(of_w1[(oc * 33 + ci + 1) * 9 + s]);
            v2 = f2b(of_w2[(oc * 33 + ci + 1) * 9 + s]);
        }
        wp_ai[i] = va; wp1[i] = v1; wp2[i] = v2;
    }
    for (int i = t; i < 32 * 9; i += 256) {
        const int oc = i / 9;
        const int cls = i - oc * 9;
        const int rc = cls / 3, cc = cls - rc * 3;
        float s1 = 0.f, s2 = 0.f;
        for (int ky = 0; ky < 3; ++ky) {
            if ((rc == 0 && ky == 0) || (rc == 2 && ky == 2)) continue;
            for (int kx = 0; kx < 3; ++kx) {
                if ((cc == 0 && kx == 0) || (cc == 2 && kx == 2)) continue;
                s1 += of_w1[(oc * 33) * 9 + ky * 3 + kx];
                s2 += of_w2[(oc * 33) * 9 + ky * 3 + kx];
            }
        }
        tc1[i] = s1; tc2[i] = s2;
    }
}

// ---------- per-plane GN stats (fp32 input) --------------------------------
__global__ __launch_bounds__(256)
void stats_kernel(const float* __restrict__ in, float* __restrict__ st,
                  const float* __restrict__ gamma, const float* __restrict__ beta)
{
    const int p = blockIdx.x;
    const int c = p & 31;
    const int t = threadIdx.x;
    const float4* ip = (const float4*)(in + (size_t)p * HW);
    float s = 0.f, ss = 0.f;
#pragma unroll
    for (int i = 0; i < 4; ++i) {
        float4 q = ip[t + i * 256];
        s += q.x + q.y + q.z + q.w;
        ss += q.x * q.x + q.y * q.y + q.z * q.z + q.w * q.w;
    }
#pragma unroll
    for (int off = 32; off > 0; off >>= 1) {
        s  += __shfl_xor(s, off);
        ss += __shfl_xor(ss, off);
    }
    __shared__ float red[8];
    const int wid = t >> 6;
    if ((t & 63) == 0) { red[wid] = s; red[4 + wid] = ss; }
    __syncthreads();
    if (t == 0) {
        s  = red[0] + red[1] + red[2] + red[3];
        ss = red[4] + red[5] + red[6] + red[7];
        const float mean = s * (1.f / HW);
        const float var  = ss * (1.f / HW) - mean * mean;
        const float rstd = rsqrtf(var + 1e-5f);
        const float sc = gamma[c] * rstd;
        st[p * 2]     = sc;
        st[p * 2 + 1] = beta[c] - mean * sc;
    }
}

// ---------- x init: y = x (fp32) ; XB = bf16(x) ----------------------------
__global__ __launch_bounds__(256)
void xcopy_kernel(const float* __restrict__ x, float* __restrict__ y,
                  unsigned short* __restrict__ xb)
{
    const int i = blockIdx.x * 256 + threadIdx.x;
    const float4 v = ((const float4*)x)[i];
    ((float4*)y)[i] = v;
    ushort4 u; u.x = f2b(v.x); u.y = f2b(v.y); u.z = f2b(v.z); u.w = f2b(v.w);
    ((ushort4*)xb)[i] = u;
}

// ---------- MFMA implicit-GEMM conv 3x3 ------------------------------------
// Input: bf16 raw tensor + per-plane GN (sc,sh); GN+ReLU applied at staging.
// Block: 256 thr = 4 waves; wave = one output row (h0+wid), 32 oc x 64 w.
// K = 9 taps x 32 ci; one mfma_16x16x32 per (Mtile,Ntile,tap).
template<int HAS_TIME, int STATS, int OUT_BF16>
__global__ __launch_bounds__(256)
void conv_kernel(const unsigned short* __restrict__ in, void* __restrict__ outv,
                 const float* __restrict__ st, const unsigned short* __restrict__ wp,
                 const float* __restrict__ cb, const float* __restrict__ tcls,
                 float tval, float* __restrict__ straw)
{
    const int blk = blockIdx.x;
    const int b  = blk >> 4;
    const int hb = blk & 15;
    const int h0 = hb * 4;
    const int t  = threadIdx.x;
    const int l  = t & 63;
    const int wid = t >> 6;
    const int m = l & 15;
    const int g = l >> 4;

    __shared__ unsigned short tile[6 * 66 * 40];   // [r][w''][ci40]
    __shared__ unsigned short wlds[9 * 32 * 40];   // [tap][oc][ci40]
    __shared__ float biasL[32];
    __shared__ float tclsL[288];
    __shared__ float sredS[128], sredSS[128];

    // ---- stage weights (b128 copies) ----
    for (int i = t; i < 1440; i += 256)
        ((ushort8_v*)wlds)[i] = ((const ushort8_v*)wp)[i];
    if (t < 32) biasL[t] = cb[t];
    if (HAS_TIME) for (int i = t; i < 288; i += 256) tclsL[i] = tcls[i];

    // ---- zero pad columns w''=0,65 ----
    for (int i = t; i < 480; i += 256) {
        const int r = i / 80;
        const int rem = i - r * 80;
        const int col = (rem < 40) ? 0 : 65;
        const int ci = (rem < 40) ? rem : rem - 40;
        tile[(r * 66 + col) * 40 + ci] = 0;
    }

    // ---- stage normalized input tile: 6 rows x 64 w x 32 ci ----
    const unsigned short* inb = in + (size_t)b * (CIN * HW);
    for (int i = t; i < 3072; i += 256) {
        const int w4 = (i & 15) * 4;
        const int ci = (i >> 4) & 31;
        const int r  = i >> 9;
        const int hh = h0 - 1 + r;
        unsigned short o0 = 0, o1 = 0, o2 = 0, o3 = 0;
        if (hh >= 0 && hh < 64) {
            const ushort4 u = *(const ushort4*)(inb + (size_t)ci * HW + hh * 64 + w4);
            const float2 scsh = *(const float2*)(st + (size_t)(b * 32 + ci) * 2);
            o0 = f2b(fmaxf(b2f(u.x) * scsh.x + scsh.y, 0.f));
            o1 = f2b(fmaxf(b2f(u.y) * scsh.x + scsh.y, 0.f));
            o2 = f2b(fmaxf(b2f(u.z) * scsh.x + scsh.y, 0.f));
            o3 = f2b(fmaxf(b2f(u.w) * scsh.x + scsh.y, 0.f));
        }
        unsigned short* dst = &tile[(r * 66 + w4 + 1) * 40 + ci];
        dst[0] = o0; dst[40] = o1; dst[80] = o2; dst[120] = o3;
    }
    __syncthreads();

    // ---- K loop: 9 taps, mfma 16x16x32 ----
    f32x4 acc[2][4];
#pragma unroll
    for (int mt = 0; mt < 2; ++mt)
#pragma unroll
        for (int nt = 0; nt < 4; ++nt) acc[mt][nt] = (f32x4){0.f, 0.f, 0.f, 0.f};

    const int aoff0 = (0 * 16 + m) * 40 + 8 * g;
    const int aoff1 = (1 * 16 + m) * 40 + 8 * g;
    int boff[4];
#pragma unroll
    for (int nt = 0; nt < 4; ++nt)
        boff[nt] = ((wid * 66) + nt * 16 + m) * 40 + 8 * g;

#pragma unroll
    for (int s = 0; s < 9; ++s) {
        const int ky = s / 3, kx = s - ky * 3;
        const int toff = (ky * 66 + kx) * 40;
        const bf16x8 a0 = ld_frag(&wlds[aoff0 + s * 1280]);
        const bf16x8 a1 = ld_frag(&wlds[aoff1 + s * 1280]);
        bf16x8 bf[4];
#pragma unroll
        for (int nt = 0; nt < 4; ++nt) bf[nt] = ld_frag(&tile[boff[nt] + toff]);
#pragma unroll
        for (int nt = 0; nt < 4; ++nt) {
            acc[0][nt] = __builtin_amdgcn_mfma_f32_16x16x32_bf16(a0, bf[nt], acc[0][nt], 0, 0, 0);
            acc[1][nt] = __builtin_amdgcn_mfma_f32_16x16x32_bf16(a1, bf[nt], acc[1][nt], 0, 0, 0);
        }
    }

    // ---- epilogue: bias + time-channel + store + optional stats ----
    const int h = h0 + wid;
    const int rc = (h == 0) ? 0 : ((h == 63) ? 2 : 1);
    float sl[2][4], ssl[2][4];
    if (STATS) {
#pragma unroll
        for (int mt = 0; mt < 2; ++mt)
#pragma unroll
            for (int r = 0; r < 4; ++r) { sl[mt][r] = 0.f; ssl[mt][r] = 0.f; }
    }
    float* outf = (float*)outv;
    unsigned short* outb = (unsigned short*)outv;
#pragma unroll
    for (int mt = 0; mt < 2; ++mt) {
#pragma unroll
        for (int nt = 0; nt < 4; ++nt) {
            const int w = nt * 16 + m;
            const int cc = (w == 0) ? 0 : ((w == 63) ? 2 : 1);
#pragma unroll
            for (int r = 0; r < 4; ++r) {
                const int oc = mt * 16 + g * 4 + r;
                float v = acc[mt][nt][r] + biasL[oc];
                if (HAS_TIME) v += tval * tclsL[oc * 9 + rc * 3 + cc];
                const size_t o = ((size_t)(b * 32 + oc)) * HW + (size_t)h * 64 + w;
                if (OUT_BF16) outb[o] = f2b(v); else outf[o] = v;
                if (STATS) { sl[mt][r] += v; ssl[mt][r] += v * v; }
            }
        }
    }
    if (STATS) {
#pragma unroll
        for (int mt = 0; mt < 2; ++mt)
#pragma unroll
            for (int r = 0; r < 4; ++r) {
                float s = sl[mt][r], q = ssl[mt][r];
#pragma unroll
                for (int off = 1; off < 16; off <<= 1) {
                    s += __shfl_xor(s, off);
                    q += __shfl_xor(q, off);
                }
                if (m == 0) {
                    const int oc = mt * 16 + g * 4 + r;
                    sredS[wid * 32 + oc] = s;
                    sredSS[wid * 32 + oc] = q;
                }
            }
        __syncthreads();
        if (t < 32) {
            const float s = sredS[t] + sredS[32 + t] + sredS[64 + t] + sredS[96 + t];
            const float q = sredSS[t] + sredSS[32 + t] + sredSS[64 + t] + sredSS[96 + t];
            float* dst = straw + ((size_t)(b * 32 + t) * 16 + hb) * 2;
            dst[0] = s; dst[1] = q;
        }
    }
}

// ---------- stats finalize: 16 per-block partials -> (sc, sh) --------------
__global__ __launch_bounds__(256)
void finalize_kernel(const float* __restrict__ straw, float* __restrict__ st,
                     const float* __restrict__ g, const float* __restrict__ bt)
{
    const int p = blockIdx.x * 256 + threadIdx.x;   // 8192 planes
    const int c = p & 31;
    const float* sp = straw + (size_t)p * 32;
    float s = 0.f, ss = 0.f;
#pragma unroll
    for (int i = 0; i < 16; ++i) { s += sp[2 * i]; ss += sp[2 * i + 1]; }
    const float mean = s * (1.f / HW);
    const float var  = ss * (1.f / HW) - mean * mean;
    const float rstd = rsqrtf(var + 1e-5f);
    const float sc = g[c] * rstd;
    st[p * 2]     = sc;
    st[p * 2 + 1] = bt[c] - mean * sc;
}

// ---------- atten_init tail: gn2+relu -> gn3; fp32 + bf16 out + GN1 stats --
__global__ __launch_bounds__(256)
void dgn_kernel(const float* __restrict__ in, float* __restrict__ out,
                unsigned short* __restrict__ xbout,
                const float* __restrict__ g2, const float* __restrict__ b2,
                const float* __restrict__ g3, const float* __restrict__ b3,
                const float* __restrict__ g1n, const float* __restrict__ b1n,
                float* __restrict__ stout)
{
    const int p = blockIdx.x;
    const int c = p & 31;
    const int t = threadIdx.x;
    const float4* ip = (const float4*)(in + (size_t)p * HW);
    float4* op = (float4*)(out + (size_t)p * HW);
    ushort4* xp = (ushort4*)(xbout + (size_t)p * HW);
    __shared__ float red[8];
    const int wid = t >> 6;

    float4 v[4];
    float s = 0.f, ss = 0.f;
#pragma unroll
    for (int i = 0; i < 4; ++i) {
        float4 q = ip[t + i * 256];
        v[i] = q;
        s += q.x + q.y + q.z + q.w;
        ss += q.x * q.x + q.y * q.y + q.z * q.z + q.w * q.w;
    }
#pragma unroll
    for (int off = 32; off > 0; off >>= 1) {
        s  += __shfl_xor(s, off);
        ss += __shfl_xor(ss, off);
    }
    if ((t & 63) == 0) { red[wid] = s; red[4 + wid] = ss; }
    __syncthreads();
    s  = red[0] + red[1] + red[2] + red[3];
    ss = red[4] + red[5] + red[6] + red[7];
    float mean = s * (1.f / HW);
    float var  = ss * (1.f / HW) - mean * mean;
    float rstd = rsqrtf(var + 1e-5f);
    float sc = g2[c] * rstd;
    float sh = b2[c] - mean * sc;

    s = 0.f; ss = 0.f;
#pragma unroll
    for (int i = 0; i < 4; ++i) {
        float4 q = v[i];
        q.x = fmaxf(q.x * sc + sh, 0.f); q.y = fmaxf(q.y * sc + sh, 0.f);
        q.z = fmaxf(q.z * sc + sh, 0.f); q.w = fmaxf(q.w * sc + sh, 0.f);
        v[i] = q;
        s += q.x + q.y + q.z + q.w;
        ss += q.x * q.x + q.y * q.y + q.z * q.z + q.w * q.w;
    }
#pragma unroll
    for (int off = 32; off > 0; off >>= 1) {
        s  += __shfl_xor(s, off);
        ss += __shfl_xor(ss, off);
    }
    __syncthreads();
    if ((t & 63) == 0) { red[wid] = s; red[4 + wid] = ss; }
    __syncthreads();
    s  = red[0] + red[1] + red[2] + red[3];
    ss = red[4] + red[5] + red[6] + red[7];
    mean = s * (1.f / HW);
    var  = ss * (1.f / HW) - mean * mean;
    rstd = rsqrtf(var + 1e-5f);
    sc = g3[c] * rstd;
    sh = b3[c] - mean * sc;

    float s3 = 0.f, ss3 = 0.f;
#pragma unroll
    for (int i = 0; i < 4; ++i) {
        float4 q = v[i];
        q.x = q.x * sc + sh; q.y = q.y * sc + sh;
        q.z = q.z * sc + sh; q.w = q.w * sc + sh;
        op[t + i * 256] = q;
        ushort4 u; u.x = f2b(q.x); u.y = f2b(q.y); u.z = f2b(q.z); u.w = f2b(q.w);
        xp[t + i * 256] = u;
        s3 += q.x + q.y + q.z + q.w;
        ss3 += q.x * q.x + q.y * q.y + q.z * q.z + q.w * q.w;
    }
#pragma unroll
    for (int off = 32; off > 0; off >>= 1) {
        s3  += __shfl_xor(s3, off);
        ss3 += __shfl_xor(ss3, off);
    }
    __syncthreads();
    if ((t & 63) == 0) { red[wid] = s3; red[4 + wid] = ss3; }
    __syncthreads();
    if (t == 0) {
        s3  = red[0] + red[1] + red[2] + red[3];
        ss3 = red[4] + red[5] + red[6] + red[7];
        const float m3 = s3 * (1.f / HW);
        const float v3 = ss3 * (1.f / HW) - m3 * m3;
        const float r3 = rsqrtf(v3 + 1e-5f);
        const float sc1 = g1n[c] * r3;
        stout[p * 2]     = sc1;
        stout[p * 2 + 1] = b1n[c] - m3 * sc1;
    }
}

// ---------- fused GN3 + RK update; writes bf16 next-stage input + GN1 stats
// mode 0: acc = y + ca*k ; w = y + cy*k -> XB
// mode 1: acc += ca*k    ; w = y + cy*k -> XB
// mode 2: y = acc + ca*k ; w = y_new    -> XB
__global__ __launch_bounds__(256)
void gnrk_kernel(const float* __restrict__ kin,
                 const float* __restrict__ g, const float* __restrict__ bt,
                 float* __restrict__ y, float* __restrict__ acc,
                 float ca, float cy, int mode,
                 const float* __restrict__ g1n, const float* __restrict__ b1n,
                 float* __restrict__ stout, unsigned short* __restrict__ xb)
{
    const int p = blockIdx.x;
    const int c = p & 31;
    const int t = threadIdx.x;
    const float4* kp = (const float4*)(kin + (size_t)p * HW);
    float4* yp = (float4*)(y   + (size_t)p * HW);
    float4* ap = (float4*)(acc + (size_t)p * HW);
    ushort4* xp = (ushort4*)(xb + (size_t)p * HW);
    __shared__ float red[8];
    const int wid = t >> 6;

    float4 v[4];
    float s = 0.f, ss = 0.f;
#pragma unroll
    for (int i = 0; i < 4; ++i) {
        float4 q = kp[t + i * 256];
        v[i] = q;
        s += q.x + q.y + q.z + q.w;
        ss += q.x * q.x + q.y * q.y + q.z * q.z + q.w * q.w;
    }
#pragma unroll
    for (int off = 32; off > 0; off >>= 1) {
        s  += __shfl_xor(s, off);
        ss += __shfl_xor(ss, off);
    }
    if ((t & 63) == 0) { red[wid] = s; red[4 + wid] = ss; }
    __syncthreads();
    s  = red[0] + red[1] + red[2] + red[3];
    ss = red[4] + red[5] + red[6] + red[7];
    const float mean = s * (1.f / HW);
    const float var  = ss * (1.f / HW) - mean * mean;
    const float rstd = rsqrtf(var + 1e-5f);
    const float sc = g[c] * rstd;
    const float sh = bt[c] - mean * sc;

    float s2 = 0.f, ss2 = 0.f;
#pragma unroll
    for (int i = 0; i < 4; ++i) {
        float4 kq = v[i];
        kq.x = kq.x * sc + sh; kq.y = kq.y * sc + sh;
        kq.z = kq.z * sc + sh; kq.w = kq.w * sc + sh;
        const int idx = t + i * 256;
        float4 w;
        if (mode == 2) {
            float4 av = ap[idx];
            w.x = av.x + ca * kq.x; w.y = av.y + ca * kq.y;
            w.z = av.z + ca * kq.z; w.w = av.w + ca * kq.w;
            yp[idx] = w;
        } else {
            float4 yv = yp[idx];
            float4 av;
            if (mode == 0) {
                av.x = yv.x + ca * kq.x; av.y = yv.y + ca * kq.y;
                av.z = yv.z + ca * kq.z; av.w = yv.w + ca * kq.w;
            } else {
                av = ap[idx];
                av.x += ca * kq.x; av.y += ca * kq.y;
                av.z += ca * kq.z; av.w += ca * kq.w;
            }
            ap[idx] = av;
            w.x = yv.x + cy * kq.x; w.y = yv.y + cy * kq.y;
            w.z = yv.z + cy * kq.z; w.w = yv.w + cy * kq.w;
        }
        ushort4 u; u.x = f2b(w.x); u.y = f2b(w.y); u.z = f2b(w.z); u.w = f2b(w.w);
        xp[idx] = u;
        s2  += w.x + w.y + w.z + w.w;
        ss2 += w.x * w.x + w.y * w.y + w.z * w.z + w.w * w.w;
    }
#pragma unroll
    for (int off = 32; off > 0; off >>= 1) {
        s2  += __shfl_xor(s2, off);
        ss2 += __shfl_xor(ss2, off);
    }
    __syncthreads();
    if ((t & 63) == 0) { red[wid] = s2; red[4 + wid] = ss2; }
    __syncthreads();
    if (t == 0) {
        s2  = red[0] + red[1] + red[2] + red[3];
        ss2 = red[4] + red[5] + red[6] + red[7];
        const float m2 = s2 * (1.f / HW);
        const float v2 = ss2 * (1.f / HW) - m2 * m2;
        const float r2 = rsqrtf(v2 + 1e-5f);
        const float sc1 = g1n[c] * r2;
        stout[p * 2]     = sc1;
        stout[p * 2 + 1] = b1n[c] - m2 * sc1;
    }
}

extern "C" void kernel_launch(void* const* d_in, const int* in_sizes, int n_in,
                              void* d_out, int out_size, void* d_ws, size_t ws_size,
                              hipStream_t stream) {
    (void)in_sizes; (void)n_in; (void)out_size; (void)ws_size;
    const float* x      = (const float*)d_in[0];
    const float* ai_g1  = (const float*)d_in[1];
    const float* ai_b1  = (const float*)d_in[2];
    const float* ai_w   = (const float*)d_in[3];
    const float* ai_cb  = (const float*)d_in[4];
    const float* ai_g2  = (const float*)d_in[5];
    const float* ai_b2  = (const float*)d_in[6];
    const float* ai_g3  = (const float*)d_in[7];
    const float* ai_b3  = (const float*)d_in[8];
    const float* of_g1  = (const float*)d_in[9];
    const float* of_b1  = (const float*)d_in[10];
    const float* of_w1  = (const float*)d_in[11];
    const float* of_cb1 = (const float*)d_in[12];
    const float* of_g2  = (const float*)d_in[13];
    const float* of_b2  = (const float*)d_in[14];
    const float* of_w2  = (const float*)d_in[15];
    const float* of_cb2 = (const float*)d_in[16];
    const float* of_g3  = (const float*)d_in[17];
    const float* of_b3  = (const float*)d_in[18];

    float* y = (float*)d_out;                         // (256,32,64,64) fp32
    const size_t N  = (size_t)256 * 32 * 64 * 64;
    const size_t NH = N / 2;
    float* ws = (float*)d_ws;
    float* YT  = ws;                      // conv2 out (fp32)
    float* ACC = ws + N;                  // RK accumulator (fp32)
    unsigned short* Abf = (unsigned short*)(ws + 2 * N);         // conv1 out (bf16)
    unsigned short* XB  = (unsigned short*)(ws + 2 * N + N / 2); // stage input (bf16)
    float* tail  = ws + 3 * N;
    float* ST1   = tail;                tail += 16384;
    float* ST2   = tail;                tail += 16384;
    float* ST_AI = tail;                tail += 8192;
    float* STRAW = tail;                tail += 262144;
    unsigned short* WPai = (unsigned short*)tail;  tail += 5760;   // 9*32*40 bf16
    unsigned short* WP1  = (unsigned short*)tail;  tail += 5760;
    unsigned short* WP2  = (unsigned short*)tail;  tail += 5760;
    float* TC1  = tail;                 tail += 288;
    float* TC2  = tail;                 tail += 288;

    const float h = 0.125f;

    prep_kernel<<<1, 256, 0, stream>>>(ai_w, of_w1, of_w2, WPai, WP1, WP2, TC1, TC2);

    // ---- atten_init (batch 128) ----
    stats_kernel<<<4096, 256, 0, stream>>>(x, ST_AI, ai_g1, ai_b1);
    xcopy_kernel<<<16384, 256, 0, stream>>>(x, y, XB);   // lower half: y=x, XB=bf16(x)
    conv_kernel<0, 0, 0><<<2048, 256, 0, stream>>>(XB, YT, ST_AI, WPai, ai_cb,
                                                   nullptr, 0.f, nullptr);
    stats_kernel<<<4096, 256, 0, stream>>>(x, ST1, of_g1, of_b1);
    dgn_kernel<<<4096, 256, 0, stream>>>(YT, y + NH, XB + NH, ai_g2, ai_b2,
                                         ai_g3, ai_b3, of_g1, of_b1, ST1 + 8192);

    auto eval = [&](float tv, float ca, float cy, int mode) {
        conv_kernel<1, 1, 1><<<4096, 256, 0, stream>>>(XB, Abf, ST1, WP1, of_cb1,
                                                       TC1, tv, STRAW);
        finalize_kernel<<<32, 256, 0, stream>>>(STRAW, ST2, of_g2, of_b2);
        conv_kernel<1, 0, 0><<<4096, 256, 0, stream>>>(Abf, YT, ST2, WP2, of_cb2,
                                                       TC2, tv, nullptr);
        gnrk_kernel<<<8192, 256, 0, stream>>>(YT, of_g3, of_b3, y, ACC, ca, cy, mode,
                                              of_g1, of_b1, ST1, XB);
    };

    for (int s = 0; s < 8; ++s) {
        const float t0 = h * (float)s;
        eval(t0,            h / 6.f, 0.5f * h, 0);   // k1
        eval(t0 + 0.5f * h, h / 3.f, 0.5f * h, 1);   // k2
        eval(t0 + 0.5f * h, h / 3.f, h,        1);   // k3
        eval(t0 + h,        h / 6.f, 0.f,      2);   // k4
    }
}

// Round 5
// 7003.415 us; speedup vs baseline: 4.2187x; 1.3602x over previous
//
#include <hip/hip_runtime.h>

#define HW 4096            // 64*64
#define CIN 32

typedef __bf16 bf16x8 __attribute__((ext_vector_type(8)));
typedef float  f32x4  __attribute__((ext_vector_type(4)));
typedef unsigned short ushort8_v __attribute__((ext_vector_type(8)));

__device__ __forceinline__ unsigned short f2b(float f) {
    unsigned int u = __builtin_bit_cast(unsigned int, f);
    unsigned int r = (u + 0x7FFFu + ((u >> 16) & 1u)) >> 16;
    return (unsigned short)r;
}
__device__ __forceinline__ float b2f(unsigned short s) {
    unsigned int u = ((unsigned int)s) << 16;
    return __builtin_bit_cast(float, u);
}
__device__ __forceinline__ bf16x8 ld_frag(const unsigned short* p) {
    ushort8_v u = *(const ushort8_v*)p;
    return __builtin_bit_cast(bf16x8, u);
}

// ---------- weight prep: WP[tap s][oc][ci pad 40] bf16; Tcls[oc][9] --------
__global__ __launch_bounds__(256)
void prep_kernel(const float* __restrict__ ai_w,
                 const float* __restrict__ of_w1,
                 const float* __restrict__ of_w2,
                 unsigned short* __restrict__ wp_ai,
                 unsigned short* __restrict__ wp1,
                 unsigned short* __restrict__ wp2,
                 float* __restrict__ tc1, float* __restrict__ tc2)
{
    const int t = threadIdx.x;
    for (int i = t; i < 9 * 32 * 40; i += 256) {
        const int s = i / 1280;
        const int rem = i - s * 1280;
        const int oc = rem / 40;
        const int ci = rem - oc * 40;
        unsigned short va = 0, v1 = 0, v2 = 0;
        if (ci < 32) {
            va = f2b(ai_w[(oc * 32 + ci) * 9 + s]);
            v1 = f2b(of_w1[(oc * 33 + ci + 1) * 9 + s]);
            v2 = f2b(of_w2[(oc * 33 + ci + 1) * 9 + s]);
        }
        wp_ai[i] = va; wp1[i] = v1; wp2[i] = v2;
    }
    for (int i = t; i < 32 * 9; i += 256) {
        const int oc = i / 9;
        const int cls = i - oc * 9;
        const int rc = cls / 3, cc = cls - rc * 3;
        float s1 = 0.f, s2 = 0.f;
        for (int ky = 0; ky < 3; ++ky) {
            if ((rc == 0 && ky == 0) || (rc == 2 && ky == 2)) continue;
            for (int kx = 0; kx < 3; ++kx) {
                if ((cc == 0 && kx == 0) || (cc == 2 && kx == 2)) continue;
                s1 += of_w1[(oc * 33) * 9 + ky * 3 + kx];
                s2 += of_w2[(oc * 33) * 9 + ky * 3 + kx];
            }
        }
        tc1[i] = s1; tc2[i] = s2;
    }
}

// ---------- per-plane GN stats (fp32 input) --------------------------------
__global__ __launch_bounds__(256)
void stats_kernel(const float* __restrict__ in, float* __restrict__ st,
                  const float* __restrict__ gamma, const float* __restrict__ beta)
{
    const int p = blockIdx.x;
    const int c = p & 31;
    const int t = threadIdx.x;
    const float4* ip = (const float4*)(in + (size_t)p * HW);
    float s = 0.f, ss = 0.f;
#pragma unroll
    for (int i = 0; i < 4; ++i) {
        float4 q = ip[t + i * 256];
        s += q.x + q.y + q.z + q.w;
        ss += q.x * q.x + q.y * q.y + q.z * q.z + q.w * q.w;
    }
#pragma unroll
    for (int off = 32; off > 0; off >>= 1) {
        s  += __shfl_xor(s, off);
        ss += __shfl_xor(ss, off);
    }
    __shared__ float red[8];
    const int wid = t >> 6;
    if ((t & 63) == 0) { red[wid] = s; red[4 + wid] = ss; }
    __syncthreads();
    if (t == 0) {
        s  = red[0] + red[1] + red[2] + red[3];
        ss = red[4] + red[5] + red[6] + red[7];
        const float mean = s * (1.f / HW);
        const float var  = ss * (1.f / HW) - mean * mean;
        const float rstd = rsqrtf(var + 1e-5f);
        const float sc = gamma[c] * rstd;
        st[p * 2]     = sc;
        st[p * 2 + 1] = beta[c] - mean * sc;
    }
}

// ---------- x init: y = x (fp32) ; XB = bf16(x) ----------------------------
__global__ __launch_bounds__(256)
void xcopy_kernel(const float* __restrict__ x, float* __restrict__ y,
                  unsigned short* __restrict__ xb)
{
    const int i = blockIdx.x * 256 + threadIdx.x;
    const float4 v = ((const float4*)x)[i];
    ((float4*)y)[i] = v;
    ushort4 u; u.x = f2b(v.x); u.y = f2b(v.y); u.z = f2b(v.z); u.w = f2b(v.w);
    ((ushort4*)xb)[i] = u;
}

// ---------- MFMA implicit-GEMM conv 3x3 ------------------------------------
// 512 thr = 8 waves; block = (b, 8 output rows). Wave wid = one row of 64 px.
// A = pixel tile (LDS, gather-staged, GN+ReLU fused), B = weights (registers).
// acc lane: oc = l&15 (per nt), w = mt*16 + (l>>4)*4 + reg  -> vector stores.
template<int HAS_TIME, int STATS, int OUT_BF16>
__global__ __launch_bounds__(512)
void conv_kernel(const unsigned short* __restrict__ in, void* __restrict__ outv,
                 const float* __restrict__ st, const unsigned short* __restrict__ wp,
                 const float* __restrict__ cb, const float* __restrict__ tcls,
                 float tval, float* __restrict__ straw)
{
    const int blk = blockIdx.x;
    const int b  = blk >> 3;
    const int hb = blk & 7;
    const int h0 = hb * 8;
    const int t  = threadIdx.x;
    const int l  = t & 63;
    const int wid = t >> 6;            // 0..7 = output row
    const int lm = l & 15;
    const int lg = l >> 4;

    __shared__ unsigned short tile[10 * 66 * 40];   // 52800 B

    // ---- weight fragments into registers: wreg[nt][tap] ----
    bf16x8 wreg[2][9];
    {
        const unsigned short* wb = wp + (size_t)(lm * 40 + 8 * lg);
#pragma unroll
        for (int nt = 0; nt < 2; ++nt)
#pragma unroll
            for (int s = 0; s < 9; ++s)
                wreg[nt][s] = ld_frag(wb + s * 1280 + nt * 640);
    }

    // ---- gather-stage normalized input: one ds_write_b128 per task ----
    const unsigned short* inb = in + (size_t)b * (CIN * HW);
    const float* stb = st + (size_t)b * 64;
#pragma unroll
    for (int it = 0; it < 5; ++it) {
        const int tau = it * 512 + t;          // 2560 tasks = 4g x 10r x 64w
        const int g = tau / 640;
        const int rem = tau - g * 640;
        const int r = rem >> 6;
        const int w = rem & 63;
        const int hh = h0 - 1 + r;
        ushort8_v frag = {0, 0, 0, 0, 0, 0, 0, 0};
        if (hh >= 0 && hh < 64) {
            const unsigned short* src = inb + (size_t)(8 * g) * HW + hh * 64 + w;
#pragma unroll
            for (int j = 0; j < 8; ++j) {
                const float2 sc = *(const float2*)(stb + (8 * g + j) * 2);
                frag[j] = f2b(fmaxf(b2f(src[(size_t)j * HW]) * sc.x + sc.y, 0.f));
            }
        }
        *(ushort8_v*)&tile[(r * 66 + w + 1) * 40 + 8 * g] = frag;
    }
    if (t < 80) {   // zero pad columns w''=0,65
        const int g = t & 3;
        const int rr = t >> 2;
        const int r = rr >> 1;
        const int col = (rr & 1) ? 65 : 0;
        ushort8_v z = {0, 0, 0, 0, 0, 0, 0, 0};
        *(ushort8_v*)&tile[(r * 66 + col) * 40 + 8 * g] = z;
    }
    __syncthreads();

    // ---- K loop: 9 taps x 4 M-tiles, weights from regs ----
    f32x4 acc[4][2];
#pragma unroll
    for (int mt = 0; mt < 4; ++mt)
#pragma unroll
        for (int nt = 0; nt < 2; ++nt) acc[mt][nt] = (f32x4){0.f, 0.f, 0.f, 0.f};

#pragma unroll
    for (int ky = 0; ky < 3; ++ky)
#pragma unroll
        for (int kx = 0; kx < 3; ++kx) {
            const int s = ky * 3 + kx;
            const int base = ((wid + ky) * 66 + kx + lm) * 40 + 8 * lg;
#pragma unroll
            for (int mt = 0; mt < 4; ++mt) {
                const bf16x8 a = ld_frag(&tile[base + mt * 640]);
                acc[mt][0] = __builtin_amdgcn_mfma_f32_16x16x32_bf16(a, wreg[0][s], acc[mt][0], 0, 0, 0);
                acc[mt][1] = __builtin_amdgcn_mfma_f32_16x16x32_bf16(a, wreg[1][s], acc[mt][1], 0, 0, 0);
            }
        }

    // ---- epilogue ----
    const int h = h0 + wid;
    const int rc = (h == 0) ? 0 : ((h == 63) ? 2 : 1);
    float bias_[2], tcn[2], tc0[2], tc2[2];
#pragma unroll
    for (int nt = 0; nt < 2; ++nt) {
        const int oc = nt * 16 + lm;
        bias_[nt] = cb[oc];
        if (HAS_TIME) {
            tcn[nt] = tcls[oc * 9 + rc * 3 + 1];
            tc0[nt] = tcls[oc * 9 + rc * 3 + 0];
            tc2[nt] = tcls[oc * 9 + rc * 3 + 2];
        }
    }
    float sl[2] = {0.f, 0.f}, ssl[2] = {0.f, 0.f};
    float* outf = (float*)outv;
    unsigned short* outb = (unsigned short*)outv;
#pragma unroll
    for (int mt = 0; mt < 4; ++mt) {
#pragma unroll
        for (int nt = 0; nt < 2; ++nt) {
            const int oc = nt * 16 + lm;
            float v[4];
#pragma unroll
            for (int r = 0; r < 4; ++r) {
                v[r] = acc[mt][nt][r] + bias_[nt];
                if (HAS_TIME) v[r] += tval * tcn[nt];
            }
            if (HAS_TIME && mt == 0 && lg == 0) v[0] += tval * (tc0[nt] - tcn[nt]);
            if (HAS_TIME && mt == 3 && lg == 3) v[3] += tval * (tc2[nt] - tcn[nt]);
            const int w0 = mt * 16 + lg * 4;
            const size_t o = ((size_t)(b * 32 + oc)) * HW + (size_t)h * 64 + w0;
            if (OUT_BF16) {
                ushort4 u;
                u.x = f2b(v[0]); u.y = f2b(v[1]); u.z = f2b(v[2]); u.w = f2b(v[3]);
                *(ushort4*)&outb[o] = u;
            } else {
                float4 q; q.x = v[0]; q.y = v[1]; q.z = v[2]; q.w = v[3];
                *(float4*)&outf[o] = q;
            }
            if (STATS) {
#pragma unroll
                for (int r = 0; r < 4; ++r) { sl[nt] += v[r]; ssl[nt] += v[r] * v[r]; }
            }
        }
    }
    if (STATS) {
        float s0 = sl[0], q0 = ssl[0], s1 = sl[1], q1 = ssl[1];
        s0 += __shfl_xor(s0, 16); s0 += __shfl_xor(s0, 32);
        q0 += __shfl_xor(q0, 16); q0 += __shfl_xor(q0, 32);
        s1 += __shfl_xor(s1, 16); s1 += __shfl_xor(s1, 32);
        q1 += __shfl_xor(q1, 16); q1 += __shfl_xor(q1, 32);
        __syncthreads();                       // tile no longer needed
        float* red = (float*)tile;             // [0..255]=S, [256..511]=SS
        if (lg == 0) {
            red[wid * 32 + lm]       = s0;  red[256 + wid * 32 + lm]       = q0;
            red[wid * 32 + 16 + lm]  = s1;  red[256 + wid * 32 + 16 + lm]  = q1;
        }
        __syncthreads();
        if (t < 32) {
            float S = 0.f, Q = 0.f;
#pragma unroll
            for (int w = 0; w < 8; ++w) { S += red[w * 32 + t]; Q += red[256 + w * 32 + t]; }
            float* dst = straw + ((size_t)(b * 32 + t) * 8 + hb) * 2;
            dst[0] = S; dst[1] = Q;
        }
    }
}

// ---------- stats finalize: 8 per-block partials -> (sc, sh) ---------------
__global__ __launch_bounds__(256)
void finalize_kernel(const float* __restrict__ straw, float* __restrict__ st,
                     const float* __restrict__ g, const float* __restrict__ bt)
{
    const int p = blockIdx.x * 256 + threadIdx.x;   // 8192 planes
    const int c = p & 31;
    const float* sp = straw + (size_t)p * 16;
    float s = 0.f, ss = 0.f;
#pragma unroll
    for (int i = 0; i < 8; ++i) { s += sp[2 * i]; ss += sp[2 * i + 1]; }
    const float mean = s * (1.f / HW);
    const float var  = ss * (1.f / HW) - mean * mean;
    const float rstd = rsqrtf(var + 1e-5f);
    const float sc = g[c] * rstd;
    st[p * 2]     = sc;
    st[p * 2 + 1] = bt[c] - mean * sc;
}

// ---------- atten_init tail: gn2+relu -> gn3; fp32 + bf16 out + GN1 stats --
__global__ __launch_bounds__(256)
void dgn_kernel(const float* __restrict__ in, float* __restrict__ out,
                unsigned short* __restrict__ xbout,
                const float* __restrict__ g2, const float* __restrict__ b2,
                const float* __restrict__ g3, const float* __restrict__ b3,
                const float* __restrict__ g1n, const float* __restrict__ b1n,
                float* __restrict__ stout)
{
    const int p = blockIdx.x;
    const int c = p & 31;
    const int t = threadIdx.x;
    const float4* ip = (const float4*)(in + (size_t)p * HW);
    float4* op = (float4*)(out + (size_t)p * HW);
    ushort4* xp = (ushort4*)(xbout + (size_t)p * HW);
    __shared__ float red[8];
    const int wid = t >> 6;

    float4 v[4];
    float s = 0.f, ss = 0.f;
#pragma unroll
    for (int i = 0; i < 4; ++i) {
        float4 q = ip[t + i * 256];
        v[i] = q;
        s += q.x + q.y + q.z + q.w;
        ss += q.x * q.x + q.y * q.y + q.z * q.z + q.w * q.w;
    }
#pragma unroll
    for (int off = 32; off > 0; off >>= 1) {
        s  += __shfl_xor(s, off);
        ss += __shfl_xor(ss, off);
    }
    if ((t & 63) == 0) { red[wid] = s; red[4 + wid] = ss; }
    __syncthreads();
    s  = red[0] + red[1] + red[2] + red[3];
    ss = red[4] + red[5] + red[6] + red[7];
    float mean = s * (1.f / HW);
    float var  = ss * (1.f / HW) - mean * mean;
    float rstd = rsqrtf(var + 1e-5f);
    float sc = g2[c] * rstd;
    float sh = b2[c] - mean * sc;

    s = 0.f; ss = 0.f;
#pragma unroll
    for (int i = 0; i < 4; ++i) {
        float4 q = v[i];
        q.x = fmaxf(q.x * sc + sh, 0.f); q.y = fmaxf(q.y * sc + sh, 0.f);
        q.z = fmaxf(q.z * sc + sh, 0.f); q.w = fmaxf(q.w * sc + sh, 0.f);
        v[i] = q;
        s += q.x + q.y + q.z + q.w;
        ss += q.x * q.x + q.y * q.y + q.z * q.z + q.w * q.w;
    }
#pragma unroll
    for (int off = 32; off > 0; off >>= 1) {
        s  += __shfl_xor(s, off);
        ss += __shfl_xor(ss, off);
    }
    __syncthreads();
    if ((t & 63) == 0) { red[wid] = s; red[4 + wid] = ss; }
    __syncthreads();
    s  = red[0] + red[1] + red[2] + red[3];
    ss = red[4] + red[5] + red[6] + red[7];
    mean = s * (1.f / HW);
    var  = ss * (1.f / HW) - mean * mean;
    rstd = rsqrtf(var + 1e-5f);
    sc = g3[c] * rstd;
    sh = b3[c] - mean * sc;

    float s3 = 0.f, ss3 = 0.f;
#pragma unroll
    for (int i = 0; i < 4; ++i) {
        float4 q = v[i];
        q.x = q.x * sc + sh; q.y = q.y * sc + sh;
        q.z = q.z * sc + sh; q.w = q.w * sc + sh;
        op[t + i * 256] = q;
        ushort4 u; u.x = f2b(q.x); u.y = f2b(q.y); u.z = f2b(q.z); u.w = f2b(q.w);
        xp[t + i * 256] = u;
        s3 += q.x + q.y + q.z + q.w;
        ss3 += q.x * q.x + q.y * q.y + q.z * q.z + q.w * q.w;
    }
#pragma unroll
    for (int off = 32; off > 0; off >>= 1) {
        s3  += __shfl_xor(s3, off);
        ss3 += __shfl_xor(ss3, off);
    }
    __syncthreads();
    if ((t & 63) == 0) { red[wid] = s3; red[4 + wid] = ss3; }
    __syncthreads();
    if (t == 0) {
        s3  = red[0] + red[1] + red[2] + red[3];
        ss3 = red[4] + red[5] + red[6] + red[7];
        const float m3 = s3 * (1.f / HW);
        const float v3 = ss3 * (1.f / HW) - m3 * m3;
        const float r3 = rsqrtf(v3 + 1e-5f);
        const float sc1 = g1n[c] * r3;
        stout[p * 2]     = sc1;
        stout[p * 2 + 1] = b1n[c] - m3 * sc1;
    }
}

// ---------- fused GN3 + RK update; writes bf16 next-stage input + GN1 stats
__global__ __launch_bounds__(256)
void gnrk_kernel(const float* __restrict__ kin,
                 const float* __restrict__ g, const float* __restrict__ bt,
                 float* __restrict__ y, float* __restrict__ acc,
                 float ca, float cy, int mode,
                 const float* __restrict__ g1n, const float* __restrict__ b1n,
                 float* __restrict__ stout, unsigned short* __restrict__ xb)
{
    const int p = blockIdx.x;
    const int c = p & 31;
    const int t = threadIdx.x;
    const float4* kp = (const float4*)(kin + (size_t)p * HW);
    float4* yp = (float4*)(y   + (size_t)p * HW);
    float4* ap = (float4*)(acc + (size_t)p * HW);
    ushort4* xp = (ushort4*)(xb + (size_t)p * HW);
    __shared__ float red[8];
    const int wid = t >> 6;

    float4 v[4];
    float s = 0.f, ss = 0.f;
#pragma unroll
    for (int i = 0; i < 4; ++i) {
        float4 q = kp[t + i * 256];
        v[i] = q;
        s += q.x + q.y + q.z + q.w;
        ss += q.x * q.x + q.y * q.y + q.z * q.z + q.w * q.w;
    }
#pragma unroll
    for (int off = 32; off > 0; off >>= 1) {
        s  += __shfl_xor(s, off);
        ss += __shfl_xor(ss, off);
    }
    if ((t & 63) == 0) { red[wid] = s; red[4 + wid] = ss; }
    __syncthreads();
    s  = red[0] + red[1] + red[2] + red[3];
    ss = red[4] + red[5] + red[6] + red[7];
    const float mean = s * (1.f / HW);
    const float var  = ss * (1.f / HW) - mean * mean;
    const float rstd = rsqrtf(var + 1e-5f);
    const float sc = g[c] * rstd;
    const float sh = bt[c] - mean * sc;

    float s2 = 0.f, ss2 = 0.f;
#pragma unroll
    for (int i = 0; i < 4; ++i) {
        float4 kq = v[i];
        kq.x = kq.x * sc + sh; kq.y = kq.y * sc + sh;
        kq.z = kq.z * sc + sh; kq.w = kq.w * sc + sh;
        const int idx = t + i * 256;
        float4 w;
        if (mode == 2) {
            float4 av = ap[idx];
            w.x = av.x + ca * kq.x; w.y = av.y + ca * kq.y;
            w.z = av.z + ca * kq.z; w.w = av.w + ca * kq.w;
            yp[idx] = w;
        } else {
            float4 yv = yp[idx];
            float4 av;
            if (mode == 0) {
                av.x = yv.x + ca * kq.x; av.y = yv.y + ca * kq.y;
                av.z = yv.z + ca * kq.z; av.w = yv.w + ca * kq.w;
            } else {
                av = ap[idx];
                av.x += ca * kq.x; av.y += ca * kq.y;
                av.z += ca * kq.z; av.w += ca * kq.w;
            }
            ap[idx] = av;
            w.x = yv.x + cy * kq.x; w.y = yv.y + cy * kq.y;
            w.z = yv.z + cy * kq.z; w.w = yv.w + cy * kq.w;
        }
        ushort4 u; u.x = f2b(w.x); u.y = f2b(w.y); u.z = f2b(w.z); u.w = f2b(w.w);
        xp[idx] = u;
        s2  += w.x + w.y + w.z + w.w;
        ss2 += w.x * w.x + w.y * w.y + w.z * w.z + w.w * w.w;
    }
#pragma unroll
    for (int off = 32; off > 0; off >>= 1) {
        s2  += __shfl_xor(s2, off);
        ss2 += __shfl_xor(ss2, off);
    }
    __syncthreads();
    if ((t & 63) == 0) { red[wid] = s2; red[4 + wid] = ss2; }
    __syncthreads();
    if (t == 0) {
        s2  = red[0] + red[1] + red[2] + red[3];
        ss2 = red[4] + red[5] + red[6] + red[7];
        const float m2 = s2 * (1.f / HW);
        const float v2 = ss2 * (1.f / HW) - m2 * m2;
        const float r2 = rsqrtf(v2 + 1e-5f);
        const float sc1 = g1n[c] * r2;
        stout[p * 2]     = sc1;
        stout[p * 2 + 1] = b1n[c] - m2 * sc1;
    }
}

extern "C" void kernel_launch(void* const* d_in, const int* in_sizes, int n_in,
                              void* d_out, int out_size, void* d_ws, size_t ws_size,
                              hipStream_t stream) {
    (void)in_sizes; (void)n_in; (void)out_size; (void)ws_size;
    const float* x      = (const float*)d_in[0];
    const float* ai_g1  = (const float*)d_in[1];
    const float* ai_b1  = (const float*)d_in[2];
    const float* ai_w   = (const float*)d_in[3];
    const float* ai_cb  = (const float*)d_in[4];
    const float* ai_g2  = (const float*)d_in[5];
    const float* ai_b2  = (const float*)d_in[6];
    const float* ai_g3  = (const float*)d_in[7];
    const float* ai_b3  = (const float*)d_in[8];
    const float* of_g1  = (const float*)d_in[9];
    const float* of_b1  = (const float*)d_in[10];
    const float* of_w1  = (const float*)d_in[11];
    const float* of_cb1 = (const float*)d_in[12];
    const float* of_g2  = (const float*)d_in[13];
    const float* of_b2  = (const float*)d_in[14];
    const float* of_w2  = (const float*)d_in[15];
    const float* of_cb2 = (const float*)d_in[16];
    const float* of_g3  = (const float*)d_in[17];
    const float* of_b3  = (const float*)d_in[18];

    float* y = (float*)d_out;                         // (256,32,64,64) fp32
    const size_t N  = (size_t)256 * 32 * 64 * 64;
    const size_t NH = N / 2;
    float* ws = (float*)d_ws;
    float* YT  = ws;                      // conv2 out (fp32)
    float* ACC = ws + N;                  // RK accumulator (fp32)
    unsigned short* Abf = (unsigned short*)(ws + 2 * N);         // conv1 out (bf16)
    unsigned short* XB  = (unsigned short*)(ws + 2 * N + N / 2); // stage input (bf16)
    float* tail  = ws + 3 * N;
    float* ST1   = tail;                tail += 16384;
    float* ST2   = tail;                tail += 16384;
    float* ST_AI = tail;                tail += 8192;
    float* STRAW = tail;                tail += 131072;
    unsigned short* WPai = (unsigned short*)tail;  tail += 5760;   // 9*32*40 bf16
    unsigned short* WP1  = (unsigned short*)tail;  tail += 5760;
    unsigned short* WP2  = (unsigned short*)tail;  tail += 5760;
    float* TC1  = tail;                 tail += 288;
    float* TC2  = tail;                 tail += 288;

    const float h = 0.125f;

    prep_kernel<<<1, 256, 0, stream>>>(ai_w, of_w1, of_w2, WPai, WP1, WP2, TC1, TC2);

    // ---- atten_init (batch 128) ----
    stats_kernel<<<4096, 256, 0, stream>>>(x, ST_AI, ai_g1, ai_b1);
    xcopy_kernel<<<16384, 256, 0, stream>>>(x, y, XB);   // y=x, XB=bf16(x) (lower half)
    conv_kernel<0, 0, 0><<<1024, 512, 0, stream>>>(XB, YT, ST_AI, WPai, ai_cb,
                                                   nullptr, 0.f, nullptr);
    stats_kernel<<<4096, 256, 0, stream>>>(x, ST1, of_g1, of_b1);
    dgn_kernel<<<4096, 256, 0, stream>>>(YT, y + NH, XB + NH, ai_g2, ai_b2,
                                         ai_g3, ai_b3, of_g1, of_b1, ST1 + 8192);

    auto eval = [&](float tv, float ca, float cy, int mode) {
        conv_kernel<1, 1, 1><<<2048, 512, 0, stream>>>(XB, Abf, ST1, WP1, of_cb1,
                                                       TC1, tv, STRAW);
        finalize_kernel<<<32, 256, 0, stream>>>(STRAW, ST2, of_g2, of_b2);
        conv_kernel<1, 0, 0><<<2048, 512, 0, stream>>>(Abf, YT, ST2, WP2, of_cb2,
                                                       TC2, tv, nullptr);
        gnrk_kernel<<<8192, 256, 0, stream>>>(YT, of_g3, of_b3, y, ACC, ca, cy, mode,
                                              of_g1, of_b1, ST1, XB);
    };

    for (int s = 0; s < 8; ++s) {
        const float t0 = h * (float)s;
        eval(t0,            h / 6.f, 0.5f * h, 0);   // k1
        eval(t0 + 0.5f * h, h / 3.f, 0.5f * h, 1);   // k2
        eval(t0 + 0.5f * h, h / 3.f, h,        1);   // k3
        eval(t0 + h,        h / 6.f, 0.f,      2);   // k4
    }
}

// Round 6
// 6126.313 us; speedup vs baseline: 4.8227x; 1.1432x over previous
//
#include <hip/hip_runtime.h>

#define HW 4096            // 64*64
#define CIN 32

typedef __bf16 bf16x8 __attribute__((ext_vector_type(8)));
typedef float  f32x4  __attribute__((ext_vector_type(4)));
typedef unsigned short ushort8_v __attribute__((ext_vector_type(8)));

__device__ __forceinline__ unsigned short f2b(float f) {
    unsigned int u = __builtin_bit_cast(unsigned int, f);
    unsigned int r = (u + 0x7FFFu + ((u >> 16) & 1u)) >> 16;
    return (unsigned short)r;
}
__device__ __forceinline__ float b2f(unsigned short s) {
    unsigned int u = ((unsigned int)s) << 16;
    return __builtin_bit_cast(float, u);
}
__device__ __forceinline__ bf16x8 ld_frag(const unsigned short* p) {
    ushort8_v u = *(const ushort8_v*)p;
    return __builtin_bit_cast(bf16x8, u);
}

// ---------- weight prep: WP[tap s][oc][ci pad 40] bf16; Tcls[oc][9] --------
__global__ __launch_bounds__(256)
void prep_kernel(const float* __restrict__ ai_w,
                 const float* __restrict__ of_w1,
                 const float* __restrict__ of_w2,
                 unsigned short* __restrict__ wp_ai,
                 unsigned short* __restrict__ wp1,
                 unsigned short* __restrict__ wp2,
                 float* __restrict__ tc1, float* __restrict__ tc2)
{
    const int t = threadIdx.x;
    for (int i = t; i < 9 * 32 * 40; i += 256) {
        const int s = i / 1280;
        const int rem = i - s * 1280;
        const int oc = rem / 40;
        const int ci = rem - oc * 40;
        unsigned short va = 0, v1 = 0, v2 = 0;
        if (ci < 32) {
            va = f2b(ai_w[(oc * 32 + ci) * 9 + s]);
            v1 = f2b(of_w1[(oc * 33 + ci + 1) * 9 + s]);
            v2 = f2b(of_w2[(oc * 33 + ci + 1) * 9 + s]);
        }
        wp_ai[i] = va; wp1[i] = v1; wp2[i] = v2;
    }
    for (int i = t; i < 32 * 9; i += 256) {
        const int oc = i / 9;
        const int cls = i - oc * 9;
        const int rc = cls / 3, cc = cls - rc * 3;
        float s1 = 0.f, s2 = 0.f;
        for (int ky = 0; ky < 3; ++ky) {
            if ((rc == 0 && ky == 0) || (rc == 2 && ky == 2)) continue;
            for (int kx = 0; kx < 3; ++kx) {
                if ((cc == 0 && kx == 0) || (cc == 2 && kx == 2)) continue;
                s1 += of_w1[(oc * 33) * 9 + ky * 3 + kx];
                s2 += of_w2[(oc * 33) * 9 + ky * 3 + kx];
            }
        }
        tc1[i] = s1; tc2[i] = s2;
    }
}

// ---------- per-plane GN stats (fp32 input) --------------------------------
__global__ __launch_bounds__(256)
void stats_kernel(const float* __restrict__ in, float* __restrict__ st,
                  const float* __restrict__ gamma, const float* __restrict__ beta)
{
    const int p = blockIdx.x;
    const int c = p & 31;
    const int t = threadIdx.x;
    const float4* ip = (const float4*)(in + (size_t)p * HW);
    float s = 0.f, ss = 0.f;
#pragma unroll
    for (int i = 0; i < 4; ++i) {
        float4 q = ip[t + i * 256];
        s += q.x + q.y + q.z + q.w;
        ss += q.x * q.x + q.y * q.y + q.z * q.z + q.w * q.w;
    }
#pragma unroll
    for (int off = 32; off > 0; off >>= 1) {
        s  += __shfl_xor(s, off);
        ss += __shfl_xor(ss, off);
    }
    __shared__ float red[8];
    const int wid = t >> 6;
    if ((t & 63) == 0) { red[wid] = s; red[4 + wid] = ss; }
    __syncthreads();
    if (t == 0) {
        s  = red[0] + red[1] + red[2] + red[3];
        ss = red[4] + red[5] + red[6] + red[7];
        const float mean = s * (1.f / HW);
        const float var  = ss * (1.f / HW) - mean * mean;
        const float rstd = rsqrtf(var + 1e-5f);
        const float sc = gamma[c] * rstd;
        st[p * 2]     = sc;
        st[p * 2 + 1] = beta[c] - mean * sc;
    }
}

// ---------- x init: y = x (fp32) ; XB = bf16(x) ----------------------------
__global__ __launch_bounds__(256)
void xcopy_kernel(const float* __restrict__ x, float* __restrict__ y,
                  unsigned short* __restrict__ xb)
{
    const int i = blockIdx.x * 256 + threadIdx.x;
    const float4 v = ((const float4*)x)[i];
    ((float4*)y)[i] = v;
    ushort4 u; u.x = f2b(v.x); u.y = f2b(v.y); u.z = f2b(v.z); u.w = f2b(v.w);
    ((ushort4*)xb)[i] = u;
}

// ---------- MFMA implicit-GEMM conv 3x3 ------------------------------------
// 512 thr = 8 waves; block = (b, 8 output rows). Wave wid = one row of 64 px.
// A = pixel tile (LDS, gather-staged, GN+ReLU fused), B = weights (registers).
// FIN=0: st = per-plane (sc,sh). FIN=1: st = raw partials [plane][8][2],
// finalized in-block with (fg, fb).
template<int HAS_TIME, int STATS, int OUT_BF16, int FIN>
__global__ __launch_bounds__(512)
void conv_kernel(const unsigned short* __restrict__ in, void* __restrict__ outv,
                 const float* __restrict__ st,
                 const float* __restrict__ fg, const float* __restrict__ fb,
                 const unsigned short* __restrict__ wp,
                 const float* __restrict__ cb, const float* __restrict__ tcls,
                 float tval, float* __restrict__ straw)
{
    const int blk = blockIdx.x;
    const int b  = blk >> 3;
    const int hb = blk & 7;
    const int h0 = hb * 8;
    const int t  = threadIdx.x;
    const int l  = t & 63;
    const int wid = t >> 6;            // 0..7 = output row
    const int lm = l & 15;
    const int lg = l >> 4;

    __shared__ unsigned short tile[10 * 66 * 40];   // 52800 B
    __shared__ float sst[64];                        // (sc,sh) per ci

    // ---- GN scale/shift table ----
    if (FIN) {
        float s = 0.f, ss = 0.f;
        if (t < 256) {
            const float2 pr = ((const float2*)st)[(size_t)(b * 32 + (t >> 3)) * 8 + (t & 7)];
            s = pr.x; ss = pr.y;
        }
        s += __shfl_xor(s, 1); ss += __shfl_xor(ss, 1);
        s += __shfl_xor(s, 2); ss += __shfl_xor(ss, 2);
        s += __shfl_xor(s, 4); ss += __shfl_xor(ss, 4);
        if (t < 256 && (t & 7) == 0) {
            const int ci = t >> 3;
            const float mean = s * (1.f / HW);
            const float var  = ss * (1.f / HW) - mean * mean;
            const float rstd = rsqrtf(var + 1e-5f);
            const float sc = fg[ci] * rstd;
            sst[ci * 2]     = sc;
            sst[ci * 2 + 1] = fb[ci] - mean * sc;
        }
    } else {
        if (t < 64) sst[t] = st[b * 64 + t];
    }

    // ---- weight fragments into registers: wreg[nt][tap] ----
    bf16x8 wreg[2][9];
    {
        const unsigned short* wb = wp + (size_t)(lm * 40 + 8 * lg);
#pragma unroll
        for (int nt = 0; nt < 2; ++nt)
#pragma unroll
            for (int s = 0; s < 9; ++s)
                wreg[nt][s] = ld_frag(wb + s * 1280 + nt * 640);
    }
    __syncthreads();   // sst ready

    // ---- gather-stage normalized input: one ds_write_b128 per task ----
    const unsigned short* inb = in + (size_t)b * (CIN * HW);
#pragma unroll
    for (int it = 0; it < 5; ++it) {
        const int tau = it * 512 + t;          // 2560 tasks = 4g x 10r x 64w
        const int g = tau / 640;
        const int rem = tau - g * 640;
        const int r = rem >> 6;
        const int w = rem & 63;
        const int hh = h0 - 1 + r;
        ushort8_v frag = {0, 0, 0, 0, 0, 0, 0, 0};
        if (hh >= 0 && hh < 64) {
            const unsigned short* src = inb + (size_t)(8 * g) * HW + hh * 64 + w;
#pragma unroll
            for (int j = 0; j < 8; ++j) {
                const float2 sc = *(const float2*)(&sst[(8 * g + j) * 2]);
                frag[j] = f2b(fmaxf(b2f(src[(size_t)j * HW]) * sc.x + sc.y, 0.f));
            }
        }
        *(ushort8_v*)&tile[(r * 66 + w + 1) * 40 + 8 * g] = frag;
    }
    if (t < 80) {   // zero pad columns w''=0,65
        const int g = t & 3;
        const int rr = t >> 2;
        const int r = rr >> 1;
        const int col = (rr & 1) ? 65 : 0;
        ushort8_v z = {0, 0, 0, 0, 0, 0, 0, 0};
        *(ushort8_v*)&tile[(r * 66 + col) * 40 + 8 * g] = z;
    }
    __syncthreads();

    // ---- K loop: 9 taps x 4 M-tiles, weights from regs ----
    f32x4 acc[4][2];
#pragma unroll
    for (int mt = 0; mt < 4; ++mt)
#pragma unroll
        for (int nt = 0; nt < 2; ++nt) acc[mt][nt] = (f32x4){0.f, 0.f, 0.f, 0.f};

#pragma unroll
    for (int ky = 0; ky < 3; ++ky)
#pragma unroll
        for (int kx = 0; kx < 3; ++kx) {
            const int s = ky * 3 + kx;
            const int base = ((wid + ky) * 66 + kx + lm) * 40 + 8 * lg;
#pragma unroll
            for (int mt = 0; mt < 4; ++mt) {
                const bf16x8 a = ld_frag(&tile[base + mt * 640]);
                acc[mt][0] = __builtin_amdgcn_mfma_f32_16x16x32_bf16(a, wreg[0][s], acc[mt][0], 0, 0, 0);
                acc[mt][1] = __builtin_amdgcn_mfma_f32_16x16x32_bf16(a, wreg[1][s], acc[mt][1], 0, 0, 0);
            }
        }

    // ---- epilogue ----
    const int h = h0 + wid;
    const int rc = (h == 0) ? 0 : ((h == 63) ? 2 : 1);
    float bias_[2], tcn[2], tc0[2], tc2[2];
#pragma unroll
    for (int nt = 0; nt < 2; ++nt) {
        const int oc = nt * 16 + lm;
        bias_[nt] = cb[oc];
        if (HAS_TIME) {
            tcn[nt] = tcls[oc * 9 + rc * 3 + 1];
            tc0[nt] = tcls[oc * 9 + rc * 3 + 0];
            tc2[nt] = tcls[oc * 9 + rc * 3 + 2];
        }
    }
    float sl[2] = {0.f, 0.f}, ssl[2] = {0.f, 0.f};
    float* outf = (float*)outv;
    unsigned short* outb = (unsigned short*)outv;
#pragma unroll
    for (int mt = 0; mt < 4; ++mt) {
#pragma unroll
        for (int nt = 0; nt < 2; ++nt) {
            const int oc = nt * 16 + lm;
            float v[4];
#pragma unroll
            for (int r = 0; r < 4; ++r) {
                v[r] = acc[mt][nt][r] + bias_[nt];
                if (HAS_TIME) v[r] += tval * tcn[nt];
            }
            if (HAS_TIME && mt == 0 && lg == 0) v[0] += tval * (tc0[nt] - tcn[nt]);
            if (HAS_TIME && mt == 3 && lg == 3) v[3] += tval * (tc2[nt] - tcn[nt]);
            const int w0 = mt * 16 + lg * 4;
            const size_t o = ((size_t)(b * 32 + oc)) * HW + (size_t)h * 64 + w0;
            if (OUT_BF16) {
                ushort4 u;
                u.x = f2b(v[0]); u.y = f2b(v[1]); u.z = f2b(v[2]); u.w = f2b(v[3]);
                *(ushort4*)&outb[o] = u;
                if (STATS) {   // stats on rounded values (consumer reads bf16)
#pragma unroll
                    for (int r = 0; r < 4; ++r) {
                        const float vr = b2f(f2b(v[r]));
                        sl[nt] += vr; ssl[nt] += vr * vr;
                    }
                }
            } else {
                float4 q; q.x = v[0]; q.y = v[1]; q.z = v[2]; q.w = v[3];
                *(float4*)&outf[o] = q;
                if (STATS) {
#pragma unroll
                    for (int r = 0; r < 4; ++r) { sl[nt] += v[r]; ssl[nt] += v[r] * v[r]; }
                }
            }
        }
    }
    if (STATS) {
        float s0 = sl[0], q0 = ssl[0], s1 = sl[1], q1 = ssl[1];
        s0 += __shfl_xor(s0, 16); s0 += __shfl_xor(s0, 32);
        q0 += __shfl_xor(q0, 16); q0 += __shfl_xor(q0, 32);
        s1 += __shfl_xor(s1, 16); s1 += __shfl_xor(s1, 32);
        q1 += __shfl_xor(q1, 16); q1 += __shfl_xor(q1, 32);
        __syncthreads();                       // tile no longer needed
        float* red = (float*)tile;             // [0..255]=S, [256..511]=SS
        if (lg == 0) {
            red[wid * 32 + lm]       = s0;  red[256 + wid * 32 + lm]       = q0;
            red[wid * 32 + 16 + lm]  = s1;  red[256 + wid * 32 + 16 + lm]  = q1;
        }
        __syncthreads();
        if (t < 32) {
            float S = 0.f, Q = 0.f;
#pragma unroll
            for (int w = 0; w < 8; ++w) { S += red[w * 32 + t]; Q += red[256 + w * 32 + t]; }
            float* dst = straw + ((size_t)(b * 32 + t) * 8 + hb) * 2;
            dst[0] = S; dst[1] = Q;
        }
    }
}

// ---------- atten_init tail: gn2+relu -> gn3; fp32 + bf16 out + GN1 stats --
__global__ __launch_bounds__(256)
void dgn_kernel(const float* __restrict__ in, float* __restrict__ out,
                unsigned short* __restrict__ xbout,
                const float* __restrict__ g2, const float* __restrict__ b2,
                const float* __restrict__ g3, const float* __restrict__ b3,
                const float* __restrict__ g1n, const float* __restrict__ b1n,
                float* __restrict__ stout)
{
    const int p = blockIdx.x;
    const int c = p & 31;
    const int t = threadIdx.x;
    const float4* ip = (const float4*)(in + (size_t)p * HW);
    float4* op = (float4*)(out + (size_t)p * HW);
    ushort4* xp = (ushort4*)(xbout + (size_t)p * HW);
    __shared__ float red[8];
    const int wid = t >> 6;

    float4 v[4];
    float s = 0.f, ss = 0.f;
#pragma unroll
    for (int i = 0; i < 4; ++i) {
        float4 q = ip[t + i * 256];
        v[i] = q;
        s += q.x + q.y + q.z + q.w;
        ss += q.x * q.x + q.y * q.y + q.z * q.z + q.w * q.w;
    }
#pragma unroll
    for (int off = 32; off > 0; off >>= 1) {
        s  += __shfl_xor(s, off);
        ss += __shfl_xor(ss, off);
    }
    if ((t & 63) == 0) { red[wid] = s; red[4 + wid] = ss; }
    __syncthreads();
    s  = red[0] + red[1] + red[2] + red[3];
    ss = red[4] + red[5] + red[6] + red[7];
    float mean = s * (1.f / HW);
    float var  = ss * (1.f / HW) - mean * mean;
    float rstd = rsqrtf(var + 1e-5f);
    float sc = g2[c] * rstd;
    float sh = b2[c] - mean * sc;

    s = 0.f; ss = 0.f;
#pragma unroll
    for (int i = 0; i < 4; ++i) {
        float4 q = v[i];
        q.x = fmaxf(q.x * sc + sh, 0.f); q.y = fmaxf(q.y * sc + sh, 0.f);
        q.z = fmaxf(q.z * sc + sh, 0.f); q.w = fmaxf(q.w * sc + sh, 0.f);
        v[i] = q;
        s += q.x + q.y + q.z + q.w;
        ss += q.x * q.x + q.y * q.y + q.z * q.z + q.w * q.w;
    }
#pragma unroll
    for (int off = 32; off > 0; off >>= 1) {
        s  += __shfl_xor(s, off);
        ss += __shfl_xor(ss, off);
    }
    __syncthreads();
    if ((t & 63) == 0) { red[wid] = s; red[4 + wid] = ss; }
    __syncthreads();
    s  = red[0] + red[1] + red[2] + red[3];
    ss = red[4] + red[5] + red[6] + red[7];
    mean = s * (1.f / HW);
    var  = ss * (1.f / HW) - mean * mean;
    rstd = rsqrtf(var + 1e-5f);
    sc = g3[c] * rstd;
    sh = b3[c] - mean * sc;

    float s3 = 0.f, ss3 = 0.f;
#pragma unroll
    for (int i = 0; i < 4; ++i) {
        float4 q = v[i];
        q.x = q.x * sc + sh; q.y = q.y * sc + sh;
        q.z = q.z * sc + sh; q.w = q.w * sc + sh;
        op[t + i * 256] = q;
        ushort4 u; u.x = f2b(q.x); u.y = f2b(q.y); u.z = f2b(q.z); u.w = f2b(q.w);
        xp[t + i * 256] = u;
        s3 += q.x + q.y + q.z + q.w;
        ss3 += q.x * q.x + q.y * q.y + q.z * q.z + q.w * q.w;
    }
#pragma unroll
    for (int off = 32; off > 0; off >>= 1) {
        s3  += __shfl_xor(s3, off);
        ss3 += __shfl_xor(ss3, off);
    }
    __syncthreads();
    if ((t & 63) == 0) { red[wid] = s3; red[4 + wid] = ss3; }
    __syncthreads();
    if (t == 0) {
        s3  = red[0] + red[1] + red[2] + red[3];
        ss3 = red[4] + red[5] + red[6] + red[7];
        const float m3 = s3 * (1.f / HW);
        const float v3 = ss3 * (1.f / HW) - m3 * m3;
        const float r3 = rsqrtf(v3 + 1e-5f);
        const float sc1 = g1n[c] * r3;
        stout[p * 2]     = sc1;
        stout[p * 2 + 1] = b1n[c] - m3 * sc1;
    }
}

// ---------- streaming GN3 + RK update --------------------------------------
// kin = bf16 conv2 output; GN3 finalized in-register from straw (no barrier).
// MODE 0: acc = y + ca*k ; w = y + cy*k -> XB
// MODE 1: acc += ca*k    ; w = y + cy*k -> XB
// MODE 2: y = acc + ca*k ; w = y_new    -> XB
template<int MODE>
__global__ __launch_bounds__(256)
void gnrk_kernel(const unsigned short* __restrict__ kin,
                 const float* __restrict__ straw,
                 const float* __restrict__ g, const float* __restrict__ bt,
                 float* __restrict__ y, float* __restrict__ acc,
                 float ca, float cy,
                 const float* __restrict__ g1n, const float* __restrict__ b1n,
                 float* __restrict__ stout, unsigned short* __restrict__ xb)
{
    const int p = blockIdx.x;
    const int c = p & 31;
    const int t = threadIdx.x;

    // in-register GN3 finalize: broadcast 8 partials, 3 shuffles, no barrier
    const float2 pr = ((const float2*)straw)[(size_t)p * 8 + (t & 7)];
    float s = pr.x, ss = pr.y;
    s += __shfl_xor(s, 1); ss += __shfl_xor(ss, 1);
    s += __shfl_xor(s, 2); ss += __shfl_xor(ss, 2);
    s += __shfl_xor(s, 4); ss += __shfl_xor(ss, 4);
    const float mean = s * (1.f / HW);
    const float var  = ss * (1.f / HW) - mean * mean;
    const float rstd = rsqrtf(var + 1e-5f);
    const float sc = g[c] * rstd;
    const float sh = bt[c] - mean * sc;

    const ushort4* kp = (const ushort4*)(kin + (size_t)p * HW);
    float4* yp = (float4*)(y   + (size_t)p * HW);
    float4* ap = (float4*)(acc + (size_t)p * HW);
    ushort4* xp = (ushort4*)(xb + (size_t)p * HW);
    __shared__ float red[8];
    const int wid = t >> 6;

    float s2 = 0.f, ss2 = 0.f;
#pragma unroll
    for (int i = 0; i < 4; ++i) {
        const int idx = t + i * 256;
        const ushort4 ku = kp[idx];
        float4 kq;
        kq.x = b2f(ku.x) * sc + sh; kq.y = b2f(ku.y) * sc + sh;
        kq.z = b2f(ku.z) * sc + sh; kq.w = b2f(ku.w) * sc + sh;
        float4 w;
        if (MODE == 2) {
            float4 av = ap[idx];
            w.x = av.x + ca * kq.x; w.y = av.y + ca * kq.y;
            w.z = av.z + ca * kq.z; w.w = av.w + ca * kq.w;
            yp[idx] = w;
        } else {
            float4 yv = yp[idx];
            float4 av;
            if (MODE == 0) {
                av.x = yv.x + ca * kq.x; av.y = yv.y + ca * kq.y;
                av.z = yv.z + ca * kq.z; av.w = yv.w + ca * kq.w;
            } else {
                av = ap[idx];
                av.x += ca * kq.x; av.y += ca * kq.y;
                av.z += ca * kq.z; av.w += ca * kq.w;
            }
            ap[idx] = av;
            w.x = yv.x + cy * kq.x; w.y = yv.y + cy * kq.y;
            w.z = yv.z + cy * kq.z; w.w = yv.w + cy * kq.w;
        }
        ushort4 u; u.x = f2b(w.x); u.y = f2b(w.y); u.z = f2b(w.z); u.w = f2b(w.w);
        xp[idx] = u;
        // GN1 stats of NEXT stage input, on rounded values (conv1 reads bf16)
        const float r0 = b2f(u.x), r1 = b2f(u.y), r2 = b2f(u.z), r3 = b2f(u.w);
        s2  += r0 + r1 + r2 + r3;
        ss2 += r0 * r0 + r1 * r1 + r2 * r2 + r3 * r3;
    }
#pragma unroll
    for (int off = 32; off > 0; off >>= 1) {
        s2  += __shfl_xor(s2, off);
        ss2 += __shfl_xor(ss2, off);
    }
    if ((t & 63) == 0) { red[wid] = s2; red[4 + wid] = ss2; }
    __syncthreads();
    if (t == 0) {
        s2  = red[0] + red[1] + red[2] + red[3];
        ss2 = red[4] + red[5] + red[6] + red[7];
        const float m2 = s2 * (1.f / HW);
        const float v2 = ss2 * (1.f / HW) - m2 * m2;
        const float r2 = rsqrtf(v2 + 1e-5f);
        const float sc1 = g1n[c] * r2;
        stout[p * 2]     = sc1;
        stout[p * 2 + 1] = b1n[c] - m2 * sc1;
    }
}

extern "C" void kernel_launch(void* const* d_in, const int* in_sizes, int n_in,
                              void* d_out, int out_size, void* d_ws, size_t ws_size,
                              hipStream_t stream) {
    (void)in_sizes; (void)n_in; (void)out_size; (void)ws_size;
    const float* x      = (const float*)d_in[0];
    const float* ai_g1  = (const float*)d_in[1];
    const float* ai_b1  = (const float*)d_in[2];
    const float* ai_w   = (const float*)d_in[3];
    const float* ai_cb  = (const float*)d_in[4];
    const float* ai_g2  = (const float*)d_in[5];
    const float* ai_b2  = (const float*)d_in[6];
    const float* ai_g3  = (const float*)d_in[7];
    const float* ai_b3  = (const float*)d_in[8];
    const float* of_g1  = (const float*)d_in[9];
    const float* of_b1  = (const float*)d_in[10];
    const float* of_w1  = (const float*)d_in[11];
    const float* of_cb1 = (const float*)d_in[12];
    const float* of_g2  = (const float*)d_in[13];
    const float* of_b2  = (const float*)d_in[14];
    const float* of_w2  = (const float*)d_in[15];
    const float* of_cb2 = (const float*)d_in[16];
    const float* of_g3  = (const float*)d_in[17];
    const float* of_b3  = (const float*)d_in[18];

    float* y = (float*)d_out;                         // (256,32,64,64) fp32
    const size_t N  = (size_t)256 * 32 * 64 * 64;
    const size_t NH = N / 2;
    float* ws = (float*)d_ws;
    float* ACC = ws;                                  // RK accumulator (fp32)
    float* YTf = ACC;                                 // prologue-only alias
    unsigned short* Abf = (unsigned short*)(ws + N);             // conv1 out bf16
    unsigned short* XB  = (unsigned short*)(ws + N + N / 2);     // stage in bf16
    unsigned short* YTB = (unsigned short*)(ws + 2 * N);         // conv2 out bf16
    float* tail  = ws + 2 * N + N / 2;
    float* ST1    = tail;               tail += 16384;   // GN1 (sc,sh), 8192 pl
    float* ST_AI  = tail;               tail += 8192;
    float* STRAW1 = tail;               tail += 131072;  // conv1 partials
    float* STRAW2 = tail;               tail += 131072;  // conv2 partials
    unsigned short* WPai = (unsigned short*)tail;  tail += 5760;
    unsigned short* WP1  = (unsigned short*)tail;  tail += 5760;
    unsigned short* WP2  = (unsigned short*)tail;  tail += 5760;
    float* TC1  = tail;                 tail += 288;
    float* TC2  = tail;                 tail += 288;

    const float h = 0.125f;

    prep_kernel<<<1, 256, 0, stream>>>(ai_w, of_w1, of_w2, WPai, WP1, WP2, TC1, TC2);

    // ---- atten_init (batch 128) ----
    stats_kernel<<<4096, 256, 0, stream>>>(x, ST_AI, ai_g1, ai_b1);
    xcopy_kernel<<<16384, 256, 0, stream>>>(x, y, XB);   // y=x, XB=bf16(x), lower
    conv_kernel<0, 0, 0, 0><<<1024, 512, 0, stream>>>(XB, YTf, ST_AI, nullptr, nullptr,
                                                      WPai, ai_cb, nullptr, 0.f, nullptr);
    stats_kernel<<<4096, 256, 0, stream>>>(x, ST1, of_g1, of_b1);
    dgn_kernel<<<4096, 256, 0, stream>>>(YTf, y + NH, XB + NH, ai_g2, ai_b2,
                                         ai_g3, ai_b3, of_g1, of_b1, ST1 + 8192);

    auto eval = [&](float tv, float ca, float cy, int mode) {
        conv_kernel<1, 1, 1, 0><<<2048, 512, 0, stream>>>(XB, Abf, ST1, nullptr, nullptr,
                                                          WP1, of_cb1, TC1, tv, STRAW1);
        conv_kernel<1, 1, 1, 1><<<2048, 512, 0, stream>>>(Abf, YTB, STRAW1, of_g2, of_b2,
                                                          WP2, of_cb2, TC2, tv, STRAW2);
        if (mode == 0)
            gnrk_kernel<0><<<8192, 256, 0, stream>>>(YTB, STRAW2, of_g3, of_b3, y, ACC,
                                                     ca, cy, of_g1, of_b1, ST1, XB);
        else if (mode == 1)
            gnrk_kernel<1><<<8192, 256, 0, stream>>>(YTB, STRAW2, of_g3, of_b3, y, ACC,
                                                     ca, cy, of_g1, of_b1, ST1, XB);
        else
            gnrk_kernel<2><<<8192, 256, 0, stream>>>(YTB, STRAW2, of_g3, of_b3, y, ACC,
                                                     ca, cy, of_g1, of_b1, ST1, XB);
    };

    for (int s = 0; s < 8; ++s) {
        const float t0 = h * (float)s;
        eval(t0,            h / 6.f, 0.5f * h, 0);   // k1
        eval(t0 + 0.5f * h, h / 3.f, 0.5f * h, 1);   // k2
        eval(t0 + 0.5f * h, h / 3.f, h,        1);   // k3
        eval(t0 + h,        h / 6.f, 0.f,      2);   // k4
    }
}

// Round 7
// 5667.833 us; speedup vs baseline: 5.2128x; 1.0809x over previous
//
#include <hip/hip_runtime.h>

#define HW 4096            // 64*64
#define CIN 32

typedef __bf16 bf16x8 __attribute__((ext_vector_type(8)));
typedef float  f32x4  __attribute__((ext_vector_type(4)));
typedef unsigned short ushort8_v __attribute__((ext_vector_type(8)));

__device__ __forceinline__ unsigned short f2b(float f) {
    __bf16 b = (__bf16)f;                    // v_cvt, RNE
    return __builtin_bit_cast(unsigned short, b);
}
__device__ __forceinline__ float b2f(unsigned short s) {
    unsigned int u = ((unsigned int)s) << 16;
    return __builtin_bit_cast(float, u);
}
__device__ __forceinline__ bf16x8 ld_frag(const unsigned short* p) {
    ushort8_v u = *(const ushort8_v*)p;
    return __builtin_bit_cast(bf16x8, u);
}

// ---------- weight prep: WP[tap s][oc][ci pad 40] bf16; Tcls[oc][9] --------
__global__ __launch_bounds__(256)
void prep_kernel(const float* __restrict__ ai_w,
                 const float* __restrict__ of_w1,
                 const float* __restrict__ of_w2,
                 unsigned short* __restrict__ wp_ai,
                 unsigned short* __restrict__ wp1,
                 unsigned short* __restrict__ wp2,
                 float* __restrict__ tc1, float* __restrict__ tc2)
{
    const int t = threadIdx.x;
    for (int i = t; i < 9 * 32 * 40; i += 256) {
        const int s = i / 1280;
        const int rem = i - s * 1280;
        const int oc = rem / 40;
        const int ci = rem - oc * 40;
        unsigned short va = 0, v1 = 0, v2 = 0;
        if (ci < 32) {
            va = f2b(ai_w[(oc * 32 + ci) * 9 + s]);
            v1 = f2b(of_w1[(oc * 33 + ci + 1) * 9 + s]);
            v2 = f2b(of_w2[(oc * 33 + ci + 1) * 9 + s]);
        }
        wp_ai[i] = va; wp1[i] = v1; wp2[i] = v2;
    }
    for (int i = t; i < 32 * 9; i += 256) {
        const int oc = i / 9;
        const int cls = i - oc * 9;
        const int rc = cls / 3, cc = cls - rc * 3;
        float s1 = 0.f, s2 = 0.f;
        for (int ky = 0; ky < 3; ++ky) {
            if ((rc == 0 && ky == 0) || (rc == 2 && ky == 2)) continue;
            for (int kx = 0; kx < 3; ++kx) {
                if ((cc == 0 && kx == 0) || (cc == 2 && kx == 2)) continue;
                s1 += of_w1[(oc * 33) * 9 + ky * 3 + kx];
                s2 += of_w2[(oc * 33) * 9 + ky * 3 + kx];
            }
        }
        tc1[i] = s1; tc2[i] = s2;
    }
}

// ---------- fused prologue: y=x, XB=bf16(x), GN stats for ai_g1 AND of_g1 --
__global__ __launch_bounds__(256)
void xstat_kernel(const float* __restrict__ x, float* __restrict__ y,
                  unsigned short* __restrict__ xb,
                  const float* __restrict__ g_ai, const float* __restrict__ b_ai,
                  const float* __restrict__ g_of, const float* __restrict__ b_of,
                  float* __restrict__ st_ai, float* __restrict__ st_of)
{
    const int p = blockIdx.x;          // 4096 planes (batch-128 half)
    const int c = p & 31;
    const int t = threadIdx.x;
    const float4* ip = (const float4*)(x + (size_t)p * HW);
    float4* yp = (float4*)(y + (size_t)p * HW);
    ushort4* xp = (ushort4*)(xb + (size_t)p * HW);
    float s = 0.f, ss = 0.f;
#pragma unroll
    for (int i = 0; i < 4; ++i) {
        const float4 q = ip[t + i * 256];
        yp[t + i * 256] = q;
        ushort4 u; u.x = f2b(q.x); u.y = f2b(q.y); u.z = f2b(q.z); u.w = f2b(q.w);
        xp[t + i * 256] = u;
        s += q.x + q.y + q.z + q.w;
        ss += q.x * q.x + q.y * q.y + q.z * q.z + q.w * q.w;
    }
#pragma unroll
    for (int off = 32; off > 0; off >>= 1) {
        s  += __shfl_xor(s, off);
        ss += __shfl_xor(ss, off);
    }
    __shared__ float red[8];
    const int wid = t >> 6;
    if ((t & 63) == 0) { red[wid] = s; red[4 + wid] = ss; }
    __syncthreads();
    if (t == 0) {
        s  = red[0] + red[1] + red[2] + red[3];
        ss = red[4] + red[5] + red[6] + red[7];
        const float mean = s * (1.f / HW);
        const float var  = ss * (1.f / HW) - mean * mean;
        const float rstd = rsqrtf(var + 1e-5f);
        const float sa = g_ai[c] * rstd;
        st_ai[p * 2]     = sa;
        st_ai[p * 2 + 1] = b_ai[c] - mean * sa;
        const float so = g_of[c] * rstd;
        st_of[p * 2]     = so;
        st_of[p * 2 + 1] = b_of[c] - mean * so;
    }
}

// ---------- MFMA implicit-GEMM conv 3x3 ------------------------------------
// 512 thr = 8 waves; block = (b, 8 output rows). Wave wid = one row of 64 px.
// A = pixel tile (LDS, gather-staged, GN+ReLU fused), B = weights (registers).
// FIN=0: st = per-plane (sc,sh). FIN=1: st = raw partials [plane][8][2],
// finalized in-block with (fg, fb).
template<int HAS_TIME, int STATS, int OUT_BF16, int FIN>
__global__ __launch_bounds__(512)
void conv_kernel(const unsigned short* __restrict__ in, void* __restrict__ outv,
                 const float* __restrict__ st,
                 const float* __restrict__ fg, const float* __restrict__ fb,
                 const unsigned short* __restrict__ wp,
                 const float* __restrict__ cb, const float* __restrict__ tcls,
                 float tval, float* __restrict__ straw)
{
    const int blk = blockIdx.x;
    const int b  = blk >> 3;
    const int hb = blk & 7;
    const int h0 = hb * 8;
    const int t  = threadIdx.x;
    const int l  = t & 63;
    const int wid = t >> 6;            // 0..7 = output row
    const int lm = l & 15;
    const int lg = l >> 4;

    __shared__ unsigned short tile[10 * 66 * 40];   // 52800 B
    __shared__ float sst[64];                        // (sc,sh) per ci

    // ---- GN scale/shift table ----
    if (FIN) {
        float s = 0.f, ss = 0.f;
        if (t < 256) {
            const float2 pr = ((const float2*)st)[(size_t)(b * 32 + (t >> 3)) * 8 + (t & 7)];
            s = pr.x; ss = pr.y;
        }
        s += __shfl_xor(s, 1); ss += __shfl_xor(ss, 1);
        s += __shfl_xor(s, 2); ss += __shfl_xor(ss, 2);
        s += __shfl_xor(s, 4); ss += __shfl_xor(ss, 4);
        if (t < 256 && (t & 7) == 0) {
            const int ci = t >> 3;
            const float mean = s * (1.f / HW);
            const float var  = ss * (1.f / HW) - mean * mean;
            const float rstd = rsqrtf(var + 1e-5f);
            const float sc = fg[ci] * rstd;
            sst[ci * 2]     = sc;
            sst[ci * 2 + 1] = fb[ci] - mean * sc;
        }
    } else {
        if (t < 64) sst[t] = st[b * 64 + t];
    }

    // ---- weight fragments into registers: wreg[nt][tap] ----
    bf16x8 wreg[2][9];
    {
        const unsigned short* wb = wp + (size_t)(lm * 40 + 8 * lg);
#pragma unroll
        for (int nt = 0; nt < 2; ++nt)
#pragma unroll
            for (int s = 0; s < 9; ++s)
                wreg[nt][s] = ld_frag(wb + s * 1280 + nt * 640);
    }
    __syncthreads();   // sst ready

    // ---- gather-stage normalized input: one ds_write_b128 per task ----
    const unsigned short* inb = in + (size_t)b * (CIN * HW);
#pragma unroll
    for (int it = 0; it < 5; ++it) {
        const int tau = it * 512 + t;          // 2560 tasks = 4g x 10r x 64w
        const int g = tau / 640;
        const int rem = tau - g * 640;
        const int r = rem >> 6;
        const int w = rem & 63;
        const int hh = h0 - 1 + r;
        ushort8_v frag = {0, 0, 0, 0, 0, 0, 0, 0};
        if (hh >= 0 && hh < 64) {
            const unsigned short* src = inb + (size_t)(8 * g) * HW + hh * 64 + w;
#pragma unroll
            for (int j = 0; j < 8; ++j) {
                const float2 sc = *(const float2*)(&sst[(8 * g + j) * 2]);
                frag[j] = f2b(fmaxf(b2f(src[(size_t)j * HW]) * sc.x + sc.y, 0.f));
            }
        }
        *(ushort8_v*)&tile[(r * 66 + w + 1) * 40 + 8 * g] = frag;
    }
    if (t < 80) {   // zero pad columns w''=0,65
        const int g = t & 3;
        const int rr = t >> 2;
        const int r = rr >> 1;
        const int col = (rr & 1) ? 65 : 0;
        ushort8_v z = {0, 0, 0, 0, 0, 0, 0, 0};
        *(ushort8_v*)&tile[(r * 66 + col) * 40 + 8 * g] = z;
    }
    __syncthreads();

    // ---- K loop: 9 taps x 4 M-tiles, weights from regs ----
    f32x4 acc[4][2];
#pragma unroll
    for (int mt = 0; mt < 4; ++mt)
#pragma unroll
        for (int nt = 0; nt < 2; ++nt) acc[mt][nt] = (f32x4){0.f, 0.f, 0.f, 0.f};

#pragma unroll
    for (int ky = 0; ky < 3; ++ky)
#pragma unroll
        for (int kx = 0; kx < 3; ++kx) {
            const int s = ky * 3 + kx;
            const int base = ((wid + ky) * 66 + kx + lm) * 40 + 8 * lg;
#pragma unroll
            for (int mt = 0; mt < 4; ++mt) {
                const bf16x8 a = ld_frag(&tile[base + mt * 640]);
                acc[mt][0] = __builtin_amdgcn_mfma_f32_16x16x32_bf16(a, wreg[0][s], acc[mt][0], 0, 0, 0);
                acc[mt][1] = __builtin_amdgcn_mfma_f32_16x16x32_bf16(a, wreg[1][s], acc[mt][1], 0, 0, 0);
            }
        }

    // ---- epilogue ----
    const int h = h0 + wid;
    const int rc = (h == 0) ? 0 : ((h == 63) ? 2 : 1);
    float bias_[2], tcn[2], tc0[2], tc2[2];
#pragma unroll
    for (int nt = 0; nt < 2; ++nt) {
        const int oc = nt * 16 + lm;
        bias_[nt] = cb[oc];
        if (HAS_TIME) {
            tcn[nt] = tcls[oc * 9 + rc * 3 + 1];
            tc0[nt] = tcls[oc * 9 + rc * 3 + 0];
            tc2[nt] = tcls[oc * 9 + rc * 3 + 2];
        }
    }
    float sl[2] = {0.f, 0.f}, ssl[2] = {0.f, 0.f};
    float* outf = (float*)outv;
    unsigned short* outb = (unsigned short*)outv;
#pragma unroll
    for (int mt = 0; mt < 4; ++mt) {
#pragma unroll
        for (int nt = 0; nt < 2; ++nt) {
            const int oc = nt * 16 + lm;
            float v[4];
#pragma unroll
            for (int r = 0; r < 4; ++r) {
                v[r] = acc[mt][nt][r] + bias_[nt];
                if (HAS_TIME) v[r] += tval * tcn[nt];
            }
            if (HAS_TIME && mt == 0 && lg == 0) v[0] += tval * (tc0[nt] - tcn[nt]);
            if (HAS_TIME && mt == 3 && lg == 3) v[3] += tval * (tc2[nt] - tcn[nt]);
            const int w0 = mt * 16 + lg * 4;
            const size_t o = ((size_t)(b * 32 + oc)) * HW + (size_t)h * 64 + w0;
            if (OUT_BF16) {
                ushort4 u;
                u.x = f2b(v[0]); u.y = f2b(v[1]); u.z = f2b(v[2]); u.w = f2b(v[3]);
                *(ushort4*)&outb[o] = u;
                if (STATS) {   // stats on rounded values (consumer reads bf16)
#pragma unroll
                    for (int r = 0; r < 4; ++r) {
                        const float vr = b2f(f2b(v[r]));
                        sl[nt] += vr; ssl[nt] += vr * vr;
                    }
                }
            } else {
                float4 q; q.x = v[0]; q.y = v[1]; q.z = v[2]; q.w = v[3];
                *(float4*)&outf[o] = q;
                if (STATS) {
#pragma unroll
                    for (int r = 0; r < 4; ++r) { sl[nt] += v[r]; ssl[nt] += v[r] * v[r]; }
                }
            }
        }
    }
    if (STATS) {
        float s0 = sl[0], q0 = ssl[0], s1 = sl[1], q1 = ssl[1];
        s0 += __shfl_xor(s0, 16); s0 += __shfl_xor(s0, 32);
        q0 += __shfl_xor(q0, 16); q0 += __shfl_xor(q0, 32);
        s1 += __shfl_xor(s1, 16); s1 += __shfl_xor(s1, 32);
        q1 += __shfl_xor(q1, 16); q1 += __shfl_xor(q1, 32);
        __syncthreads();                       // tile no longer needed
        float* red = (float*)tile;             // [0..255]=S, [256..511]=SS
        if (lg == 0) {
            red[wid * 32 + lm]       = s0;  red[256 + wid * 32 + lm]       = q0;
            red[wid * 32 + 16 + lm]  = s1;  red[256 + wid * 32 + 16 + lm]  = q1;
        }
        __syncthreads();
        if (t < 32) {
            float S = 0.f, Q = 0.f;
#pragma unroll
            for (int w = 0; w < 8; ++w) { S += red[w * 32 + t]; Q += red[256 + w * 32 + t]; }
            float* dst = straw + ((size_t)(b * 32 + t) * 8 + hb) * 2;
            dst[0] = S; dst[1] = Q;
        }
    }
}

// ---------- atten_init tail: gn2+relu -> gn3; fp32 + bf16 out + GN1 stats --
__global__ __launch_bounds__(256)
void dgn_kernel(const float* __restrict__ in, float* __restrict__ out,
                unsigned short* __restrict__ xbout,
                const float* __restrict__ g2, const float* __restrict__ b2,
                const float* __restrict__ g3, const float* __restrict__ b3,
                const float* __restrict__ g1n, const float* __restrict__ b1n,
                float* __restrict__ stout)
{
    const int p = blockIdx.x;
    const int c = p & 31;
    const int t = threadIdx.x;
    const float4* ip = (const float4*)(in + (size_t)p * HW);
    float4* op = (float4*)(out + (size_t)p * HW);
    ushort4* xp = (ushort4*)(xbout + (size_t)p * HW);
    __shared__ float red[8];
    const int wid = t >> 6;

    float4 v[4];
    float s = 0.f, ss = 0.f;
#pragma unroll
    for (int i = 0; i < 4; ++i) {
        float4 q = ip[t + i * 256];
        v[i] = q;
        s += q.x + q.y + q.z + q.w;
        ss += q.x * q.x + q.y * q.y + q.z * q.z + q.w * q.w;
    }
#pragma unroll
    for (int off = 32; off > 0; off >>= 1) {
        s  += __shfl_xor(s, off);
        ss += __shfl_xor(ss, off);
    }
    if ((t & 63) == 0) { red[wid] = s; red[4 + wid] = ss; }
    __syncthreads();
    s  = red[0] + red[1] + red[2] + red[3];
    ss = red[4] + red[5] + red[6] + red[7];
    float mean = s * (1.f / HW);
    float var  = ss * (1.f / HW) - mean * mean;
    float rstd = rsqrtf(var + 1e-5f);
    float sc = g2[c] * rstd;
    float sh = b2[c] - mean * sc;

    s = 0.f; ss = 0.f;
#pragma unroll
    for (int i = 0; i < 4; ++i) {
        float4 q = v[i];
        q.x = fmaxf(q.x * sc + sh, 0.f); q.y = fmaxf(q.y * sc + sh, 0.f);
        q.z = fmaxf(q.z * sc + sh, 0.f); q.w = fmaxf(q.w * sc + sh, 0.f);
        v[i] = q;
        s += q.x + q.y + q.z + q.w;
        ss += q.x * q.x + q.y * q.y + q.z * q.z + q.w * q.w;
    }
#pragma unroll
    for (int off = 32; off > 0; off >>= 1) {
        s  += __shfl_xor(s, off);
        ss += __shfl_xor(ss, off);
    }
    __syncthreads();
    if ((t & 63) == 0) { red[wid] = s; red[4 + wid] = ss; }
    __syncthreads();
    s  = red[0] + red[1] + red[2] + red[3];
    ss = red[4] + red[5] + red[6] + red[7];
    mean = s * (1.f / HW);
    var  = ss * (1.f / HW) - mean * mean;
    rstd = rsqrtf(var + 1e-5f);
    sc = g3[c] * rstd;
    sh = b3[c] - mean * sc;

    float s3 = 0.f, ss3 = 0.f;
#pragma unroll
    for (int i = 0; i < 4; ++i) {
        float4 q = v[i];
        q.x = q.x * sc + sh; q.y = q.y * sc + sh;
        q.z = q.z * sc + sh; q.w = q.w * sc + sh;
        op[t + i * 256] = q;
        ushort4 u; u.x = f2b(q.x); u.y = f2b(q.y); u.z = f2b(q.z); u.w = f2b(q.w);
        xp[t + i * 256] = u;
        s3 += q.x + q.y + q.z + q.w;
        ss3 += q.x * q.x + q.y * q.y + q.z * q.z + q.w * q.w;
    }
#pragma unroll
    for (int off = 32; off > 0; off >>= 1) {
        s3  += __shfl_xor(s3, off);
        ss3 += __shfl_xor(ss3, off);
    }
    __syncthreads();
    if ((t & 63) == 0) { red[wid] = s3; red[4 + wid] = ss3; }
    __syncthreads();
    if (t == 0) {
        s3  = red[0] + red[1] + red[2] + red[3];
        ss3 = red[4] + red[5] + red[6] + red[7];
        const float m3 = s3 * (1.f / HW);
        const float v3 = ss3 * (1.f / HW) - m3 * m3;
        const float r3 = rsqrtf(v3 + 1e-5f);
        const float sc1 = g1n[c] * r3;
        stout[p * 2]     = sc1;
        stout[p * 2 + 1] = b1n[c] - m3 * sc1;
    }
}

// ---------- streaming GN3 + RK update --------------------------------------
// kin = bf16 conv2 output; GN3 finalized in-register from straw (no barrier).
// y loads are NONTEMPORAL (no L3 allocate: y re-reads are far apart and its
// allocations only evict the useful acc/YTB/XB streams).
// MODE 0: acc = y + ca*k ; w = y + cy*k -> XB
// MODE 1: acc += ca*k    ; w = y + cy*k -> XB
// MODE 2: y = acc + ca*k ; w = y_new    -> XB
template<int MODE>
__global__ __launch_bounds__(256)
void gnrk_kernel(const unsigned short* __restrict__ kin,
                 const float* __restrict__ straw,
                 const float* __restrict__ g, const float* __restrict__ bt,
                 float* __restrict__ y, float* __restrict__ acc,
                 float ca, float cy,
                 const float* __restrict__ g1n, const float* __restrict__ b1n,
                 float* __restrict__ stout, unsigned short* __restrict__ xb)
{
    const int p = blockIdx.x;
    const int c = p & 31;
    const int t = threadIdx.x;

    // in-register GN3 finalize: broadcast 8 partials, 3 shuffles, no barrier
    const float2 pr = ((const float2*)straw)[(size_t)p * 8 + (t & 7)];
    float s = pr.x, ss = pr.y;
    s += __shfl_xor(s, 1); ss += __shfl_xor(ss, 1);
    s += __shfl_xor(s, 2); ss += __shfl_xor(ss, 2);
    s += __shfl_xor(s, 4); ss += __shfl_xor(ss, 4);
    const float mean = s * (1.f / HW);
    const float var  = ss * (1.f / HW) - mean * mean;
    const float rstd = rsqrtf(var + 1e-5f);
    const float sc = g[c] * rstd;
    const float sh = bt[c] - mean * sc;

    const ushort4* kp = (const ushort4*)(kin + (size_t)p * HW);
    const f32x4* ypl = (const f32x4*)(y + (size_t)p * HW);
    f32x4* yps = (f32x4*)(y   + (size_t)p * HW);
    f32x4* ap  = (f32x4*)(acc + (size_t)p * HW);
    ushort4* xp = (ushort4*)(xb + (size_t)p * HW);
    __shared__ float red[8];
    const int wid = t >> 6;

    // ---- batch all loads first (max MLP) ----
    ushort4 ku[4];
#pragma unroll
    for (int i = 0; i < 4; ++i) ku[i] = kp[t + i * 256];
    f32x4 yv[4];
    if (MODE != 2) {
#pragma unroll
        for (int i = 0; i < 4; ++i)
            yv[i] = __builtin_nontemporal_load(ypl + t + i * 256);   // NT: no alloc
    }
    f32x4 av[4];
    if (MODE != 0) {
#pragma unroll
        for (int i = 0; i < 4; ++i) av[i] = ap[t + i * 256];
    }

    float s2 = 0.f, ss2 = 0.f;
#pragma unroll
    for (int i = 0; i < 4; ++i) {
        const int idx = t + i * 256;
        f32x4 kq;
        kq[0] = b2f(ku[i].x) * sc + sh; kq[1] = b2f(ku[i].y) * sc + sh;
        kq[2] = b2f(ku[i].z) * sc + sh; kq[3] = b2f(ku[i].w) * sc + sh;
        f32x4 w;
        if (MODE == 2) {
#pragma unroll
            for (int j = 0; j < 4; ++j) w[j] = av[i][j] + ca * kq[j];
            yps[idx] = w;
        } else {
            f32x4 a;
            if (MODE == 0) {
#pragma unroll
                for (int j = 0; j < 4; ++j) a[j] = yv[i][j] + ca * kq[j];
            } else {
                a = av[i];
#pragma unroll
                for (int j = 0; j < 4; ++j) a[j] += ca * kq[j];
            }
            ap[idx] = a;
#pragma unroll
            for (int j = 0; j < 4; ++j) w[j] = yv[i][j] + cy * kq[j];
        }
        ushort4 u;
        u.x = f2b(w[0]); u.y = f2b(w[1]); u.z = f2b(w[2]); u.w = f2b(w[3]);
        xp[idx] = u;
        // GN1 stats of NEXT stage input, on rounded values (conv1 reads bf16)
        const float r0 = b2f(u.x), r1 = b2f(u.y), r2 = b2f(u.z), r3 = b2f(u.w);
        s2  += r0 + r1 + r2 + r3;
        ss2 += r0 * r0 + r1 * r1 + r2 * r2 + r3 * r3;
    }
#pragma unroll
    for (int off = 32; off > 0; off >>= 1) {
        s2  += __shfl_xor(s2, off);
        ss2 += __shfl_xor(ss2, off);
    }
    if ((t & 63) == 0) { red[wid] = s2; red[4 + wid] = ss2; }
    __syncthreads();
    if (t == 0) {
        s2  = red[0] + red[1] + red[2] + red[3];
        ss2 = red[4] + red[5] + red[6] + red[7];
        const float m2 = s2 * (1.f / HW);
        const float v2 = ss2 * (1.f / HW) - m2 * m2;
        const float r2 = rsqrtf(v2 + 1e-5f);
        const float sc1 = g1n[c] * r2;
        stout[p * 2]     = sc1;
        stout[p * 2 + 1] = b1n[c] - m2 * sc1;
    }
}

extern "C" void kernel_launch(void* const* d_in, const int* in_sizes, int n_in,
                              void* d_out, int out_size, void* d_ws, size_t ws_size,
                              hipStream_t stream) {
    (void)in_sizes; (void)n_in; (void)out_size; (void)ws_size;
    const float* x      = (const float*)d_in[0];
    const float* ai_g1  = (const float*)d_in[1];
    const float* ai_b1  = (const float*)d_in[2];
    const float* ai_w   = (const float*)d_in[3];
    const float* ai_cb  = (const float*)d_in[4];
    const float* ai_g2  = (const float*)d_in[5];
    const float* ai_b2  = (const float*)d_in[6];
    const float* ai_g3  = (const float*)d_in[7];
    const float* ai_b3  = (const float*)d_in[8];
    const float* of_g1  = (const float*)d_in[9];
    const float* of_b1  = (const float*)d_in[10];
    const float* of_w1  = (const float*)d_in[11];
    const float* of_cb1 = (const float*)d_in[12];
    const float* of_g2  = (const float*)d_in[13];
    const float* of_b2  = (const float*)d_in[14];
    const float* of_w2  = (const float*)d_in[15];
    const float* of_cb2 = (const float*)d_in[16];
    const float* of_g3  = (const float*)d_in[17];
    const float* of_b3  = (const float*)d_in[18];

    float* y = (float*)d_out;                         // (256,32,64,64) fp32
    const size_t N  = (size_t)256 * 32 * 64 * 64;
    const size_t NH = N / 2;
    float* ws = (float*)d_ws;
    float* ACC = ws;                                  // RK accumulator (fp32)
    float* YTf = ACC;                                 // prologue-only alias
    unsigned short* Abf = (unsigned short*)(ws + N);             // conv1 out bf16
    unsigned short* XB  = (unsigned short*)(ws + N + N / 2);     // stage in bf16
    unsigned short* YTB = (unsigned short*)(ws + 2 * N);         // conv2 out bf16
    float* tail  = ws + 2 * N + N / 2;
    float* ST1    = tail;               tail += 16384;   // GN1 (sc,sh), 8192 pl
    float* ST_AI  = tail;               tail += 8192;
    float* STRAW1 = tail;               tail += 131072;  // conv1 partials
    float* STRAW2 = tail;               tail += 131072;  // conv2 partials
    unsigned short* WPai = (unsigned short*)tail;  tail += 5760;
    unsigned short* WP1  = (unsigned short*)tail;  tail += 5760;
    unsigned short* WP2  = (unsigned short*)tail;  tail += 5760;
    float* TC1  = tail;                 tail += 288;
    float* TC2  = tail;                 tail += 288;

    const float h = 0.125f;

    prep_kernel<<<1, 256, 0, stream>>>(ai_w, of_w1, of_w2, WPai, WP1, WP2, TC1, TC2);

    // ---- atten_init (batch 128): fused y=x / XB / both stat sets ----
    xstat_kernel<<<4096, 256, 0, stream>>>(x, y, XB, ai_g1, ai_b1, of_g1, of_b1,
                                           ST_AI, ST1);
    conv_kernel<0, 0, 0, 0><<<1024, 512, 0, stream>>>(XB, YTf, ST_AI, nullptr, nullptr,
                                                      WPai, ai_cb, nullptr, 0.f, nullptr);
    dgn_kernel<<<4096, 256, 0, stream>>>(YTf, y + NH, XB + NH, ai_g2, ai_b2,
                                         ai_g3, ai_b3, of_g1, of_b1, ST1 + 8192);

    auto eval = [&](float tv, float ca, float cy, int mode) {
        conv_kernel<1, 1, 1, 0><<<2048, 512, 0, stream>>>(XB, Abf, ST1, nullptr, nullptr,
                                                          WP1, of_cb1, TC1, tv, STRAW1);
        conv_kernel<1, 1, 1, 1><<<2048, 512, 0, stream>>>(Abf, YTB, STRAW1, of_g2, of_b2,
                                                          WP2, of_cb2, TC2, tv, STRAW2);
        if (mode == 0)
            gnrk_kernel<0><<<8192, 256, 0, stream>>>(YTB, STRAW2, of_g3, of_b3, y, ACC,
                                                     ca, cy, of_g1, of_b1, ST1, XB);
        else if (mode == 1)
            gnrk_kernel<1><<<8192, 256, 0, stream>>>(YTB, STRAW2, of_g3, of_b3, y, ACC,
                                                     ca, cy, of_g1, of_b1, ST1, XB);
        else
            gnrk_kernel<2><<<8192, 256, 0, stream>>>(YTB, STRAW2, of_g3, of_b3, y, ACC,
                                                     ca, cy, of_g1, of_b1, ST1, XB);
    };

    for (int s = 0; s < 8; ++s) {
        const float t0 = h * (float)s;
        eval(t0,            h / 6.f, 0.5f * h, 0);   // k1
        eval(t0 + 0.5f * h, h / 3.f, 0.5f * h, 1);   // k2
        eval(t0 + 0.5f * h, h / 3.f, h,        1);   // k3
        eval(t0 + h,        h / 6.f, 0.f,      2);   // k4
    }
}

// Round 8
// 5533.204 us; speedup vs baseline: 5.3397x; 1.0243x over previous
//
#include <hip/hip_runtime.h>

#define HW 4096            // 64*64
#define CIN 32

typedef __bf16 bf16x8 __attribute__((ext_vector_type(8)));
typedef float  f32x4  __attribute__((ext_vector_type(4)));
typedef unsigned short ushort8_v __attribute__((ext_vector_type(8)));

__device__ __forceinline__ unsigned short f2b(float f) {
    __bf16 b = (__bf16)f;                    // v_cvt, RNE
    return __builtin_bit_cast(unsigned short, b);
}
__device__ __forceinline__ float b2f(unsigned short s) {
    unsigned int u = ((unsigned int)s) << 16;
    return __builtin_bit_cast(float, u);
}
__device__ __forceinline__ bf16x8 ld_frag(const unsigned short* p) {
    ushort8_v u = *(const ushort8_v*)p;
    return __builtin_bit_cast(bf16x8, u);
}

// ---------- weight prep: WP[tap s][oc][ci pad 40] bf16; Tcls[oc][9] --------
__global__ __launch_bounds__(256)
void prep_kernel(const float* __restrict__ ai_w,
                 const float* __restrict__ of_w1,
                 const float* __restrict__ of_w2,
                 unsigned short* __restrict__ wp_ai,
                 unsigned short* __restrict__ wp1,
                 unsigned short* __restrict__ wp2,
                 float* __restrict__ tc1, float* __restrict__ tc2)
{
    const int t = threadIdx.x;
    for (int i = t; i < 9 * 32 * 40; i += 256) {
        const int s = i / 1280;
        const int rem = i - s * 1280;
        const int oc = rem / 40;
        const int ci = rem - oc * 40;
        unsigned short va = 0, v1 = 0, v2 = 0;
        if (ci < 32) {
            va = f2b(ai_w[(oc * 32 + ci) * 9 + s]);
            v1 = f2b(of_w1[(oc * 33 + ci + 1) * 9 + s]);
            v2 = f2b(of_w2[(oc * 33 + ci + 1) * 9 + s]);
        }
        wp_ai[i] = va; wp1[i] = v1; wp2[i] = v2;
    }
    for (int i = t; i < 32 * 9; i += 256) {
        const int oc = i / 9;
        const int cls = i - oc * 9;
        const int rc = cls / 3, cc = cls - rc * 3;
        float s1 = 0.f, s2 = 0.f;
        for (int ky = 0; ky < 3; ++ky) {
            if ((rc == 0 && ky == 0) || (rc == 2 && ky == 2)) continue;
            for (int kx = 0; kx < 3; ++kx) {
                if ((cc == 0 && kx == 0) || (cc == 2 && kx == 2)) continue;
                s1 += of_w1[(oc * 33) * 9 + ky * 3 + kx];
                s2 += of_w2[(oc * 33) * 9 + ky * 3 + kx];
            }
        }
        tc1[i] = s1; tc2[i] = s2;
    }
}

// ---------- fused prologue: y=x, XB=bf16(x), GN stats for ai_g1 AND of_g1 --
__global__ __launch_bounds__(256)
void xstat_kernel(const float* __restrict__ x, float* __restrict__ y,
                  unsigned short* __restrict__ xb,
                  const float* __restrict__ g_ai, const float* __restrict__ b_ai,
                  const float* __restrict__ g_of, const float* __restrict__ b_of,
                  float* __restrict__ st_ai, float* __restrict__ st_of)
{
    const int p = blockIdx.x;          // 4096 planes (batch-128 half)
    const int c = p & 31;
    const int t = threadIdx.x;
    const float4* ip = (const float4*)(x + (size_t)p * HW);
    float4* yp = (float4*)(y + (size_t)p * HW);
    ushort4* xp = (ushort4*)(xb + (size_t)p * HW);
    float s = 0.f, ss = 0.f;
#pragma unroll
    for (int i = 0; i < 4; ++i) {
        const float4 q = ip[t + i * 256];
        yp[t + i * 256] = q;
        ushort4 u; u.x = f2b(q.x); u.y = f2b(q.y); u.z = f2b(q.z); u.w = f2b(q.w);
        xp[t + i * 256] = u;
        s += q.x + q.y + q.z + q.w;
        ss += q.x * q.x + q.y * q.y + q.z * q.z + q.w * q.w;
    }
#pragma unroll
    for (int off = 32; off > 0; off >>= 1) {
        s  += __shfl_xor(s, off);
        ss += __shfl_xor(ss, off);
    }
    __shared__ float red[8];
    const int wid = t >> 6;
    if ((t & 63) == 0) { red[wid] = s; red[4 + wid] = ss; }
    __syncthreads();
    if (t == 0) {
        s  = red[0] + red[1] + red[2] + red[3];
        ss = red[4] + red[5] + red[6] + red[7];
        const float mean = s * (1.f / HW);
        const float var  = ss * (1.f / HW) - mean * mean;
        const float rstd = rsqrtf(var + 1e-5f);
        const float sa = g_ai[c] * rstd;
        st_ai[p * 2]     = sa;
        st_ai[p * 2 + 1] = b_ai[c] - mean * sa;
        const float so = g_of[c] * rstd;
        st_of[p * 2]     = so;
        st_of[p * 2 + 1] = b_of[c] - mean * so;
    }
}

// ---------- MFMA implicit-GEMM conv 3x3 ------------------------------------
// 512 thr = 8 waves; block = (b, 8 output rows). Wave wid = one row of 64 px.
// A = pixel tile (LDS, gather-staged, GN+ReLU fused), B = weights (registers).
// Staging task = (cgroup, row, w-quad): 8 x ushort4 coalesced loads ->
// register transpose -> 4 x ds_write_b128. 10 VMEM/thread (was 40 scalar).
// FIN=0: st = per-plane (sc,sh). FIN=1: st = raw partials [plane][8][2].
template<int HAS_TIME, int STATS, int OUT_BF16, int FIN>
__global__ __launch_bounds__(512)
void conv_kernel(const unsigned short* __restrict__ in, void* __restrict__ outv,
                 const float* __restrict__ st,
                 const float* __restrict__ fg, const float* __restrict__ fb,
                 const unsigned short* __restrict__ wp,
                 const float* __restrict__ cb, const float* __restrict__ tcls,
                 float tval, float* __restrict__ straw)
{
    const int blk = blockIdx.x;
    const int b  = blk >> 3;
    const int hb = blk & 7;
    const int h0 = hb * 8;
    const int t  = threadIdx.x;
    const int l  = t & 63;
    const int wid = t >> 6;            // 0..7 = output row
    const int lm = l & 15;
    const int lg = l >> 4;

    __shared__ unsigned short tile[10 * 66 * 40];   // 52800 B
    __shared__ float sst[64];                        // (sc,sh) per ci

    // ---- GN scale/shift table ----
    if (FIN) {
        float s = 0.f, ss = 0.f;
        if (t < 256) {
            const float2 pr = ((const float2*)st)[(size_t)(b * 32 + (t >> 3)) * 8 + (t & 7)];
            s = pr.x; ss = pr.y;
        }
        s += __shfl_xor(s, 1); ss += __shfl_xor(ss, 1);
        s += __shfl_xor(s, 2); ss += __shfl_xor(ss, 2);
        s += __shfl_xor(s, 4); ss += __shfl_xor(ss, 4);
        if (t < 256 && (t & 7) == 0) {
            const int ci = t >> 3;
            const float mean = s * (1.f / HW);
            const float var  = ss * (1.f / HW) - mean * mean;
            const float rstd = rsqrtf(var + 1e-5f);
            const float sc = fg[ci] * rstd;
            sst[ci * 2]     = sc;
            sst[ci * 2 + 1] = fb[ci] - mean * sc;
        }
    } else {
        if (t < 64) sst[t] = st[b * 64 + t];
    }

    // ---- weight fragments into registers: wreg[nt][tap] ----
    bf16x8 wreg[2][9];
    {
        const unsigned short* wb = wp + (size_t)(lm * 40 + 8 * lg);
#pragma unroll
        for (int nt = 0; nt < 2; ++nt)
#pragma unroll
            for (int s = 0; s < 9; ++s)
                wreg[nt][s] = ld_frag(wb + s * 1280 + nt * 640);
    }
    __syncthreads();   // sst ready

    // ---- stage: 640 w-quad tasks; 8 x ushort4 loads -> 4 x ds_write_b128 --
    const unsigned short* inb = in + (size_t)b * (CIN * HW);
#pragma unroll
    for (int tau = t; tau < 640; tau += 512) {
        const int g = tau / 160;           // channel group (8 ci)
        const int rem = tau - g * 160;
        const int r = rem >> 4;            // tile row 0..9
        const int wq = rem & 15;           // w-quad 0..15
        const int hh = h0 - 1 + r;
        unsigned short* dst = &tile[(r * 66 + wq * 4 + 1) * 40 + 8 * g];
        if (hh >= 0 && hh < 64) {
            const unsigned short* src = inb + (size_t)(8 * g) * HW + hh * 64 + wq * 4;
            ushort4 U[8];
#pragma unroll
            for (int j = 0; j < 8; ++j) U[j] = *(const ushort4*)(src + (size_t)j * HW);
            float scv[8], shv[8];
#pragma unroll
            for (int j = 0; j < 8; ++j) {
                const float2 s2 = *(const float2*)(&sst[(8 * g + j) * 2]);
                scv[j] = s2.x; shv[j] = s2.y;
            }
#pragma unroll
            for (int k = 0; k < 4; ++k) {
                ushort8_v F;
#pragma unroll
                for (int j = 0; j < 8; ++j) {
                    const unsigned short e = ((const unsigned short*)&U[j])[k];
                    F[j] = f2b(fmaxf(b2f(e) * scv[j] + shv[j], 0.f));
                }
                *(ushort8_v*)(dst + k * 40) = F;
            }
        } else {
            const ushort8_v z = {0, 0, 0, 0, 0, 0, 0, 0};
#pragma unroll
            for (int k = 0; k < 4; ++k) *(ushort8_v*)(dst + k * 40) = z;
        }
    }
    if (t < 80) {   // zero pad columns w''=0,65
        const int g = t & 3;
        const int rr = t >> 2;
        const int r = rr >> 1;
        const int col = (rr & 1) ? 65 : 0;
        const ushort8_v z = {0, 0, 0, 0, 0, 0, 0, 0};
        *(ushort8_v*)&tile[(r * 66 + col) * 40 + 8 * g] = z;
    }
    __syncthreads();

    // ---- K loop: 9 taps x 4 M-tiles, weights from regs ----
    f32x4 acc[4][2];
#pragma unroll
    for (int mt = 0; mt < 4; ++mt)
#pragma unroll
        for (int nt = 0; nt < 2; ++nt) acc[mt][nt] = (f32x4){0.f, 0.f, 0.f, 0.f};

#pragma unroll
    for (int ky = 0; ky < 3; ++ky)
#pragma unroll
        for (int kx = 0; kx < 3; ++kx) {
            const int s = ky * 3 + kx;
            const int base = ((wid + ky) * 66 + kx + lm) * 40 + 8 * lg;
#pragma unroll
            for (int mt = 0; mt < 4; ++mt) {
                const bf16x8 a = ld_frag(&tile[base + mt * 640]);
                acc[mt][0] = __builtin_amdgcn_mfma_f32_16x16x32_bf16(a, wreg[0][s], acc[mt][0], 0, 0, 0);
                acc[mt][1] = __builtin_amdgcn_mfma_f32_16x16x32_bf16(a, wreg[1][s], acc[mt][1], 0, 0, 0);
            }
        }

    // ---- epilogue ----
    const int h = h0 + wid;
    const int rc = (h == 0) ? 0 : ((h == 63) ? 2 : 1);
    float bias_[2], tcn[2], tc0[2], tc2[2];
#pragma unroll
    for (int nt = 0; nt < 2; ++nt) {
        const int oc = nt * 16 + lm;
        bias_[nt] = cb[oc];
        if (HAS_TIME) {
            tcn[nt] = tcls[oc * 9 + rc * 3 + 1];
            tc0[nt] = tcls[oc * 9 + rc * 3 + 0];
            tc2[nt] = tcls[oc * 9 + rc * 3 + 2];
        }
    }
    float sl[2] = {0.f, 0.f}, ssl[2] = {0.f, 0.f};
    float* outf = (float*)outv;
    unsigned short* outb = (unsigned short*)outv;
#pragma unroll
    for (int mt = 0; mt < 4; ++mt) {
#pragma unroll
        for (int nt = 0; nt < 2; ++nt) {
            const int oc = nt * 16 + lm;
            float v[4];
#pragma unroll
            for (int r = 0; r < 4; ++r) {
                v[r] = acc[mt][nt][r] + bias_[nt];
                if (HAS_TIME) v[r] += tval * tcn[nt];
            }
            if (HAS_TIME && mt == 0 && lg == 0) v[0] += tval * (tc0[nt] - tcn[nt]);
            if (HAS_TIME && mt == 3 && lg == 3) v[3] += tval * (tc2[nt] - tcn[nt]);
            const int w0 = mt * 16 + lg * 4;
            const size_t o = ((size_t)(b * 32 + oc)) * HW + (size_t)h * 64 + w0;
            if (OUT_BF16) {
                ushort4 u;
                u.x = f2b(v[0]); u.y = f2b(v[1]); u.z = f2b(v[2]); u.w = f2b(v[3]);
                *(ushort4*)&outb[o] = u;
                if (STATS) {   // stats on rounded values (consumer reads bf16)
#pragma unroll
                    for (int r = 0; r < 4; ++r) {
                        const float vr = b2f(f2b(v[r]));
                        sl[nt] += vr; ssl[nt] += vr * vr;
                    }
                }
            } else {
                float4 q; q.x = v[0]; q.y = v[1]; q.z = v[2]; q.w = v[3];
                *(float4*)&outf[o] = q;
                if (STATS) {
#pragma unroll
                    for (int r = 0; r < 4; ++r) { sl[nt] += v[r]; ssl[nt] += v[r] * v[r]; }
                }
            }
        }
    }
    if (STATS) {
        float s0 = sl[0], q0 = ssl[0], s1 = sl[1], q1 = ssl[1];
        s0 += __shfl_xor(s0, 16); s0 += __shfl_xor(s0, 32);
        q0 += __shfl_xor(q0, 16); q0 += __shfl_xor(q0, 32);
        s1 += __shfl_xor(s1, 16); s1 += __shfl_xor(s1, 32);
        q1 += __shfl_xor(q1, 16); q1 += __shfl_xor(q1, 32);
        __syncthreads();                       // tile no longer needed
        float* red = (float*)tile;             // [0..255]=S, [256..511]=SS
        if (lg == 0) {
            red[wid * 32 + lm]       = s0;  red[256 + wid * 32 + lm]       = q0;
            red[wid * 32 + 16 + lm]  = s1;  red[256 + wid * 32 + 16 + lm]  = q1;
        }
        __syncthreads();
        if (t < 32) {
            float S = 0.f, Q = 0.f;
#pragma unroll
            for (int w = 0; w < 8; ++w) { S += red[w * 32 + t]; Q += red[256 + w * 32 + t]; }
            float* dst = straw + ((size_t)(b * 32 + t) * 8 + hb) * 2;
            dst[0] = S; dst[1] = Q;
        }
    }
}

// ---------- atten_init tail: gn2+relu -> gn3; fp32 + bf16 out + GN1 stats --
__global__ __launch_bounds__(256)
void dgn_kernel(const float* __restrict__ in, float* __restrict__ out,
                unsigned short* __restrict__ xbout,
                const float* __restrict__ g2, const float* __restrict__ b2,
                const float* __restrict__ g3, const float* __restrict__ b3,
                const float* __restrict__ g1n, const float* __restrict__ b1n,
                float* __restrict__ stout)
{
    const int p = blockIdx.x;
    const int c = p & 31;
    const int t = threadIdx.x;
    const float4* ip = (const float4*)(in + (size_t)p * HW);
    float4* op = (float4*)(out + (size_t)p * HW);
    ushort4* xp = (ushort4*)(xbout + (size_t)p * HW);
    __shared__ float red[8];
    const int wid = t >> 6;

    float4 v[4];
    float s = 0.f, ss = 0.f;
#pragma unroll
    for (int i = 0; i < 4; ++i) {
        float4 q = ip[t + i * 256];
        v[i] = q;
        s += q.x + q.y + q.z + q.w;
        ss += q.x * q.x + q.y * q.y + q.z * q.z + q.w * q.w;
    }
#pragma unroll
    for (int off = 32; off > 0; off >>= 1) {
        s  += __shfl_xor(s, off);
        ss += __shfl_xor(ss, off);
    }
    if ((t & 63) == 0) { red[wid] = s; red[4 + wid] = ss; }
    __syncthreads();
    s  = red[0] + red[1] + red[2] + red[3];
    ss = red[4] + red[5] + red[6] + red[7];
    float mean = s * (1.f / HW);
    float var  = ss * (1.f / HW) - mean * mean;
    float rstd = rsqrtf(var + 1e-5f);
    float sc = g2[c] * rstd;
    float sh = b2[c] - mean * sc;

    s = 0.f; ss = 0.f;
#pragma unroll
    for (int i = 0; i < 4; ++i) {
        float4 q = v[i];
        q.x = fmaxf(q.x * sc + sh, 0.f); q.y = fmaxf(q.y * sc + sh, 0.f);
        q.z = fmaxf(q.z * sc + sh, 0.f); q.w = fmaxf(q.w * sc + sh, 0.f);
        v[i] = q;
        s += q.x + q.y + q.z + q.w;
        ss += q.x * q.x + q.y * q.y + q.z * q.z + q.w * q.w;
    }
#pragma unroll
    for (int off = 32; off > 0; off >>= 1) {
        s  += __shfl_xor(s, off);
        ss += __shfl_xor(ss, off);
    }
    __syncthreads();
    if ((t & 63) == 0) { red[wid] = s; red[4 + wid] = ss; }
    __syncthreads();
    s  = red[0] + red[1] + red[2] + red[3];
    ss = red[4] + red[5] + red[6] + red[7];
    mean = s * (1.f / HW);
    var  = ss * (1.f / HW) - mean * mean;
    rstd = rsqrtf(var + 1e-5f);
    sc = g3[c] * rstd;
    sh = b3[c] - mean * sc;

    float s3 = 0.f, ss3 = 0.f;
#pragma unroll
    for (int i = 0; i < 4; ++i) {
        float4 q = v[i];
        q.x = q.x * sc + sh; q.y = q.y * sc + sh;
        q.z = q.z * sc + sh; q.w = q.w * sc + sh;
        op[t + i * 256] = q;
        ushort4 u; u.x = f2b(q.x); u.y = f2b(q.y); u.z = f2b(q.z); u.w = f2b(q.w);
        xp[t + i * 256] = u;
        s3 += q.x + q.y + q.z + q.w;
        ss3 += q.x * q.x + q.y * q.y + q.z * q.z + q.w * q.w;
    }
#pragma unroll
    for (int off = 32; off > 0; off >>= 1) {
        s3  += __shfl_xor(s3, off);
        ss3 += __shfl_xor(ss3, off);
    }
    __syncthreads();
    if ((t & 63) == 0) { red[wid] = s3; red[4 + wid] = ss3; }
    __syncthreads();
    if (t == 0) {
        s3  = red[0] + red[1] + red[2] + red[3];
        ss3 = red[4] + red[5] + red[6] + red[7];
        const float m3 = s3 * (1.f / HW);
        const float v3 = ss3 * (1.f / HW) - m3 * m3;
        const float r3 = rsqrtf(v3 + 1e-5f);
        const float sc1 = g1n[c] * r3;
        stout[p * 2]     = sc1;
        stout[p * 2 + 1] = b1n[c] - m3 * sc1;
    }
}

// ---------- streaming GN3 + RK update --------------------------------------
// kin = bf16 conv2 output; GN3 finalized in-register from straw (no barrier).
// y loads are NONTEMPORAL (no L3 allocate).
// MODE 0: acc = y + ca*k ; w = y + cy*k -> XB
// MODE 1: acc += ca*k    ; w = y + cy*k -> XB
// MODE 2: y = acc + ca*k ; w = y_new    -> XB
template<int MODE>
__global__ __launch_bounds__(256)
void gnrk_kernel(const unsigned short* __restrict__ kin,
                 const float* __restrict__ straw,
                 const float* __restrict__ g, const float* __restrict__ bt,
                 float* __restrict__ y, float* __restrict__ acc,
                 float ca, float cy,
                 const float* __restrict__ g1n, const float* __restrict__ b1n,
                 float* __restrict__ stout, unsigned short* __restrict__ xb)
{
    const int p = blockIdx.x;
    const int c = p & 31;
    const int t = threadIdx.x;

    // in-register GN3 finalize: broadcast 8 partials, 3 shuffles, no barrier
    const float2 pr = ((const float2*)straw)[(size_t)p * 8 + (t & 7)];
    float s = pr.x, ss = pr.y;
    s += __shfl_xor(s, 1); ss += __shfl_xor(ss, 1);
    s += __shfl_xor(s, 2); ss += __shfl_xor(ss, 2);
    s += __shfl_xor(s, 4); ss += __shfl_xor(ss, 4);
    const float mean = s * (1.f / HW);
    const float var  = ss * (1.f / HW) - mean * mean;
    const float rstd = rsqrtf(var + 1e-5f);
    const float sc = g[c] * rstd;
    const float sh = bt[c] - mean * sc;

    const ushort4* kp = (const ushort4*)(kin + (size_t)p * HW);
    const f32x4* ypl = (const f32x4*)(y + (size_t)p * HW);
    f32x4* yps = (f32x4*)(y   + (size_t)p * HW);
    f32x4* ap  = (f32x4*)(acc + (size_t)p * HW);
    ushort4* xp = (ushort4*)(xb + (size_t)p * HW);
    __shared__ float red[8];
    const int wid = t >> 6;

    // ---- batch all loads first (max MLP) ----
    ushort4 ku[4];
#pragma unroll
    for (int i = 0; i < 4; ++i) ku[i] = kp[t + i * 256];
    f32x4 yv[4];
    if (MODE != 2) {
#pragma unroll
        for (int i = 0; i < 4; ++i)
            yv[i] = __builtin_nontemporal_load(ypl + t + i * 256);   // NT: no alloc
    }
    f32x4 av[4];
    if (MODE != 0) {
#pragma unroll
        for (int i = 0; i < 4; ++i) av[i] = ap[t + i * 256];
    }

    float s2 = 0.f, ss2 = 0.f;
#pragma unroll
    for (int i = 0; i < 4; ++i) {
        const int idx = t + i * 256;
        f32x4 kq;
        kq[0] = b2f(ku[i].x) * sc + sh; kq[1] = b2f(ku[i].y) * sc + sh;
        kq[2] = b2f(ku[i].z) * sc + sh; kq[3] = b2f(ku[i].w) * sc + sh;
        f32x4 w;
        if (MODE == 2) {
#pragma unroll
            for (int j = 0; j < 4; ++j) w[j] = av[i][j] + ca * kq[j];
            yps[idx] = w;
        } else {
            f32x4 a;
            if (MODE == 0) {
#pragma unroll
                for (int j = 0; j < 4; ++j) a[j] = yv[i][j] + ca * kq[j];
            } else {
                a = av[i];
#pragma unroll
                for (int j = 0; j < 4; ++j) a[j] += ca * kq[j];
            }
            ap[idx] = a;
#pragma unroll
            for (int j = 0; j < 4; ++j) w[j] = yv[i][j] + cy * kq[j];
        }
        ushort4 u;
        u.x = f2b(w[0]); u.y = f2b(w[1]); u.z = f2b(w[2]); u.w = f2b(w[3]);
        xp[idx] = u;
        // GN1 stats of NEXT stage input, on rounded values (conv1 reads bf16)
        const float r0 = b2f(u.x), r1 = b2f(u.y), r2 = b2f(u.z), r3 = b2f(u.w);
        s2  += r0 + r1 + r2 + r3;
        ss2 += r0 * r0 + r1 * r1 + r2 * r2 + r3 * r3;
    }
#pragma unroll
    for (int off = 32; off > 0; off >>= 1) {
        s2  += __shfl_xor(s2, off);
        ss2 += __shfl_xor(ss2, off);
    }
    if ((t & 63) == 0) { red[wid] = s2; red[4 + wid] = ss2; }
    __syncthreads();
    if (t == 0) {
        s2  = red[0] + red[1] + red[2] + red[3];
        ss2 = red[4] + red[5] + red[6] + red[7];
        const float m2 = s2 * (1.f / HW);
        const float v2 = ss2 * (1.f / HW) - m2 * m2;
        const float r2 = rsqrtf(v2 + 1e-5f);
        const float sc1 = g1n[c] * r2;
        stout[p * 2]     = sc1;
        stout[p * 2 + 1] = b1n[c] - m2 * sc1;
    }
}

extern "C" void kernel_launch(void* const* d_in, const int* in_sizes, int n_in,
                              void* d_out, int out_size, void* d_ws, size_t ws_size,
                              hipStream_t stream) {
    (void)in_sizes; (void)n_in; (void)out_size; (void)ws_size;
    const float* x      = (const float*)d_in[0];
    const float* ai_g1  = (const float*)d_in[1];
    const float* ai_b1  = (const float*)d_in[2];
    const float* ai_w   = (const float*)d_in[3];
    const float* ai_cb  = (const float*)d_in[4];
    const float* ai_g2  = (const float*)d_in[5];
    const float* ai_b2  = (const float*)d_in[6];
    const float* ai_g3  = (const float*)d_in[7];
    const float* ai_b3  = (const float*)d_in[8];
    const float* of_g1  = (const float*)d_in[9];
    const float* of_b1  = (const float*)d_in[10];
    const float* of_w1  = (const float*)d_in[11];
    const float* of_cb1 = (const float*)d_in[12];
    const float* of_g2  = (const float*)d_in[13];
    const float* of_b2  = (const float*)d_in[14];
    const float* of_w2  = (const float*)d_in[15];
    const float* of_cb2 = (const float*)d_in[16];
    const float* of_g3  = (const float*)d_in[17];
    const float* of_b3  = (const float*)d_in[18];

    float* y = (float*)d_out;                         // (256,32,64,64) fp32
    const size_t N  = (size_t)256 * 32 * 64 * 64;
    const size_t NH = N / 2;
    float* ws = (float*)d_ws;
    float* ACC = ws;                                  // RK accumulator (fp32)
    float* YTf = ACC;                                 // prologue-only alias
    unsigned short* Abf = (unsigned short*)(ws + N);             // conv1 out bf16
    unsigned short* XB  = (unsigned short*)(ws + N + N / 2);     // stage in bf16
    unsigned short* YTB = (unsigned short*)(ws + 2 * N);         // conv2 out bf16
    float* tail  = ws + 2 * N + N / 2;
    float* ST1    = tail;               tail += 16384;   // GN1 (sc,sh), 8192 pl
    float* ST_AI  = tail;               tail += 8192;
    float* STRAW1 = tail;               tail += 131072;  // conv1 partials
    float* STRAW2 = tail;               tail += 131072;  // conv2 partials
    unsigned short* WPai = (unsigned short*)tail;  tail += 5760;
    unsigned short* WP1  = (unsigned short*)tail;  tail += 5760;
    unsigned short* WP2  = (unsigned short*)tail;  tail += 5760;
    float* TC1  = tail;                 tail += 288;
    float* TC2  = tail;                 tail += 288;

    const float h = 0.125f;

    prep_kernel<<<1, 256, 0, stream>>>(ai_w, of_w1, of_w2, WPai, WP1, WP2, TC1, TC2);

    // ---- atten_init (batch 128): fused y=x / XB / both stat sets ----
    xstat_kernel<<<4096, 256, 0, stream>>>(x, y, XB, ai_g1, ai_b1, of_g1, of_b1,
                                           ST_AI, ST1);
    conv_kernel<0, 0, 0, 0><<<1024, 512, 0, stream>>>(XB, YTf, ST_AI, nullptr, nullptr,
                                                      WPai, ai_cb, nullptr, 0.f, nullptr);
    dgn_kernel<<<4096, 256, 0, stream>>>(YTf, y + NH, XB + NH, ai_g2, ai_b2,
                                         ai_g3, ai_b3, of_g1, of_b1, ST1 + 8192);

    auto eval = [&](float tv, float ca, float cy, int mode) {
        conv_kernel<1, 1, 1, 0><<<2048, 512, 0, stream>>>(XB, Abf, ST1, nullptr, nullptr,
                                                          WP1, of_cb1, TC1, tv, STRAW1);
        conv_kernel<1, 1, 1, 1><<<2048, 512, 0, stream>>>(Abf, YTB, STRAW1, of_g2, of_b2,
                                                          WP2, of_cb2, TC2, tv, STRAW2);
        if (mode == 0)
            gnrk_kernel<0><<<8192, 256, 0, stream>>>(YTB, STRAW2, of_g3, of_b3, y, ACC,
                                                     ca, cy, of_g1, of_b1, ST1, XB);
        else if (mode == 1)
            gnrk_kernel<1><<<8192, 256, 0, stream>>>(YTB, STRAW2, of_g3, of_b3, y, ACC,
                                                     ca, cy, of_g1, of_b1, ST1, XB);
        else
            gnrk_kernel<2><<<8192, 256, 0, stream>>>(YTB, STRAW2, of_g3, of_b3, y, ACC,
                                                     ca, cy, of_g1, of_b1, ST1, XB);
    };

    for (int s = 0; s < 8; ++s) {
        const float t0 = h * (float)s;
        eval(t0,            h / 6.f, 0.5f * h, 0);   // k1
        eval(t0 + 0.5f * h, h / 3.f, 0.5f * h, 1);   // k2
        eval(t0 + 0.5f * h, h / 3.f, h,        1);   // k3
        eval(t0 + h,        h / 6.f, 0.f,      2);   // k4
    }
}

// Round 10
// 5493.201 us; speedup vs baseline: 5.3786x; 1.0073x over previous
//
#include <hip/hip_runtime.h>

#define HW 4096            // 64*64
#define CIN 32

typedef __bf16 bf16x8 __attribute__((ext_vector_type(8)));
typedef float  f32x4  __attribute__((ext_vector_type(4)));
typedef unsigned short ushort8_v __attribute__((ext_vector_type(8)));

__device__ __forceinline__ unsigned short f2b(float f) {
    __bf16 b = (__bf16)f;                    // v_cvt, RNE
    return __builtin_bit_cast(unsigned short, b);
}
__device__ __forceinline__ float b2f(unsigned short s) {
    unsigned int u = ((unsigned int)s) << 16;
    return __builtin_bit_cast(float, u);
}
__device__ __forceinline__ bf16x8 ld_frag(const unsigned short* p) {
    ushort8_v u = *(const ushort8_v*)p;
    return __builtin_bit_cast(bf16x8, u);
}

// ---------- weight prep: WP[tap s][oc][ci pad 40] bf16; Tcls[oc][9] --------
__global__ __launch_bounds__(256)
void prep_kernel(const float* __restrict__ ai_w,
                 const float* __restrict__ of_w1,
                 const float* __restrict__ of_w2,
                 unsigned short* __restrict__ wp_ai,
                 unsigned short* __restrict__ wp1,
                 unsigned short* __restrict__ wp2,
                 float* __restrict__ tc1, float* __restrict__ tc2)
{
    const int t = threadIdx.x;
    for (int i = t; i < 9 * 32 * 40; i += 256) {
        const int s = i / 1280;
        const int rem = i - s * 1280;
        const int oc = rem / 40;
        const int ci = rem - oc * 40;
        unsigned short va = 0, v1 = 0, v2 = 0;
        if (ci < 32) {
            va = f2b(ai_w[(oc * 32 + ci) * 9 + s]);
            v1 = f2b(of_w1[(oc * 33 + ci + 1) * 9 + s]);
            v2 = f2b(of_w2[(oc * 33 + ci + 1) * 9 + s]);
        }
        wp_ai[i] = va; wp1[i] = v1; wp2[i] = v2;
    }
    for (int i = t; i < 32 * 9; i += 256) {
        const int oc = i / 9;
        const int cls = i - oc * 9;
        const int rc = cls / 3, cc = cls - rc * 3;
        float s1 = 0.f, s2 = 0.f;
        for (int ky = 0; ky < 3; ++ky) {
            if ((rc == 0 && ky == 0) || (rc == 2 && ky == 2)) continue;
            for (int kx = 0; kx < 3; ++kx) {
                if ((cc == 0 && kx == 0) || (cc == 2 && kx == 2)) continue;
                s1 += of_w1[(oc * 33) * 9 + ky * 3 + kx];
                s2 += of_w2[(oc * 33) * 9 + ky * 3 + kx];
            }
        }
        tc1[i] = s1; tc2[i] = s2;
    }
}

// ---------- fused prologue: y=x, XB=bf16(x), GN stats (ai_g1 AND of_g1) ----
__global__ __launch_bounds__(256)
void xstat_kernel(const float* __restrict__ x, float* __restrict__ y,
                  unsigned short* __restrict__ xb,
                  const float* __restrict__ g_ai, const float* __restrict__ b_ai,
                  const float* __restrict__ g_of, const float* __restrict__ b_of,
                  float* __restrict__ st_ai, float* __restrict__ st_of)
{
    const int p = blockIdx.x;          // 4096 planes (batch-128 half)
    const int c = p & 31;
    const int t = threadIdx.x;
    const float4* ip = (const float4*)(x + (size_t)p * HW);
    float4* yp = (float4*)(y + (size_t)p * HW);
    ushort4* xp = (ushort4*)(xb + (size_t)p * HW);
    float s = 0.f, ss = 0.f;
#pragma unroll
    for (int i = 0; i < 4; ++i) {
        const float4 q = ip[t + i * 256];
        yp[t + i * 256] = q;
        ushort4 u; u.x = f2b(q.x); u.y = f2b(q.y); u.z = f2b(q.z); u.w = f2b(q.w);
        xp[t + i * 256] = u;
        s += q.x + q.y + q.z + q.w;
        ss += q.x * q.x + q.y * q.y + q.z * q.z + q.w * q.w;
    }
#pragma unroll
    for (int off = 32; off > 0; off >>= 1) {
        s  += __shfl_xor(s, off);
        ss += __shfl_xor(ss, off);
    }
    __shared__ float red[8];
    const int wid = t >> 6;
    if ((t & 63) == 0) { red[wid] = s; red[4 + wid] = ss; }
    __syncthreads();
    if (t == 0) {
        s  = red[0] + red[1] + red[2] + red[3];
        ss = red[4] + red[5] + red[6] + red[7];
        const float mean = s * (1.f / HW);
        const float var  = ss * (1.f / HW) - mean * mean;
        const float rstd = rsqrtf(var + 1e-5f);
        const float sa = g_ai[c] * rstd;
        st_ai[p * 2]     = sa;
        st_ai[p * 2 + 1] = b_ai[c] - mean * sa;
        const float so = g_of[c] * rstd;
        st_of[p * 2]     = so;
        st_of[p * 2 + 1] = b_of[c] - mean * so;
    }
}

// ---------- MFMA implicit-GEMM conv 3x3 ------------------------------------
// 512 thr = 8 waves; block = (b, 8 output rows). Wave wid = one row of 64 px.
// A = pixel tile (LDS, gather-staged, GN+ReLU fused), B = weights (registers).
// FIN=0: st = per-plane (sc,sh). FIN=1: st = raw partials [plane][8][2].
template<int HAS_TIME, int STATS, int OUT_BF16, int FIN>
__global__ __launch_bounds__(512)
void conv_kernel(const unsigned short* __restrict__ in, void* __restrict__ outv,
                 const float* __restrict__ st,
                 const float* __restrict__ fg, const float* __restrict__ fb,
                 const unsigned short* __restrict__ wp,
                 const float* __restrict__ cb, const float* __restrict__ tcls,
                 float tval, float* __restrict__ straw)
{
    const int blk = blockIdx.x;
    const int b  = blk >> 3;
    const int hb = blk & 7;
    const int h0 = hb * 8;
    const int t  = threadIdx.x;
    const int l  = t & 63;
    const int wid = t >> 6;            // 0..7 = output row
    const int lm = l & 15;
    const int lg = l >> 4;

    __shared__ unsigned short tile[10 * 66 * 40];   // 52800 B
    __shared__ float sst[64];                        // (sc,sh) per ci

    // ---- GN scale/shift table ----
    if (FIN) {
        float s = 0.f, ss = 0.f;
        if (t < 256) {
            const float2 pr = ((const float2*)st)[(size_t)(b * 32 + (t >> 3)) * 8 + (t & 7)];
            s = pr.x; ss = pr.y;
        }
        s += __shfl_xor(s, 1); ss += __shfl_xor(ss, 1);
        s += __shfl_xor(s, 2); ss += __shfl_xor(ss, 2);
        s += __shfl_xor(s, 4); ss += __shfl_xor(ss, 4);
        if (t < 256 && (t & 7) == 0) {
            const int ci = t >> 3;
            const float mean = s * (1.f / HW);
            const float var  = ss * (1.f / HW) - mean * mean;
            const float rstd = rsqrtf(var + 1e-5f);
            const float sc = fg[ci] * rstd;
            sst[ci * 2]     = sc;
            sst[ci * 2 + 1] = fb[ci] - mean * sc;
        }
    } else {
        if (t < 64) sst[t] = st[b * 64 + t];
    }

    // ---- weight fragments into registers: wreg[nt][tap] ----
    bf16x8 wreg[2][9];
    {
        const unsigned short* wb = wp + (size_t)(lm * 40 + 8 * lg);
#pragma unroll
        for (int nt = 0; nt < 2; ++nt)
#pragma unroll
            for (int s = 0; s < 9; ++s)
                wreg[nt][s] = ld_frag(wb + s * 1280 + nt * 640);
    }
    __syncthreads();   // sst ready

    // ---- stage: 640 w-quad tasks; 8 x ushort4 loads -> 4 x ds_write_b128 --
    const unsigned short* inb = in + (size_t)b * (CIN * HW);
#pragma unroll
    for (int tau = t; tau < 640; tau += 512) {
        const int g = tau / 160;           // channel group (8 ci)
        const int rem = tau - g * 160;
        const int r = rem >> 4;            // tile row 0..9
        const int wq = rem & 15;           // w-quad 0..15
        const int hh = h0 - 1 + r;
        unsigned short* dst = &tile[(r * 66 + wq * 4 + 1) * 40 + 8 * g];
        if (hh >= 0 && hh < 64) {
            const unsigned short* src = inb + (size_t)(8 * g) * HW + hh * 64 + wq * 4;
            ushort4 U[8];
#pragma unroll
            for (int j = 0; j < 8; ++j) U[j] = *(const ushort4*)(src + (size_t)j * HW);
            float scv[8], shv[8];
#pragma unroll
            for (int j = 0; j < 8; ++j) {
                const float2 s2 = *(const float2*)(&sst[(8 * g + j) * 2]);
                scv[j] = s2.x; shv[j] = s2.y;
            }
#pragma unroll
            for (int k = 0; k < 4; ++k) {
                ushort8_v F;
#pragma unroll
                for (int j = 0; j < 8; ++j) {
                    const unsigned short e = ((const unsigned short*)&U[j])[k];
                    F[j] = f2b(fmaxf(b2f(e) * scv[j] + shv[j], 0.f));
                }
                *(ushort8_v*)(dst + k * 40) = F;
            }
        } else {
            const ushort8_v z = {0, 0, 0, 0, 0, 0, 0, 0};
#pragma unroll
            for (int k = 0; k < 4; ++k) *(ushort8_v*)(dst + k * 40) = z;
        }
    }
    if (t < 80) {   // zero pad columns w''=0,65
        const int g = t & 3;
        const int rr = t >> 2;
        const int r = rr >> 1;
        const int col = (rr & 1) ? 65 : 0;
        const ushort8_v z = {0, 0, 0, 0, 0, 0, 0, 0};
        *(ushort8_v*)&tile[(r * 66 + col) * 40 + 8 * g] = z;
    }
    __syncthreads();

    // ---- K loop: 9 taps x 4 M-tiles, weights from regs ----
    f32x4 acc[4][2];
#pragma unroll
    for (int mt = 0; mt < 4; ++mt)
#pragma unroll
        for (int nt = 0; nt < 2; ++nt) acc[mt][nt] = (f32x4){0.f, 0.f, 0.f, 0.f};

#pragma unroll
    for (int ky = 0; ky < 3; ++ky)
#pragma unroll
        for (int kx = 0; kx < 3; ++kx) {
            const int s = ky * 3 + kx;
            const int base = ((wid + ky) * 66 + kx + lm) * 40 + 8 * lg;
#pragma unroll
            for (int mt = 0; mt < 4; ++mt) {
                const bf16x8 a = ld_frag(&tile[base + mt * 640]);
                acc[mt][0] = __builtin_amdgcn_mfma_f32_16x16x32_bf16(a, wreg[0][s], acc[mt][0], 0, 0, 0);
                acc[mt][1] = __builtin_amdgcn_mfma_f32_16x16x32_bf16(a, wreg[1][s], acc[mt][1], 0, 0, 0);
            }
        }

    // ---- epilogue ----
    const int h = h0 + wid;
    const int rc = (h == 0) ? 0 : ((h == 63) ? 2 : 1);
    float bias_[2], tcn[2], tc0[2], tc2[2];
#pragma unroll
    for (int nt = 0; nt < 2; ++nt) {
        const int oc = nt * 16 + lm;
        bias_[nt] = cb[oc];
        if (HAS_TIME) {
            tcn[nt] = tcls[oc * 9 + rc * 3 + 1];
            tc0[nt] = tcls[oc * 9 + rc * 3 + 0];
            tc2[nt] = tcls[oc * 9 + rc * 3 + 2];
        }
    }
    float sl[2] = {0.f, 0.f}, ssl[2] = {0.f, 0.f};
    float* outf = (float*)outv;
    unsigned short* outb = (unsigned short*)outv;
#pragma unroll
    for (int mt = 0; mt < 4; ++mt) {
#pragma unroll
        for (int nt = 0; nt < 2; ++nt) {
            const int oc = nt * 16 + lm;
            float v[4];
#pragma unroll
            for (int r = 0; r < 4; ++r) {
                v[r] = acc[mt][nt][r] + bias_[nt];
                if (HAS_TIME) v[r] += tval * tcn[nt];
            }
            if (HAS_TIME && mt == 0 && lg == 0) v[0] += tval * (tc0[nt] - tcn[nt]);
            if (HAS_TIME && mt == 3 && lg == 3) v[3] += tval * (tc2[nt] - tcn[nt]);
            const int w0 = mt * 16 + lg * 4;
            const size_t o = ((size_t)(b * 32 + oc)) * HW + (size_t)h * 64 + w0;
            if (OUT_BF16) {
                ushort4 u;
                u.x = f2b(v[0]); u.y = f2b(v[1]); u.z = f2b(v[2]); u.w = f2b(v[3]);
                *(ushort4*)&outb[o] = u;
                if (STATS) {   // stats on rounded values (consumer reads bf16)
#pragma unroll
                    for (int r = 0; r < 4; ++r) {
                        const float vr = b2f(f2b(v[r]));
                        sl[nt] += vr; ssl[nt] += vr * vr;
                    }
                }
            } else {
                float4 q; q.x = v[0]; q.y = v[1]; q.z = v[2]; q.w = v[3];
                *(float4*)&outf[o] = q;
                if (STATS) {
#pragma unroll
                    for (int r = 0; r < 4; ++r) { sl[nt] += v[r]; ssl[nt] += v[r] * v[r]; }
                }
            }
        }
    }
    if (STATS) {
        float s0 = sl[0], q0 = ssl[0], s1 = sl[1], q1 = ssl[1];
        s0 += __shfl_xor(s0, 16); s0 += __shfl_xor(s0, 32);
        q0 += __shfl_xor(q0, 16); q0 += __shfl_xor(q0, 32);
        s1 += __shfl_xor(s1, 16); s1 += __shfl_xor(s1, 32);
        q1 += __shfl_xor(q1, 16); q1 += __shfl_xor(q1, 32);
        __syncthreads();                       // tile no longer needed
        float* red = (float*)tile;             // [0..255]=S, [256..511]=SS
        if (lg == 0) {
            red[wid * 32 + lm]       = s0;  red[256 + wid * 32 + lm]       = q0;
            red[wid * 32 + 16 + lm]  = s1;  red[256 + wid * 32 + 16 + lm]  = q1;
        }
        __syncthreads();
        if (t < 32) {
            float S = 0.f, Q = 0.f;
#pragma unroll
            for (int w = 0; w < 8; ++w) { S += red[w * 32 + t]; Q += red[256 + w * 32 + t]; }
            float* dst = straw + ((size_t)(b * 32 + t) * 8 + hb) * 2;
            dst[0] = S; dst[1] = Q;
        }
    }
}

// ---------- atten_init tail: gn2+relu -> gn3; fp32 + bf16 out + GN1 stats --
__global__ __launch_bounds__(256)
void dgn_kernel(const float* __restrict__ in, float* __restrict__ out,
                unsigned short* __restrict__ xbout,
                const float* __restrict__ g2, const float* __restrict__ b2,
                const float* __restrict__ g3, const float* __restrict__ b3,
                const float* __restrict__ g1n, const float* __restrict__ b1n,
                float* __restrict__ stout)
{
    const int p = blockIdx.x;
    const int c = p & 31;
    const int t = threadIdx.x;
    const float4* ip = (const float4*)(in + (size_t)p * HW);
    float4* op = (float4*)(out + (size_t)p * HW);
    ushort4* xp = (ushort4*)(xbout + (size_t)p * HW);
    __shared__ float red[8];
    const int wid = t >> 6;

    float4 v[4];
    float s = 0.f, ss = 0.f;
#pragma unroll
    for (int i = 0; i < 4; ++i) {
        float4 q = ip[t + i * 256];
        v[i] = q;
        s += q.x + q.y + q.z + q.w;
        ss += q.x * q.x + q.y * q.y + q.z * q.z + q.w * q.w;
    }
#pragma unroll
    for (int off = 32; off > 0; off >>= 1) {
        s  += __shfl_xor(s, off);
        ss += __shfl_xor(ss, off);
    }
    if ((t & 63) == 0) { red[wid] = s; red[4 + wid] = ss; }
    __syncthreads();
    s  = red[0] + red[1] + red[2] + red[3];
    ss = red[4] + red[5] + red[6] + red[7];
    float mean = s * (1.f / HW);
    float var  = ss * (1.f / HW) - mean * mean;
    float rstd = rsqrtf(var + 1e-5f);
    float sc = g2[c] * rstd;
    float sh = b2[c] - mean * sc;

    s = 0.f; ss = 0.f;
#pragma unroll
    for (int i = 0; i < 4; ++i) {
        float4 q = v[i];
        q.x = fmaxf(q.x * sc + sh, 0.f); q.y = fmaxf(q.y * sc + sh, 0.f);
        q.z = fmaxf(q.z * sc + sh, 0.f); q.w = fmaxf(q.w * sc + sh, 0.f);
        v[i] = q;
        s += q.x + q.y + q.z + q.w;
        ss += q.x * q.x + q.y * q.y + q.z * q.z + q.w * q.w;
    }
#pragma unroll
    for (int off = 32; off > 0; off >>= 1) {
        s  += __shfl_xor(s, off);
        ss += __shfl_xor(ss, off);
    }
    __syncthreads();
    if ((t & 63) == 0) { red[wid] = s; red[4 + wid] = ss; }
    __syncthreads();
    s  = red[0] + red[1] + red[2] + red[3];
    ss = red[4] + red[5] + red[6] + red[7];
    mean = s * (1.f / HW);
    var  = ss * (1.f / HW) - mean * mean;
    rstd = rsqrtf(var + 1e-5f);
    sc = g3[c] * rstd;
    sh = b3[c] - mean * sc;

    float s3 = 0.f, ss3 = 0.f;
#pragma unroll
    for (int i = 0; i < 4; ++i) {
        float4 q = v[i];
        q.x = q.x * sc + sh; q.y = q.y * sc + sh;
        q.z = q.z * sc + sh; q.w = q.w * sc + sh;
        op[t + i * 256] = q;
        ushort4 u; u.x = f2b(q.x); u.y = f2b(q.y); u.z = f2b(q.z); u.w = f2b(q.w);
        xp[t + i * 256] = u;
        s3 += q.x + q.y + q.z + q.w;
        ss3 += q.x * q.x + q.y * q.y + q.z * q.z + q.w * q.w;
    }
#pragma unroll
    for (int off = 32; off > 0; off >>= 1) {
        s3  += __shfl_xor(s3, off);
        ss3 += __shfl_xor(ss3, off);
    }
    __syncthreads();
    if ((t & 63) == 0) { red[wid] = s3; red[4 + wid] = ss3; }
    __syncthreads();
    if (t == 0) {
        s3  = red[0] + red[1] + red[2] + red[3];
        ss3 = red[4] + red[5] + red[6] + red[7];
        const float m3 = s3 * (1.f / HW);
        const float v3 = ss3 * (1.f / HW) - m3 * m3;
        const float r3 = rsqrtf(v3 + 1e-5f);
        const float sc1 = g1n[c] * r3;
        stout[p * 2]     = sc1;
        stout[p * 2 + 1] = b1n[c] - m3 * sc1;
    }
}

// ---------- streaming GN3 + RK update (fp32 acc, bf16 y-shadow) ------------
// kin = bf16 conv2 output; GN3 finalized in-register from straw (no barrier).
// MODE 0: acc = y + ca*k ; XB = bf16(y + cy*k) ; YB = bf16(y)  [reads y fp32 NT]
// MODE 1: acc += ca*k    ; XB = bf16(yb + cy*k)                [reads YB bf16]
// MODE 2: y = acc + ca*k (NT store) ; XB = bf16(y_new)
template<int MODE>
__global__ __launch_bounds__(256)
void gnrk_kernel(const unsigned short* __restrict__ kin,
                 const float* __restrict__ straw,
                 const float* __restrict__ g, const float* __restrict__ bt,
                 float* __restrict__ y, float* __restrict__ acc,
                 float ca, float cy,
                 const float* __restrict__ g1n, const float* __restrict__ b1n,
                 float* __restrict__ stout, unsigned short* __restrict__ xb,
                 unsigned short* __restrict__ yb)
{
    const int p = blockIdx.x;
    const int c = p & 31;
    const int t = threadIdx.x;

    // in-register GN3 finalize: broadcast 8 partials, 3 shuffles, no barrier
    const float2 pr = ((const float2*)straw)[(size_t)p * 8 + (t & 7)];
    float s = pr.x, ss = pr.y;
    s += __shfl_xor(s, 1); ss += __shfl_xor(ss, 1);
    s += __shfl_xor(s, 2); ss += __shfl_xor(ss, 2);
    s += __shfl_xor(s, 4); ss += __shfl_xor(ss, 4);
    const float mean = s * (1.f / HW);
    const float var  = ss * (1.f / HW) - mean * mean;
    const float rstd = rsqrtf(var + 1e-5f);
    const float sc = g[c] * rstd;
    const float sh = bt[c] - mean * sc;

    const ushort4* kp = (const ushort4*)(kin + (size_t)p * HW);
    const f32x4* ypl = (const f32x4*)(y + (size_t)p * HW);
    f32x4* yps = (f32x4*)(y + (size_t)p * HW);
    f32x4* ap  = (f32x4*)(acc + (size_t)p * HW);
    ushort4* xp = (ushort4*)(xb + (size_t)p * HW);
    ushort4* ybp = (ushort4*)(yb + (size_t)p * HW);
    __shared__ float red[8];
    const int wid = t >> 6;

    // ---- batch all loads first (max MLP) ----
    ushort4 ku[4];
#pragma unroll
    for (int i = 0; i < 4; ++i) ku[i] = kp[t + i * 256];
    f32x4 yv[4];
    if (MODE == 0) {
#pragma unroll
        for (int i = 0; i < 4; ++i)
            yv[i] = __builtin_nontemporal_load(ypl + t + i * 256);   // NT: no alloc
    }
    ushort4 ybv[4];
    if (MODE == 1) {
#pragma unroll
        for (int i = 0; i < 4; ++i) ybv[i] = ybp[t + i * 256];
    }
    f32x4 av[4];
    if (MODE != 0) {
#pragma unroll
        for (int i = 0; i < 4; ++i) av[i] = ap[t + i * 256];
    }

    float s2 = 0.f, ss2 = 0.f;
#pragma unroll
    for (int i = 0; i < 4; ++i) {
        const int idx = t + i * 256;
        f32x4 kq;
        kq[0] = b2f(ku[i].x) * sc + sh; kq[1] = b2f(ku[i].y) * sc + sh;
        kq[2] = b2f(ku[i].z) * sc + sh; kq[3] = b2f(ku[i].w) * sc + sh;
        ushort4 u;
        if (MODE == 0) {
            f32x4 a, w;
#pragma unroll
            for (int j = 0; j < 4; ++j) {
                a[j] = yv[i][j] + ca * kq[j];
                w[j] = yv[i][j] + cy * kq[j];
            }
            ap[idx] = a;
            u.x = f2b(w[0]); u.y = f2b(w[1]); u.z = f2b(w[2]); u.w = f2b(w[3]);
            xp[idx] = u;
            ushort4 yu;
            yu.x = f2b(yv[i][0]); yu.y = f2b(yv[i][1]);
            yu.z = f2b(yv[i][2]); yu.w = f2b(yv[i][3]);
            ybp[idx] = yu;                       // base-y shadow for k2/k3
        } else if (MODE == 1) {
            f32x4 a, w;
            a[0] = av[i][0] + ca * kq[0]; a[1] = av[i][1] + ca * kq[1];
            a[2] = av[i][2] + ca * kq[2]; a[3] = av[i][3] + ca * kq[3];
            w[0] = b2f(ybv[i].x) + cy * kq[0]; w[1] = b2f(ybv[i].y) + cy * kq[1];
            w[2] = b2f(ybv[i].z) + cy * kq[2]; w[3] = b2f(ybv[i].w) + cy * kq[3];
            ap[idx] = a;
            u.x = f2b(w[0]); u.y = f2b(w[1]); u.z = f2b(w[2]); u.w = f2b(w[3]);
            xp[idx] = u;
        } else {
            f32x4 w;
            w[0] = av[i][0] + ca * kq[0]; w[1] = av[i][1] + ca * kq[1];
            w[2] = av[i][2] + ca * kq[2]; w[3] = av[i][3] + ca * kq[3];
            __builtin_nontemporal_store(w, yps + idx);
            u.x = f2b(w[0]); u.y = f2b(w[1]); u.z = f2b(w[2]); u.w = f2b(w[3]);
            xp[idx] = u;
        }
        // GN1 stats of NEXT stage input, on rounded values (conv1 reads bf16)
        const float r0 = b2f(u.x), r1 = b2f(u.y), r2 = b2f(u.z), r3 = b2f(u.w);
        s2  += r0 + r1 + r2 + r3;
        ss2 += r0 * r0 + r1 * r1 + r2 * r2 + r3 * r3;
    }
#pragma unroll
    for (int off = 32; off > 0; off >>= 1) {
        s2  += __shfl_xor(s2, off);
        ss2 += __shfl_xor(ss2, off);
    }
    if ((t & 63) == 0) { red[wid] = s2; red[4 + wid] = ss2; }
    __syncthreads();
    if (t == 0) {
        s2  = red[0] + red[1] + red[2] + red[3];
        ss2 = red[4] + red[5] + red[6] + red[7];
        const float m2 = s2 * (1.f / HW);
        const float v2 = ss2 * (1.f / HW) - m2 * m2;
        const float r2 = rsqrtf(v2 + 1e-5f);
        const float sc1 = g1n[c] * r2;
        stout[p * 2]     = sc1;
        stout[p * 2 + 1] = b1n[c] - m2 * sc1;
    }
}

extern "C" void kernel_launch(void* const* d_in, const int* in_sizes, int n_in,
                              void* d_out, int out_size, void* d_ws, size_t ws_size,
                              hipStream_t stream) {
    (void)in_sizes; (void)n_in; (void)out_size; (void)ws_size;
    const float* x      = (const float*)d_in[0];
    const float* ai_g1  = (const float*)d_in[1];
    const float* ai_b1  = (const float*)d_in[2];
    const float* ai_w   = (const float*)d_in[3];
    const float* ai_cb  = (const float*)d_in[4];
    const float* ai_g2  = (const float*)d_in[5];
    const float* ai_b2  = (const float*)d_in[6];
    const float* ai_g3  = (const float*)d_in[7];
    const float* ai_b3  = (const float*)d_in[8];
    const float* of_g1  = (const float*)d_in[9];
    const float* of_b1  = (const float*)d_in[10];
    const float* of_w1  = (const float*)d_in[11];
    const float* of_cb1 = (const float*)d_in[12];
    const float* of_g2  = (const float*)d_in[13];
    const float* of_b2  = (const float*)d_in[14];
    const float* of_w2  = (const float*)d_in[15];
    const float* of_cb2 = (const float*)d_in[16];
    const float* of_g3  = (const float*)d_in[17];
    const float* of_b3  = (const float*)d_in[18];

    float* y = (float*)d_out;                         // (256,32,64,64) fp32
    const size_t N  = (size_t)256 * 32 * 64 * 64;
    const size_t NH = N / 2;
    float* ws = (float*)d_ws;
    float* ACC = ws;                                             // RK acc (fp32)
    float* YTf = ws;                                             // prologue alias
    unsigned short* Abf = (unsigned short*)(ws + N);             // conv1 out bf16
    unsigned short* XB  = (unsigned short*)(ws + N + N / 2);     // stage in bf16
    unsigned short* YTB = (unsigned short*)(ws + 2 * N);         // conv2 out bf16
    unsigned short* YB  = (unsigned short*)(ws + 2 * N + N / 2); // bf16 y-shadow
    float* tail  = ws + 3 * N;
    float* ST1    = tail;               tail += 16384;   // GN1 (sc,sh), 8192 pl
    float* ST_AI  = tail;               tail += 8192;
    float* STRAW1 = tail;               tail += 131072;  // conv1 partials
    float* STRAW2 = tail;               tail += 131072;  // conv2 partials
    unsigned short* WPai = (unsigned short*)tail;  tail += 5760;
    unsigned short* WP1  = (unsigned short*)tail;  tail += 5760;
    unsigned short* WP2  = (unsigned short*)tail;  tail += 5760;
    float* TC1  = tail;                 tail += 288;
    float* TC2  = tail;                 tail += 288;

    const float h = 0.125f;

    prep_kernel<<<1, 256, 0, stream>>>(ai_w, of_w1, of_w2, WPai, WP1, WP2, TC1, TC2);

    // ---- atten_init (batch 128): fused y=x / XB / both stat sets ----
    xstat_kernel<<<4096, 256, 0, stream>>>(x, y, XB, ai_g1, ai_b1, of_g1, of_b1,
                                           ST_AI, ST1);
    conv_kernel<0, 0, 0, 0><<<1024, 512, 0, stream>>>(XB, YTf, ST_AI, nullptr, nullptr,
                                                      WPai, ai_cb, nullptr, 0.f, nullptr);
    dgn_kernel<<<4096, 256, 0, stream>>>(YTf, y + NH, XB + NH, ai_g2, ai_b2,
                                         ai_g3, ai_b3, of_g1, of_b1, ST1 + 8192);

    auto eval = [&](float tv, float ca, float cy, int mode) {
        conv_kernel<1, 1, 1, 0><<<2048, 512, 0, stream>>>(XB, Abf, ST1, nullptr, nullptr,
                                                          WP1, of_cb1, TC1, tv, STRAW1);
        conv_kernel<1, 1, 1, 1><<<2048, 512, 0, stream>>>(Abf, YTB, STRAW1, of_g2, of_b2,
                                                          WP2, of_cb2, TC2, tv, STRAW2);
        if (mode == 0)
            gnrk_kernel<0><<<8192, 256, 0, stream>>>(YTB, STRAW2, of_g3, of_b3, y, ACC,
                                                     ca, cy, of_g1, of_b1, ST1, XB, YB);
        else if (mode == 1)
            gnrk_kernel<1><<<8192, 256, 0, stream>>>(YTB, STRAW2, of_g3, of_b3, y, ACC,
                                                     ca, cy, of_g1, of_b1, ST1, XB, YB);
        else
            gnrk_kernel<2><<<8192, 256, 0, stream>>>(YTB, STRAW2, of_g3, of_b3, y, ACC,
                                                     ca, cy, of_g1, of_b1, ST1, XB, YB);
    };

    for (int s = 0; s < 8; ++s) {
        const float t0 = h * (float)s;
        eval(t0,            h / 6.f, 0.5f * h, 0);   // k1
        eval(t0 + 0.5f * h, h / 3.f, 0.5f * h, 1);   // k2
        eval(t0 + 0.5f * h, h / 3.f, h,        1);   // k3
        eval(t0 + h,        h / 6.f, 0.f,      2);   // k4
    }
}

// Round 11
// 4897.608 us; speedup vs baseline: 6.0326x; 1.1216x over previous
//
#include <hip/hip_runtime.h>

#define HW 4096            // 64*64
#define CIN 32

typedef __bf16 bf16x8 __attribute__((ext_vector_type(8)));
typedef float  f32x4  __attribute__((ext_vector_type(4)));
typedef unsigned short ushort8_v __attribute__((ext_vector_type(8)));

__device__ __forceinline__ unsigned short f2b(float f) {
    __bf16 b = (__bf16)f;                    // v_cvt, RNE
    return __builtin_bit_cast(unsigned short, b);
}
__device__ __forceinline__ float b2f(unsigned short s) {
    unsigned int u = ((unsigned int)s) << 16;
    return __builtin_bit_cast(float, u);
}
__device__ __forceinline__ bf16x8 ld_frag(const unsigned short* p) {
    ushort8_v u = *(const ushort8_v*)p;
    return __builtin_bit_cast(bf16x8, u);
}

// ---------- weight prep: WP[tap s][oc][ci pad 40] bf16; Tcls[oc][9] --------
__global__ __launch_bounds__(256)
void prep_kernel(const float* __restrict__ ai_w,
                 const float* __restrict__ of_w1,
                 const float* __restrict__ of_w2,
                 unsigned short* __restrict__ wp_ai,
                 unsigned short* __restrict__ wp1,
                 unsigned short* __restrict__ wp2,
                 float* __restrict__ tc1, float* __restrict__ tc2)
{
    const int t = threadIdx.x;
    for (int i = t; i < 9 * 32 * 40; i += 256) {
        const int s = i / 1280;
        const int rem = i - s * 1280;
        const int oc = rem / 40;
        const int ci = rem - oc * 40;
        unsigned short va = 0, v1 = 0, v2 = 0;
        if (ci < 32) {
            va = f2b(ai_w[(oc * 32 + ci) * 9 + s]);
            v1 = f2b(of_w1[(oc * 33 + ci + 1) * 9 + s]);
            v2 = f2b(of_w2[(oc * 33 + ci + 1) * 9 + s]);
        }
        wp_ai[i] = va; wp1[i] = v1; wp2[i] = v2;
    }
    for (int i = t; i < 32 * 9; i += 256) {
        const int oc = i / 9;
        const int cls = i - oc * 9;
        const int rc = cls / 3, cc = cls - rc * 3;
        float s1 = 0.f, s2 = 0.f;
        for (int ky = 0; ky < 3; ++ky) {
            if ((rc == 0 && ky == 0) || (rc == 2 && ky == 2)) continue;
            for (int kx = 0; kx < 3; ++kx) {
                if ((cc == 0 && kx == 0) || (cc == 2 && kx == 2)) continue;
                s1 += of_w1[(oc * 33) * 9 + ky * 3 + kx];
                s2 += of_w2[(oc * 33) * 9 + ky * 3 + kx];
            }
        }
        tc1[i] = s1; tc2[i] = s2;
    }
}

// ---------- fused prologue: y=x, XB=YB=bf16(x), GN stats (ai_g1, of_g1) ----
__global__ __launch_bounds__(256)
void xstat_kernel(const float* __restrict__ x, float* __restrict__ y,
                  unsigned short* __restrict__ xb, unsigned short* __restrict__ yb,
                  const float* __restrict__ g_ai, const float* __restrict__ b_ai,
                  const float* __restrict__ g_of, const float* __restrict__ b_of,
                  float* __restrict__ st_ai, float* __restrict__ st_of)
{
    const int p = blockIdx.x;          // 4096 planes (batch-128 half)
    const int c = p & 31;
    const int t = threadIdx.x;
    const float4* ip = (const float4*)(x + (size_t)p * HW);
    float4* yp = (float4*)(y + (size_t)p * HW);
    ushort4* xp = (ushort4*)(xb + (size_t)p * HW);
    ushort4* ybp = (ushort4*)(yb + (size_t)p * HW);
    float s = 0.f, ss = 0.f;
#pragma unroll
    for (int i = 0; i < 4; ++i) {
        const float4 q = ip[t + i * 256];
        yp[t + i * 256] = q;
        ushort4 u; u.x = f2b(q.x); u.y = f2b(q.y); u.z = f2b(q.z); u.w = f2b(q.w);
        xp[t + i * 256] = u;
        ybp[t + i * 256] = u;
        s += q.x + q.y + q.z + q.w;
        ss += q.x * q.x + q.y * q.y + q.z * q.z + q.w * q.w;
    }
#pragma unroll
    for (int off = 32; off > 0; off >>= 1) {
        s  += __shfl_xor(s, off);
        ss += __shfl_xor(ss, off);
    }
    __shared__ float red[8];
    const int wid = t >> 6;
    if ((t & 63) == 0) { red[wid] = s; red[4 + wid] = ss; }
    __syncthreads();
    if (t == 0) {
        s  = red[0] + red[1] + red[2] + red[3];
        ss = red[4] + red[5] + red[6] + red[7];
        const float mean = s * (1.f / HW);
        const float var  = ss * (1.f / HW) - mean * mean;
        const float rstd = rsqrtf(var + 1e-5f);
        const float sa = g_ai[c] * rstd;
        st_ai[p * 2]     = sa;
        st_ai[p * 2 + 1] = b_ai[c] - mean * sa;
        const float so = g_of[c] * rstd;
        st_of[p * 2]     = so;
        st_of[p * 2 + 1] = b_of[c] - mean * so;
    }
}

// ---------- MFMA implicit-GEMM conv 3x3 ------------------------------------
// 512 thr = 8 waves; block = (b, 8 output rows). Wave wid = one row of 64 px.
// A = pixel tile (LDS, gather-staged, GN+ReLU fused), B = weights (registers).
// FIN=0: st = per-plane (sc,sh). FIN=1: st = raw partials [plane][8][2].
template<int HAS_TIME, int STATS, int OUT_BF16, int FIN>
__global__ __launch_bounds__(512)
void conv_kernel(const unsigned short* __restrict__ in, void* __restrict__ outv,
                 const float* __restrict__ st,
                 const float* __restrict__ fg, const float* __restrict__ fb,
                 const unsigned short* __restrict__ wp,
                 const float* __restrict__ cb, const float* __restrict__ tcls,
                 float tval, float* __restrict__ straw)
{
    const int blk = blockIdx.x;
    const int b  = blk >> 3;
    const int hb = blk & 7;
    const int h0 = hb * 8;
    const int t  = threadIdx.x;
    const int l  = t & 63;
    const int wid = t >> 6;            // 0..7 = output row
    const int lm = l & 15;
    const int lg = l >> 4;

    __shared__ unsigned short tile[10 * 66 * 40];   // 52800 B
    __shared__ float sst[64];                        // (sc,sh) per ci

    // ---- GN scale/shift table ----
    if (FIN) {
        float s = 0.f, ss = 0.f;
        if (t < 256) {
            const float2 pr = ((const float2*)st)[(size_t)(b * 32 + (t >> 3)) * 8 + (t & 7)];
            s = pr.x; ss = pr.y;
        }
        s += __shfl_xor(s, 1); ss += __shfl_xor(ss, 1);
        s += __shfl_xor(s, 2); ss += __shfl_xor(ss, 2);
        s += __shfl_xor(s, 4); ss += __shfl_xor(ss, 4);
        if (t < 256 && (t & 7) == 0) {
            const int ci = t >> 3;
            const float mean = s * (1.f / HW);
            const float var  = ss * (1.f / HW) - mean * mean;
            const float rstd = rsqrtf(var + 1e-5f);
            const float sc = fg[ci] * rstd;
            sst[ci * 2]     = sc;
            sst[ci * 2 + 1] = fb[ci] - mean * sc;
        }
    } else {
        if (t < 64) sst[t] = st[b * 64 + t];
    }

    // ---- weight fragments into registers: wreg[nt][tap] ----
    bf16x8 wreg[2][9];
    {
        const unsigned short* wb = wp + (size_t)(lm * 40 + 8 * lg);
#pragma unroll
        for (int nt = 0; nt < 2; ++nt)
#pragma unroll
            for (int s = 0; s < 9; ++s)
                wreg[nt][s] = ld_frag(wb + s * 1280 + nt * 640);
    }
    __syncthreads();   // sst ready

    // ---- stage: 640 w-quad tasks; 8 x ushort4 loads -> 4 x ds_write_b128 --
    const unsigned short* inb = in + (size_t)b * (CIN * HW);
#pragma unroll
    for (int tau = t; tau < 640; tau += 512) {
        const int g = tau / 160;           // channel group (8 ci)
        const int rem = tau - g * 160;
        const int r = rem >> 4;            // tile row 0..9
        const int wq = rem & 15;           // w-quad 0..15
        const int hh = h0 - 1 + r;
        unsigned short* dst = &tile[(r * 66 + wq * 4 + 1) * 40 + 8 * g];
        if (hh >= 0 && hh < 64) {
            const unsigned short* src = inb + (size_t)(8 * g) * HW + hh * 64 + wq * 4;
            ushort4 U[8];
#pragma unroll
            for (int j = 0; j < 8; ++j) U[j] = *(const ushort4*)(src + (size_t)j * HW);
            float scv[8], shv[8];
#pragma unroll
            for (int j = 0; j < 8; ++j) {
                const float2 s2 = *(const float2*)(&sst[(8 * g + j) * 2]);
                scv[j] = s2.x; shv[j] = s2.y;
            }
#pragma unroll
            for (int k = 0; k < 4; ++k) {
                ushort8_v F;
#pragma unroll
                for (int j = 0; j < 8; ++j) {
                    const unsigned short e = ((const unsigned short*)&U[j])[k];
                    F[j] = f2b(fmaxf(b2f(e) * scv[j] + shv[j], 0.f));
                }
                *(ushort8_v*)(dst + k * 40) = F;
            }
        } else {
            const ushort8_v z = {0, 0, 0, 0, 0, 0, 0, 0};
#pragma unroll
            for (int k = 0; k < 4; ++k) *(ushort8_v*)(dst + k * 40) = z;
        }
    }
    if (t < 80) {   // zero pad columns w''=0,65
        const int g = t & 3;
        const int rr = t >> 2;
        const int r = rr >> 1;
        const int col = (rr & 1) ? 65 : 0;
        const ushort8_v z = {0, 0, 0, 0, 0, 0, 0, 0};
        *(ushort8_v*)&tile[(r * 66 + col) * 40 + 8 * g] = z;
    }
    __syncthreads();

    // ---- K loop: 9 taps x 4 M-tiles, weights from regs ----
    f32x4 acc[4][2];
#pragma unroll
    for (int mt = 0; mt < 4; ++mt)
#pragma unroll
        for (int nt = 0; nt < 2; ++nt) acc[mt][nt] = (f32x4){0.f, 0.f, 0.f, 0.f};

#pragma unroll
    for (int ky = 0; ky < 3; ++ky)
#pragma unroll
        for (int kx = 0; kx < 3; ++kx) {
            const int s = ky * 3 + kx;
            const int base = ((wid + ky) * 66 + kx + lm) * 40 + 8 * lg;
#pragma unroll
            for (int mt = 0; mt < 4; ++mt) {
                const bf16x8 a = ld_frag(&tile[base + mt * 640]);
                acc[mt][0] = __builtin_amdgcn_mfma_f32_16x16x32_bf16(a, wreg[0][s], acc[mt][0], 0, 0, 0);
                acc[mt][1] = __builtin_amdgcn_mfma_f32_16x16x32_bf16(a, wreg[1][s], acc[mt][1], 0, 0, 0);
            }
        }

    // ---- epilogue ----
    const int h = h0 + wid;
    const int rc = (h == 0) ? 0 : ((h == 63) ? 2 : 1);
    float bias_[2], tcn[2], tc0[2], tc2[2];
#pragma unroll
    for (int nt = 0; nt < 2; ++nt) {
        const int oc = nt * 16 + lm;
        bias_[nt] = cb[oc];
        if (HAS_TIME) {
            tcn[nt] = tcls[oc * 9 + rc * 3 + 1];
            tc0[nt] = tcls[oc * 9 + rc * 3 + 0];
            tc2[nt] = tcls[oc * 9 + rc * 3 + 2];
        }
    }
    float sl[2] = {0.f, 0.f}, ssl[2] = {0.f, 0.f};
    float* outf = (float*)outv;
    unsigned short* outb = (unsigned short*)outv;
#pragma unroll
    for (int mt = 0; mt < 4; ++mt) {
#pragma unroll
        for (int nt = 0; nt < 2; ++nt) {
            const int oc = nt * 16 + lm;
            float v[4];
#pragma unroll
            for (int r = 0; r < 4; ++r) {
                v[r] = acc[mt][nt][r] + bias_[nt];
                if (HAS_TIME) v[r] += tval * tcn[nt];
            }
            if (HAS_TIME && mt == 0 && lg == 0) v[0] += tval * (tc0[nt] - tcn[nt]);
            if (HAS_TIME && mt == 3 && lg == 3) v[3] += tval * (tc2[nt] - tcn[nt]);
            const int w0 = mt * 16 + lg * 4;
            const size_t o = ((size_t)(b * 32 + oc)) * HW + (size_t)h * 64 + w0;
            if (OUT_BF16) {
                ushort4 u;
                u.x = f2b(v[0]); u.y = f2b(v[1]); u.z = f2b(v[2]); u.w = f2b(v[3]);
                *(ushort4*)&outb[o] = u;
                if (STATS) {   // stats on rounded values (consumer reads bf16)
#pragma unroll
                    for (int r = 0; r < 4; ++r) {
                        const float vr = b2f(f2b(v[r]));
                        sl[nt] += vr; ssl[nt] += vr * vr;
                    }
                }
            } else {
                float4 q; q.x = v[0]; q.y = v[1]; q.z = v[2]; q.w = v[3];
                *(float4*)&outf[o] = q;
                if (STATS) {
#pragma unroll
                    for (int r = 0; r < 4; ++r) { sl[nt] += v[r]; ssl[nt] += v[r] * v[r]; }
                }
            }
        }
    }
    if (STATS) {
        float s0 = sl[0], q0 = ssl[0], s1 = sl[1], q1 = ssl[1];
        s0 += __shfl_xor(s0, 16); s0 += __shfl_xor(s0, 32);
        q0 += __shfl_xor(q0, 16); q0 += __shfl_xor(q0, 32);
        s1 += __shfl_xor(s1, 16); s1 += __shfl_xor(s1, 32);
        q1 += __shfl_xor(q1, 16); q1 += __shfl_xor(q1, 32);
        __syncthreads();                       // tile no longer needed
        float* red = (float*)tile;             // [0..255]=S, [256..511]=SS
        if (lg == 0) {
            red[wid * 32 + lm]       = s0;  red[256 + wid * 32 + lm]       = q0;
            red[wid * 32 + 16 + lm]  = s1;  red[256 + wid * 32 + 16 + lm]  = q1;
        }
        __syncthreads();
        if (t < 32) {
            float S = 0.f, Q = 0.f;
#pragma unroll
            for (int w = 0; w < 8; ++w) { S += red[w * 32 + t]; Q += red[256 + w * 32 + t]; }
            float* dst = straw + ((size_t)(b * 32 + t) * 8 + hb) * 2;
            dst[0] = S; dst[1] = Q;
        }
    }
}

// ---------- atten_init tail: gn2+relu -> gn3; fp32 + bf16 out + GN1 stats --
__global__ __launch_bounds__(256)
void dgn_kernel(const float* __restrict__ in, float* __restrict__ out,
                unsigned short* __restrict__ xbout, unsigned short* __restrict__ ybout,
                const float* __restrict__ g2, const float* __restrict__ b2,
                const float* __restrict__ g3, const float* __restrict__ b3,
                const float* __restrict__ g1n, const float* __restrict__ b1n,
                float* __restrict__ stout)
{
    const int p = blockIdx.x;
    const int c = p & 31;
    const int t = threadIdx.x;
    const float4* ip = (const float4*)(in + (size_t)p * HW);
    float4* op = (float4*)(out + (size_t)p * HW);
    ushort4* xp = (ushort4*)(xbout + (size_t)p * HW);
    ushort4* ybp = (ushort4*)(ybout + (size_t)p * HW);
    __shared__ float red[8];
    const int wid = t >> 6;

    float4 v[4];
    float s = 0.f, ss = 0.f;
#pragma unroll
    for (int i = 0; i < 4; ++i) {
        float4 q = ip[t + i * 256];
        v[i] = q;
        s += q.x + q.y + q.z + q.w;
        ss += q.x * q.x + q.y * q.y + q.z * q.z + q.w * q.w;
    }
#pragma unroll
    for (int off = 32; off > 0; off >>= 1) {
        s  += __shfl_xor(s, off);
        ss += __shfl_xor(ss, off);
    }
    if ((t & 63) == 0) { red[wid] = s; red[4 + wid] = ss; }
    __syncthreads();
    s  = red[0] + red[1] + red[2] + red[3];
    ss = red[4] + red[5] + red[6] + red[7];
    float mean = s * (1.f / HW);
    float var  = ss * (1.f / HW) - mean * mean;
    float rstd = rsqrtf(var + 1e-5f);
    float sc = g2[c] * rstd;
    float sh = b2[c] - mean * sc;

    s = 0.f; ss = 0.f;
#pragma unroll
    for (int i = 0; i < 4; ++i) {
        float4 q = v[i];
        q.x = fmaxf(q.x * sc + sh, 0.f); q.y = fmaxf(q.y * sc + sh, 0.f);
        q.z = fmaxf(q.z * sc + sh, 0.f); q.w = fmaxf(q.w * sc + sh, 0.f);
        v[i] = q;
        s += q.x + q.y + q.z + q.w;
        ss += q.x * q.x + q.y * q.y + q.z * q.z + q.w * q.w;
    }
#pragma unroll
    for (int off = 32; off > 0; off >>= 1) {
        s  += __shfl_xor(s, off);
        ss += __shfl_xor(ss, off);
    }
    __syncthreads();
    if ((t & 63) == 0) { red[wid] = s; red[4 + wid] = ss; }
    __syncthreads();
    s  = red[0] + red[1] + red[2] + red[3];
    ss = red[4] + red[5] + red[6] + red[7];
    mean = s * (1.f / HW);
    var  = ss * (1.f / HW) - mean * mean;
    rstd = rsqrtf(var + 1e-5f);
    sc = g3[c] * rstd;
    sh = b3[c] - mean * sc;

    float s3 = 0.f, ss3 = 0.f;
#pragma unroll
    for (int i = 0; i < 4; ++i) {
        float4 q = v[i];
        q.x = q.x * sc + sh; q.y = q.y * sc + sh;
        q.z = q.z * sc + sh; q.w = q.w * sc + sh;
        op[t + i * 256] = q;
        ushort4 u; u.x = f2b(q.x); u.y = f2b(q.y); u.z = f2b(q.z); u.w = f2b(q.w);
        xp[t + i * 256] = u;
        ybp[t + i * 256] = u;
        s3 += q.x + q.y + q.z + q.w;
        ss3 += q.x * q.x + q.y * q.y + q.z * q.z + q.w * q.w;
    }
#pragma unroll
    for (int off = 32; off > 0; off >>= 1) {
        s3  += __shfl_xor(s3, off);
        ss3 += __shfl_xor(ss3, off);
    }
    __syncthreads();
    if ((t & 63) == 0) { red[wid] = s3; red[4 + wid] = ss3; }
    __syncthreads();
    if (t == 0) {
        s3  = red[0] + red[1] + red[2] + red[3];
        ss3 = red[4] + red[5] + red[6] + red[7];
        const float m3 = s3 * (1.f / HW);
        const float v3 = ss3 * (1.f / HW) - m3 * m3;
        const float r3 = rsqrtf(v3 + 1e-5f);
        const float sc1 = g1n[c] * r3;
        stout[p * 2]     = sc1;
        stout[p * 2 + 1] = b1n[c] - m3 * sc1;
    }
}

// ---------- streaming GN3 + RK update (bf16 DELTA accumulator) -------------
// kin = bf16 conv2 output; GN3 finalized in-register from straw (no barrier).
// D = running bf16 increment (|D| <~ 0.7, ulp ~0.003 — safe, unlike bf16 y+acc).
// MODE 0: D = ca*k            ; XB = bf16(yb + cy*k)       [no fp32 y touch]
// MODE 1: D += ca*k           ; XB = bf16(yb + cy*k)
// MODE 2: y += D + ca*k (NT)  ; XB = YB = bf16(y_new)
template<int MODE>
__global__ __launch_bounds__(256)
void gnrk_kernel(const unsigned short* __restrict__ kin,
                 const float* __restrict__ straw,
                 const float* __restrict__ g, const float* __restrict__ bt,
                 float* __restrict__ y, unsigned short* __restrict__ db,
                 float ca, float cy,
                 const float* __restrict__ g1n, const float* __restrict__ b1n,
                 float* __restrict__ stout, unsigned short* __restrict__ xb,
                 unsigned short* __restrict__ yb)
{
    const int p = blockIdx.x;
    const int c = p & 31;
    const int t = threadIdx.x;

    // in-register GN3 finalize: broadcast 8 partials, 3 shuffles, no barrier
    const float2 pr = ((const float2*)straw)[(size_t)p * 8 + (t & 7)];
    float s = pr.x, ss = pr.y;
    s += __shfl_xor(s, 1); ss += __shfl_xor(ss, 1);
    s += __shfl_xor(s, 2); ss += __shfl_xor(ss, 2);
    s += __shfl_xor(s, 4); ss += __shfl_xor(ss, 4);
    const float mean = s * (1.f / HW);
    const float var  = ss * (1.f / HW) - mean * mean;
    const float rstd = rsqrtf(var + 1e-5f);
    const float sc = g[c] * rstd;
    const float sh = bt[c] - mean * sc;

    const ushort4* kp = (const ushort4*)(kin + (size_t)p * HW);
    const f32x4* ypl = (const f32x4*)(y + (size_t)p * HW);
    f32x4* yps = (f32x4*)(y + (size_t)p * HW);
    ushort4* dp  = (ushort4*)(db + (size_t)p * HW);
    ushort4* xp  = (ushort4*)(xb + (size_t)p * HW);
    ushort4* ybp = (ushort4*)(yb + (size_t)p * HW);
    __shared__ float red[8];
    const int wid = t >> 6;

    // ---- batch all loads first (max MLP) ----
    ushort4 ku[4];
#pragma unroll
    for (int i = 0; i < 4; ++i) ku[i] = kp[t + i * 256];
    ushort4 ybv[4];
    if (MODE != 2) {
#pragma unroll
        for (int i = 0; i < 4; ++i) ybv[i] = ybp[t + i * 256];
    }
    ushort4 dv[4];
    if (MODE != 0) {
#pragma unroll
        for (int i = 0; i < 4; ++i) dv[i] = dp[t + i * 256];
    }
    f32x4 yv[4];
    if (MODE == 2) {
#pragma unroll
        for (int i = 0; i < 4; ++i)
            yv[i] = __builtin_nontemporal_load(ypl + t + i * 256);   // NT: no alloc
    }

    float s2 = 0.f, ss2 = 0.f;
#pragma unroll
    for (int i = 0; i < 4; ++i) {
        const int idx = t + i * 256;
        f32x4 kq;
        kq[0] = b2f(ku[i].x) * sc + sh; kq[1] = b2f(ku[i].y) * sc + sh;
        kq[2] = b2f(ku[i].z) * sc + sh; kq[3] = b2f(ku[i].w) * sc + sh;
        ushort4 u;
        if (MODE != 2) {
            f32x4 d, w;
            if (MODE == 0) {
#pragma unroll
                for (int j = 0; j < 4; ++j) d[j] = ca * kq[j];
            } else {
                d[0] = b2f(dv[i].x) + ca * kq[0]; d[1] = b2f(dv[i].y) + ca * kq[1];
                d[2] = b2f(dv[i].z) + ca * kq[2]; d[3] = b2f(dv[i].w) + ca * kq[3];
            }
            w[0] = b2f(ybv[i].x) + cy * kq[0]; w[1] = b2f(ybv[i].y) + cy * kq[1];
            w[2] = b2f(ybv[i].z) + cy * kq[2]; w[3] = b2f(ybv[i].w) + cy * kq[3];
            ushort4 du;
            du.x = f2b(d[0]); du.y = f2b(d[1]); du.z = f2b(d[2]); du.w = f2b(d[3]);
            dp[idx] = du;
            u.x = f2b(w[0]); u.y = f2b(w[1]); u.z = f2b(w[2]); u.w = f2b(w[3]);
            xp[idx] = u;
        } else {
            f32x4 w;
            w[0] = yv[i][0] + b2f(dv[i].x) + ca * kq[0];
            w[1] = yv[i][1] + b2f(dv[i].y) + ca * kq[1];
            w[2] = yv[i][2] + b2f(dv[i].z) + ca * kq[2];
            w[3] = yv[i][3] + b2f(dv[i].w) + ca * kq[3];
            __builtin_nontemporal_store(w, yps + idx);
            u.x = f2b(w[0]); u.y = f2b(w[1]); u.z = f2b(w[2]); u.w = f2b(w[3]);
            xp[idx] = u;
            ybp[idx] = u;                     // base-y shadow for next step
        }
        // GN1 stats of NEXT stage input, on rounded values (conv1 reads bf16)
        const float r0 = b2f(u.x), r1 = b2f(u.y), r2 = b2f(u.z), r3 = b2f(u.w);
        s2  += r0 + r1 + r2 + r3;
        ss2 += r0 * r0 + r1 * r1 + r2 * r2 + r3 * r3;
    }
#pragma unroll
    for (int off = 32; off > 0; off >>= 1) {
        s2  += __shfl_xor(s2, off);
        ss2 += __shfl_xor(ss2, off);
    }
    if ((t & 63) == 0) { red[wid] = s2; red[4 + wid] = ss2; }
    __syncthreads();
    if (t == 0) {
        s2  = red[0] + red[1] + red[2] + red[3];
        ss2 = red[4] + red[5] + red[6] + red[7];
        const float m2 = s2 * (1.f / HW);
        const float v2 = ss2 * (1.f / HW) - m2 * m2;
        const float r2 = rsqrtf(v2 + 1e-5f);
        const float sc1 = g1n[c] * r2;
        stout[p * 2]     = sc1;
        stout[p * 2 + 1] = b1n[c] - m2 * sc1;
    }
}

extern "C" void kernel_launch(void* const* d_in, const int* in_sizes, int n_in,
                              void* d_out, int out_size, void* d_ws, size_t ws_size,
                              hipStream_t stream) {
    (void)in_sizes; (void)n_in; (void)out_size; (void)ws_size;
    const float* x      = (const float*)d_in[0];
    const float* ai_g1  = (const float*)d_in[1];
    const float* ai_b1  = (const float*)d_in[2];
    const float* ai_w   = (const float*)d_in[3];
    const float* ai_cb  = (const float*)d_in[4];
    const float* ai_g2  = (const float*)d_in[5];
    const float* ai_b2  = (const float*)d_in[6];
    const float* ai_g3  = (const float*)d_in[7];
    const float* ai_b3  = (const float*)d_in[8];
    const float* of_g1  = (const float*)d_in[9];
    const float* of_b1  = (const float*)d_in[10];
    const float* of_w1  = (const float*)d_in[11];
    const float* of_cb1 = (const float*)d_in[12];
    const float* of_g2  = (const float*)d_in[13];
    const float* of_b2  = (const float*)d_in[14];
    const float* of_w2  = (const float*)d_in[15];
    const float* of_cb2 = (const float*)d_in[16];
    const float* of_g3  = (const float*)d_in[17];
    const float* of_b3  = (const float*)d_in[18];

    float* y = (float*)d_out;                         // (256,32,64,64) fp32
    const size_t N  = (size_t)256 * 32 * 64 * 64;
    const size_t NH = N / 2;
    float* ws = (float*)d_ws;
    unsigned short* DB  = (unsigned short*)ws;                   // RK delta bf16 (N)
    float* YTf = ws;                                             // prologue alias (NH f)
    unsigned short* YB  = (unsigned short*)(ws + N / 2);         // bf16 y-shadow
    unsigned short* Abf = (unsigned short*)(ws + N);             // conv1 out bf16
    unsigned short* XB  = (unsigned short*)(ws + N + N / 2);     // stage in bf16
    unsigned short* YTB = (unsigned short*)(ws + 2 * N);         // conv2 out bf16
    float* tail  = ws + 2 * N + N / 2;
    float* ST1    = tail;               tail += 16384;   // GN1 (sc,sh), 8192 pl
    float* ST_AI  = tail;               tail += 8192;
    float* STRAW1 = tail;               tail += 131072;  // conv1 partials
    float* STRAW2 = tail;               tail += 131072;  // conv2 partials
    unsigned short* WPai = (unsigned short*)tail;  tail += 5760;
    unsigned short* WP1  = (unsigned short*)tail;  tail += 5760;
    unsigned short* WP2  = (unsigned short*)tail;  tail += 5760;
    float* TC1  = tail;                 tail += 288;
    float* TC2  = tail;                 tail += 288;

    const float h = 0.125f;

    prep_kernel<<<1, 256, 0, stream>>>(ai_w, of_w1, of_w2, WPai, WP1, WP2, TC1, TC2);

    // ---- atten_init (batch 128): fused y=x / XB / YB / both stat sets ----
    xstat_kernel<<<4096, 256, 0, stream>>>(x, y, XB, YB, ai_g1, ai_b1, of_g1, of_b1,
                                           ST_AI, ST1);
    conv_kernel<0, 0, 0, 0><<<1024, 512, 0, stream>>>(XB, YTf, ST_AI, nullptr, nullptr,
                                                      WPai, ai_cb, nullptr, 0.f, nullptr);
    dgn_kernel<<<4096, 256, 0, stream>>>(YTf, y + NH, XB + NH, YB + NH, ai_g2, ai_b2,
                                         ai_g3, ai_b3, of_g1, of_b1, ST1 + 8192);

    auto eval = [&](float tv, float ca, float cy, int mode) {
        conv_kernel<1, 1, 1, 0><<<2048, 512, 0, stream>>>(XB, Abf, ST1, nullptr, nullptr,
                                                          WP1, of_cb1, TC1, tv, STRAW1);
        conv_kernel<1, 1, 1, 1><<<2048, 512, 0, stream>>>(Abf, YTB, STRAW1, of_g2, of_b2,
                                                          WP2, of_cb2, TC2, tv, STRAW2);
        if (mode == 0)
            gnrk_kernel<0><<<8192, 256, 0, stream>>>(YTB, STRAW2, of_g3, of_b3, y, DB,
                                                     ca, cy, of_g1, of_b1, ST1, XB, YB);
        else if (mode == 1)
            gnrk_kernel<1><<<8192, 256, 0, stream>>>(YTB, STRAW2, of_g3, of_b3, y, DB,
                                                     ca, cy, of_g1, of_b1, ST1, XB, YB);
        else
            gnrk_kernel<2><<<8192, 256, 0, stream>>>(YTB, STRAW2, of_g3, of_b3, y, DB,
                                                     ca, cy, of_g1, of_b1, ST1, XB, YB);
    };

    for (int s = 0; s < 8; ++s) {
        const float t0 = h * (float)s;
        eval(t0,            h / 6.f, 0.5f * h, 0);   // k1
        eval(t0 + 0.5f * h, h / 3.f, 0.5f * h, 1);   // k2
        eval(t0 + 0.5f * h, h / 3.f, h,        1);   // k3
        eval(t0 + h,        h / 6.f, 0.f,      2);   // k4
    }
}